// Round 5
// baseline (316.432 us; speedup 1.0000x reference)
//
#include <hip/hip_runtime.h>
#include <math.h>

// ---------------------------------------------------------------------------
// TopoGAT: 2-layer GAT on MI355X.
// R10: fixed-capacity bucket CSR build; padded CSR with rowptr/rowEnd.
// R5:  gather tables h1/g in bf16.
// R7/R12: xform = LDS-tiled GEMM, node-minor staging (conflict-free).
// R14: CSR build — k_bin at BIN_CHUNK=4096; k_fill2 512 threads + uint4
//      count pass; gCursor memset-based.
// R16/R17: k_agg1 -> 8 groups x 8 lanes, one dwordx4 gather per 8 rows,
//      weight-lane == compute-lane, 16-edge unroll. (k_agg1 left top-5.)
// R18: k_agg2 128B-padding REVERTED (it made k_agg2 VALU-bound at 69%:
//      24/64 cols per row were pad garbage = 1.6x wasted unpack+FMA and
//      1.6x gather bytes). New mapping: 12 groups x 5 lanes on unpadded
//      80B rows — zero waste, one dwordx4 gather per 12 rows. Cross-group
//      reduce = 12->6->3->1 shfl tree (strides 30/15/5+10, all = 0 mod 5).
// R19: resubmit of R18 — prior round died on container acquisition
//      (infra), not the kernel. R18's mapping is still unmeasured.
// ---------------------------------------------------------------------------

#define NBUK_MAX 512
#define BIN_CHUNK 4096
#define BUK_CAP 4608

typedef unsigned short ushort_t;

__device__ inline unsigned int f2bf(float f) {  // RNE fp32->bf16
    unsigned int u = __float_as_uint(f);
    u += 0x7FFFu + ((u >> 16) & 1u);
    return u >> 16;
}
__device__ inline float bf_lo(unsigned int u) {
    return __uint_as_float(u << 16);
}
__device__ inline float bf_hi(unsigned int u) {
    return __uint_as_float(u & 0xFFFF0000u);
}
__device__ inline float lrelu_exp(float q) {
    return __expf(q >= 0.f ? q : 0.2f * q);
}

__device__ inline int wave_incl_scan(int v, int lane) {
    #pragma unroll
    for (int ofs = 1; ofs < 64; ofs <<= 1) {
        int t = __shfl_up(v, ofs);
        if (lane >= ofs) v += t;
    }
    return v;
}

// Bin edges into fixed-capacity bucket regions of tmp. One global atomic per
// (block,bucket); packed word = (src<<8) | (dst&255). 16 edges/thread via
// int4 loads; dst stashed in registers across the reservation barrier.
__global__ __launch_bounds__(256) void k_bin(const int* __restrict__ src,
                                             const int* __restrict__ dst,
                                             int* __restrict__ gCursor,
                                             unsigned int* __restrict__ tmp,
                                             int E, int NBUK) {
    __shared__ int lcnt[NBUK_MAX];
    __shared__ int lcur[NBUK_MAX];
    int tid = threadIdx.x;
    int base = blockIdx.x * BIN_CHUNK;
    for (int i = tid; i < NBUK; i += 256) lcnt[i] = 0;
    __syncthreads();
    int d[16];
    #pragma unroll
    for (int q = 0; q < 4; q++) {
        int e = base + q * 1024 + 4 * tid;
        if (e + 3 < E) {
            int4 v = *(const int4*)&dst[e];
            d[4 * q + 0] = v.x; d[4 * q + 1] = v.y;
            d[4 * q + 2] = v.z; d[4 * q + 3] = v.w;
        } else {
            #pragma unroll
            for (int k = 0; k < 4; k++)
                d[4 * q + k] = (e + k < E) ? dst[e + k] : -1;
        }
    }
    #pragma unroll
    for (int k = 0; k < 16; k++)
        if (d[k] >= 0) atomicAdd(&lcnt[d[k] >> 8], 1);
    __syncthreads();
    for (int b = tid; b < NBUK; b += 256) {
        int c = lcnt[b];
        lcur[b] = c ? b * BUK_CAP + atomicAdd(&gCursor[b], c) : 0;
    }
    __syncthreads();
    #pragma unroll
    for (int q = 0; q < 4; q++) {
        int e = base + q * 1024 + 4 * tid;
        int s[4];
        if (e + 3 < E) {
            int4 v = *(const int4*)&src[e];
            s[0] = v.x; s[1] = v.y; s[2] = v.z; s[3] = v.w;
        } else {
            #pragma unroll
            for (int k = 0; k < 4; k++)
                s[k] = (e + k < E) ? src[e + k] : 0;
        }
        #pragma unroll
        for (int k = 0; k < 4; k++) {
            int dd = d[4 * q + k];
            if (dd >= 0) {
                int p = atomicAdd(&lcur[dd >> 8], 1);
                tmp[p] = ((unsigned int)s[k] << 8) | (unsigned int)(dd & 255);
            }
        }
    }
}

// Exact CSR fill within a bucket (padded layout, base = b*BUK_CAP).
// 512 threads; count pass reads tmp as uint4.
__global__ __launch_bounds__(512) void k_fill2(const unsigned int* __restrict__ tmp,
                                               const int* __restrict__ gCursor,
                                               int* __restrict__ rowptr,
                                               int* __restrict__ rowEnd,
                                               int* __restrict__ csr, int N) {
    __shared__ int cnt[256];
    __shared__ int cur[256];
    __shared__ int wsum[4];
    int b = blockIdx.x, tid = threadIdx.x;
    int e0 = b * BUK_CAP;
    int cnt_e = gCursor[b];       // bucket edge count
    int e1 = e0 + cnt_e;
    if (tid < 256) cnt[tid] = 0;
    __syncthreads();
    {   // count pass: uint4 over the bulk (e0 is 16B-aligned: BUK_CAP*4 % 16 == 0)
        int nq = cnt_e >> 2;
        const uint4* t4 = (const uint4*)(tmp + e0);
        for (int q = tid; q < nq; q += 512) {
            uint4 v = t4[q];
            atomicAdd(&cnt[v.x & 255u], 1);
            atomicAdd(&cnt[v.y & 255u], 1);
            atomicAdd(&cnt[v.z & 255u], 1);
            atomicAdd(&cnt[v.w & 255u], 1);
        }
        for (int i = (nq << 2) + tid; i < cnt_e; i += 512)
            atomicAdd(&cnt[tmp[e0 + i] & 255u], 1);
    }
    __syncthreads();
    if (tid < 256) {
        int lane = tid & 63, wv = tid >> 6;
        int v = cnt[tid];
        int incl = wave_incl_scan(v, lane);
        if (lane == 63) wsum[wv] = incl;
        cnt[tid] = incl - v;  // stash exclusive-within-wave
    }
    __syncthreads();
    if (tid < 256) {
        int wv = tid >> 6;
        int woff = 0;
        for (int i = 0; i < wv; i++) woff += wsum[i];
        int excl = woff + cnt[tid];
        int node = b * 256 + tid;
        int start = e0 + excl;
        cur[tid] = start;
        if (node < N) {
            rowptr[node] = start;
        }
    }
    __syncthreads();
    // rowEnd[node] = next start (cur of tid+1) or e1 for the last
    if (tid < 256) {
        int node = b * 256 + tid;
        if (node < N) rowEnd[node] = (tid < 255) ? cur[tid + 1] : e1;
    }
    __syncthreads();
    for (int i = e0 + tid; i < e1; i += 512) {
        unsigned int t = tmp[i];
        int p = atomicAdd(&cur[t & 255u], 1);
        csr[p] = (int)(t >> 8);
    }
}

// h1b[n][64](bf16) = [x[n]|topo[n]] @ W1 ; as1/ad1 from fp32 accumulators.
// Block = 64 nodes x 64 cols GEMM tile, K=136. W1 + xT staged in LDS,
// node-minor (conflict-free transpose writes).
__global__ __launch_bounds__(256) void k_xform1(const float* __restrict__ x,
                                                const float* __restrict__ topo,
                                                const float* __restrict__ W1,
                                                const float* __restrict__ asrc,
                                                const float* __restrict__ adst,
                                                ushort_t* __restrict__ h1b,
                                                float* __restrict__ as1,
                                                float* __restrict__ ad1, int N) {
    __shared__ float XT[136 * 64];  // XT[k][node]
    __shared__ float WS[136 * 64];  // WS[k][col]
    int tid = threadIdx.x;
    int n0 = blockIdx.x * 64;
    {   // stage W1: 8704 floats = 2176 float4 (once per block)
        const float4* W4 = (const float4*)W1;
        float4* WS4 = (float4*)WS;
        for (int i = tid; i < 2176; i += 256) WS4[i] = W4[i];
    }
    {   // stage x transposed, node-minor: i = k4*64 + node
        const float4* x4 = (const float4*)x;
        for (int i = tid; i < 2048; i += 256) {
            int node = i & 63, k4 = i >> 6;
            int gn = n0 + node; if (gn > N - 1) gn = N - 1;
            float4 v = x4[(size_t)gn * 32 + k4];
            int k = k4 * 4;
            XT[(k + 0) * 64 + node] = v.x;
            XT[(k + 1) * 64 + node] = v.y;
            XT[(k + 2) * 64 + node] = v.z;
            XT[(k + 3) * 64 + node] = v.w;
        }
        // topo rows 128..135: i = j4*64 + node, j4 in {0,1}
        const float4* t4 = (const float4*)topo;
        if (tid < 128) {
            int node = tid & 63, j4 = tid >> 6;
            int gn = n0 + node; if (gn > N - 1) gn = N - 1;
            float4 v = t4[(size_t)gn * 2 + j4];
            int k = 128 + j4 * 4;
            XT[(k + 0) * 64 + node] = v.x;
            XT[(k + 1) * 64 + node] = v.y;
            XT[(k + 2) * 64 + node] = v.z;
            XT[(k + 3) * 64 + node] = v.w;
        }
    }
    __syncthreads();
    int ci = tid & 15, ni = tid >> 4;
    int nb = ni * 4, cb = ci * 4;
    float acc[16];
    #pragma unroll
    for (int i = 0; i < 16; i++) acc[i] = 0.f;
    #pragma unroll 4
    for (int k = 0; k < 136; k++) {
        float4 xv = *(const float4*)&XT[k * 64 + nb];
        float4 wv = *(const float4*)&WS[k * 64 + cb];
        acc[0]  = fmaf(xv.x, wv.x, acc[0]);  acc[1]  = fmaf(xv.x, wv.y, acc[1]);
        acc[2]  = fmaf(xv.x, wv.z, acc[2]);  acc[3]  = fmaf(xv.x, wv.w, acc[3]);
        acc[4]  = fmaf(xv.y, wv.x, acc[4]);  acc[5]  = fmaf(xv.y, wv.y, acc[5]);
        acc[6]  = fmaf(xv.y, wv.z, acc[6]);  acc[7]  = fmaf(xv.y, wv.w, acc[7]);
        acc[8]  = fmaf(xv.z, wv.x, acc[8]);  acc[9]  = fmaf(xv.z, wv.y, acc[9]);
        acc[10] = fmaf(xv.z, wv.z, acc[10]); acc[11] = fmaf(xv.z, wv.w, acc[11]);
        acc[12] = fmaf(xv.w, wv.x, acc[12]); acc[13] = fmaf(xv.w, wv.y, acc[13]);
        acc[14] = fmaf(xv.w, wv.z, acc[14]); acc[15] = fmaf(xv.w, wv.w, acc[15]);
    }
    int head = cb >> 3;  // cols cb..cb+3 lie in one head (cb multiple of 4)
    #pragma unroll
    for (int i = 0; i < 4; i++) {
        int n = n0 + nb + i;
        unsigned int p0 = f2bf(acc[i * 4 + 0]) | (f2bf(acc[i * 4 + 1]) << 16);
        unsigned int p1 = f2bf(acc[i * 4 + 2]) | (f2bf(acc[i * 4 + 3]) << 16);
        if (n < N) *(uint2*)&h1b[(size_t)n * 64 + cb] = make_uint2(p0, p1);
        float s = 0.f, d = 0.f;
        #pragma unroll
        for (int j = 0; j < 4; j++) {
            s = fmaf(acc[i * 4 + j], asrc[cb + j], s);
            d = fmaf(acc[i * 4 + j], adst[cb + j], d);
        }
        s += __shfl_xor(s, 1);  // combine the two half-head threads
        d += __shfl_xor(d, 1);
        if ((ci & 1) == 0 && n < N) {
            as1[n * 8 + head] = s;
            ad1[n * 8 + head] = d;
        }
    }
}

// NOTE: parameter names W_/U_ must not collide with vector members .x/.y/.z/.w
#define AGG_FMA(W_, U_)                                           \
    {                                                             \
        acc[0] = fmaf(W_, bf_lo(U_.x), acc[0]);                   \
        acc[1] = fmaf(W_, bf_hi(U_.x), acc[1]);                   \
        acc[2] = fmaf(W_, bf_lo(U_.y), acc[2]);                   \
        acc[3] = fmaf(W_, bf_hi(U_.y), acc[3]);                   \
        acc[4] = fmaf(W_, bf_lo(U_.z), acc[4]);                   \
        acc[5] = fmaf(W_, bf_hi(U_.z), acc[5]);                   \
        acc[6] = fmaf(W_, bf_lo(U_.w), acc[6]);                   \
        acc[7] = fmaf(W_, bf_hi(U_.w), acc[7]);                   \
        z += W_;                                                  \
    }

// Per-dst softmax-weighted aggregation, layer 1 (+ implicit self loop).
// 8 groups x 8 lanes: ONE dwordx4 gather instruction moves 8 full 128B rows.
// lane = (edge_slot<<3)|head: the weight each lane computes from its as1
// gather IS the weight it consumes — zero weight shuffles. 16-edge unroll
// keeps 16 rows in flight.
__global__ __launch_bounds__(256) void k_agg1(const ushort_t* __restrict__ h1b,
                                              const float* __restrict__ as1,
                                              const float* __restrict__ ad1,
                                              const float* __restrict__ b1,
                                              const int* __restrict__ rowptr,
                                              const int* __restrict__ rowEnd,
                                              const int* __restrict__ csr,
                                              float* __restrict__ h2, int N) {
    int tid = threadIdx.x, lane = tid & 63;
    int n = blockIdx.x * 4 + (tid >> 6);
    if (n >= N) return;
    int g = lane >> 3;      // edge slot 0..7
    int head = lane & 7;    // head (cols 8h..8h+7)
    const char* h1c = (const char*)h1b;
    unsigned hoff = (unsigned)head << 4;   // 16B per head block
    float adv = ad1[n * 8 + head];
    float acc[8];
    #pragma unroll
    for (int k = 0; k < 8; k++) acc[k] = 0.f;
    float z = 0.f;
    {   // self loop (group 0 only)
        float w = lrelu_exp(as1[n * 8 + head] + adv);
        if (g == 0) {
            uint4 u = *(const uint4*)(h1c + (((unsigned)n << 7) + hoff));
            acc[0] = w * bf_lo(u.x); acc[1] = w * bf_hi(u.x);
            acc[2] = w * bf_lo(u.y); acc[3] = w * bf_hi(u.y);
            acc[4] = w * bf_lo(u.z); acc[5] = w * bf_hi(u.z);
            acc[6] = w * bf_lo(u.w); acc[7] = w * bf_hi(u.w);
            z = w;
        }
    }
    int j = rowptr[n], j1 = rowEnd[n];
    for (; j + 16 <= j1; j += 16) {   // 16 rows in flight
        int cv = csr[j + (lane & 15)];
        int se0 = __shfl(cv, g);
        int se1 = __shfl(cv, 8 + g);
        float av0 = as1[se0 * 8 + head];
        float av1 = as1[se1 * 8 + head];
        uint4 u0 = *(const uint4*)(h1c + (((unsigned)se0 << 7) + hoff));
        uint4 u1 = *(const uint4*)(h1c + (((unsigned)se1 << 7) + hoff));
        float w0 = lrelu_exp(av0 + adv);
        float w1 = lrelu_exp(av1 + adv);
        AGG_FMA(w0, u0);
        AGG_FMA(w1, u1);
    }
    if (j + 8 <= j1) {
        int cv = csr[j + (lane & 7)];
        int se = __shfl(cv, g);
        float av = as1[se * 8 + head];
        uint4 u = *(const uint4*)(h1c + (((unsigned)se << 7) + hoff));
        float w = lrelu_exp(av + adv);
        AGG_FMA(w, u);
        j += 8;
    }
    int t = j1 - j;
    if (t > 0) {  // masked tail: clamped index, zeroed weights
        int idx = (lane & 7); idx = idx < t ? idx : t - 1;
        int cv = csr[j + idx];
        int ge = g < t ? g : t - 1;
        int se = __shfl(cv, ge);
        float w = (g < t) ? lrelu_exp(as1[se * 8 + head] + adv) : 0.f;
        uint4 u = *(const uint4*)(h1c + (((unsigned)se << 7) + hoff));
        AGG_FMA(w, u);
    }
    // reduce across the 8 edge-slot groups (lanes differing in bits 3..5)
    #pragma unroll
    for (int k = 0; k < 8; k++) {
        acc[k] += __shfl_xor(acc[k], 8);
        acc[k] += __shfl_xor(acc[k], 16);
        acc[k] += __shfl_xor(acc[k], 32);
    }
    z += __shfl_xor(z, 8); z += __shfl_xor(z, 16); z += __shfl_xor(z, 32);
    if (g == 0) {
        float inv = 1.f / (z + 1e-16f);
        float o[8];
        #pragma unroll
        for (int k = 0; k < 8; k++) {
            float v = acc[k] * inv + b1[head * 8 + k];
            o[k] = v > 0.f ? v : (__expf(v) - 1.f);
        }
        float4* dp = (float4*)&h2[(size_t)n * 64 + head * 8];
        dp[0] = make_float4(o[0], o[1], o[2], o[3]);
        dp[1] = make_float4(o[4], o[5], o[6], o[7]);
    }
}

// gb[n][40](bf16) = h2[n] @ W2 ; as2/ad2 from fp32 accumulators.
// Block = 64 nodes x 40 cols GEMM tile, K=64. Node-minor staging.
__global__ __launch_bounds__(256) void k_xform2(const float* __restrict__ h2,
                                                const float* __restrict__ W2,
                                                const float* __restrict__ asrc2,
                                                const float* __restrict__ adst2,
                                                ushort_t* __restrict__ gb,
                                                float* __restrict__ as2,
                                                float* __restrict__ ad2, int N) {
    __shared__ float XT[64 * 64];  // h2T[k][node]
    __shared__ float WS[64 * 40];  // WS[k][col]
    int tid = threadIdx.x;
    int n0 = blockIdx.x * 64;
    {   // stage W2: 2560 floats = 640 float4
        const float4* W4 = (const float4*)W2;
        float4* WS4 = (float4*)WS;
        for (int i = tid; i < 640; i += 256) WS4[i] = W4[i];
    }
    {   // stage h2 transposed, node-minor: i = k4*64 + node
        const float4* h4 = (const float4*)h2;
        for (int i = tid; i < 1024; i += 256) {
            int node = i & 63, k4 = i >> 6;
            int gn = n0 + node; if (gn > N - 1) gn = N - 1;
            float4 v = h4[(size_t)gn * 16 + k4];
            int k = k4 * 4;
            XT[(k + 0) * 64 + node] = v.x;
            XT[(k + 1) * 64 + node] = v.y;
            XT[(k + 2) * 64 + node] = v.z;
            XT[(k + 3) * 64 + node] = v.w;
        }
    }
    __syncthreads();
    int ci = tid & 15, ni = tid >> 4;
    int nb = ni * 4, cb = ci * 4;
    float acc[16];
    #pragma unroll
    for (int i = 0; i < 16; i++) acc[i] = 0.f;
    if (ci < 10) {
        #pragma unroll 4
        for (int k = 0; k < 64; k++) {
            float4 xv = *(const float4*)&XT[k * 64 + nb];
            float4 wv = *(const float4*)&WS[k * 40 + cb];
            acc[0]  = fmaf(xv.x, wv.x, acc[0]);  acc[1]  = fmaf(xv.x, wv.y, acc[1]);
            acc[2]  = fmaf(xv.x, wv.z, acc[2]);  acc[3]  = fmaf(xv.x, wv.w, acc[3]);
            acc[4]  = fmaf(xv.y, wv.x, acc[4]);  acc[5]  = fmaf(xv.y, wv.y, acc[5]);
            acc[6]  = fmaf(xv.y, wv.z, acc[6]);  acc[7]  = fmaf(xv.y, wv.w, acc[7]);
            acc[8]  = fmaf(xv.z, wv.x, acc[8]);  acc[9]  = fmaf(xv.z, wv.y, acc[9]);
            acc[10] = fmaf(xv.z, wv.z, acc[10]); acc[11] = fmaf(xv.z, wv.w, acc[11]);
            acc[12] = fmaf(xv.w, wv.x, acc[12]); acc[13] = fmaf(xv.w, wv.y, acc[13]);
            acc[14] = fmaf(xv.w, wv.z, acc[14]); acc[15] = fmaf(xv.w, wv.w, acc[15]);
        }
    }
    #pragma unroll
    for (int i = 0; i < 4; i++) {
        int n = n0 + nb + i;
        if (ci < 10 && n < N) {
            unsigned int p0 = f2bf(acc[i * 4 + 0]) | (f2bf(acc[i * 4 + 1]) << 16);
            unsigned int p1 = f2bf(acc[i * 4 + 2]) | (f2bf(acc[i * 4 + 3]) << 16);
            *(uint2*)&gb[(size_t)n * 40 + cb] = make_uint2(p0, p1);  // 80B rows
        }
        float s = 0.f, d = 0.f;
        if (ci < 10) {
            #pragma unroll
            for (int j = 0; j < 4; j++) {
                s = fmaf(acc[i * 4 + j], asrc2[cb + j], s);
                d = fmaf(acc[i * 4 + j], adst2[cb + j], d);
            }
        }
        // reduce over the 16-lane ci group (ci>=10 contribute 0)
        s += __shfl_xor(s, 1); s += __shfl_xor(s, 2);
        s += __shfl_xor(s, 4); s += __shfl_xor(s, 8);
        d += __shfl_xor(d, 1); d += __shfl_xor(d, 2);
        d += __shfl_xor(d, 4); d += __shfl_xor(d, 8);
        if (ci == 0 && n < N) { as2[n] = s; ad2[n] = d; }
    }
}

// Layer-2 aggregation + bias + log_softmax.
// 12 groups x 5 lanes on unpadded 80B rows: one dwordx4 gather moves 12 rows,
// every gathered byte is real (no pad waste). Each lane's as2 load is its own
// group's weight (5-way redundant, L1 broadcast). Cross-group reduce:
// 12->6->3->1 shfl tree with strides 30/15/{5,10} (all multiples of 5, so the
// column block p is preserved). Lanes 60-63 duplicate (g=11,p=4); unread.
__global__ __launch_bounds__(256) void k_agg2(const ushort_t* __restrict__ gb,
                                              const float* __restrict__ as2,
                                              const float* __restrict__ ad2,
                                              const float* __restrict__ b2,
                                              const int* __restrict__ rowptr,
                                              const int* __restrict__ rowEnd,
                                              const int* __restrict__ csr,
                                              float* __restrict__ out, int N) {
    int tid = threadIdx.x, lane = tid & 63;
    int n = blockIdx.x * 4 + (tid >> 6);
    if (n >= N) return;
    int g = lane / 5; if (g > 11) g = 11;   // edge slot 0..11
    int p = lane - g * 5; if (p > 4) p = 4; // col block (8p..8p+7)
    const char* gbc = (const char*)gb;
    unsigned poff = (unsigned)p << 4;       // 16B per col block
    int lm12 = lane % 12;
    float add = ad2[n];
    float acc[8];
    #pragma unroll
    for (int k = 0; k < 8; k++) acc[k] = 0.f;
    float z = 0.f;
    {   // self loop (group 0 only)
        float w = lrelu_exp(as2[n] + add);
        if (g == 0) {
            uint4 u = *(const uint4*)(gbc + ((unsigned)n * 80u + poff));
            acc[0] = w * bf_lo(u.x); acc[1] = w * bf_hi(u.x);
            acc[2] = w * bf_lo(u.y); acc[3] = w * bf_hi(u.y);
            acc[4] = w * bf_lo(u.z); acc[5] = w * bf_hi(u.z);
            acc[6] = w * bf_lo(u.w); acc[7] = w * bf_hi(u.w);
            z = w;
        }
    }
    int j = rowptr[n], j1 = rowEnd[n];
    for (; j + 24 <= j1; j += 24) {   // 24 rows in flight
        int cv0 = csr[j + lm12];
        int cv1 = csr[j + 12 + lm12];
        int se0 = __shfl(cv0, g);
        int se1 = __shfl(cv1, g);
        float av0 = as2[se0];
        float av1 = as2[se1];
        uint4 u0 = *(const uint4*)(gbc + ((unsigned)se0 * 80u + poff));
        uint4 u1 = *(const uint4*)(gbc + ((unsigned)se1 * 80u + poff));
        float w0 = lrelu_exp(av0 + add);
        float w1 = lrelu_exp(av1 + add);
        AGG_FMA(w0, u0);
        AGG_FMA(w1, u1);
    }
    if (j + 12 <= j1) {
        int cv = csr[j + lm12];
        int se = __shfl(cv, g);
        float av = as2[se];
        uint4 u = *(const uint4*)(gbc + ((unsigned)se * 80u + poff));
        float w = lrelu_exp(av + add);
        AGG_FMA(w, u);
        j += 12;
    }
    int t = j1 - j;
    if (t > 0) {  // masked tail (t in 1..11): clamped index, zeroed weights
        int idx = lm12 < t ? lm12 : t - 1;
        int cv = csr[j + idx];
        int ge = g < t ? g : t - 1;
        int se = __shfl(cv, ge);
        float w = (g < t) ? lrelu_exp(as2[se] + add) : 0.f;
        uint4 u = *(const uint4*)(gbc + ((unsigned)se * 80u + poff));
        AGG_FMA(w, u);
    }
    // 12-group tree reduce onto lanes 0..4 (strides preserve p: 30,15,5,10)
    #pragma unroll
    for (int k = 0; k < 8; k++) {
        float v = acc[k];
        v += __shfl(v, lane + 30);
        v += __shfl(v, lane + 15);
        v += __shfl(v, lane + 5) + __shfl(v, lane + 10);
        acc[k] = v;
    }
    {
        float v = z;
        v += __shfl(v, lane + 30);
        v += __shfl(v, lane + 15);
        v += __shfl(v, lane + 5) + __shfl(v, lane + 10);
        z = v;
    }
    // epilogue on lanes 0..4 (p==lane); butterfly over the 8-lane xor group
    bool act = (lane < 5);
    float l[8];
    float mv = -INFINITY;
    if (act) {
        float inv = 1.f / (z + 1e-16f);
        #pragma unroll
        for (int k = 0; k < 8; k++) {
            l[k] = acc[k] * inv + b2[lane * 8 + k];
            mv = fmaxf(mv, l[k]);
        }
    }
    mv = fmaxf(mv, __shfl_xor(mv, 1));
    mv = fmaxf(mv, __shfl_xor(mv, 2));
    mv = fmaxf(mv, __shfl_xor(mv, 4));
    float ev = 0.f;
    if (act) {
        #pragma unroll
        for (int k = 0; k < 8; k++) ev += __expf(l[k] - mv);
    }
    ev += __shfl_xor(ev, 1);
    ev += __shfl_xor(ev, 2);
    ev += __shfl_xor(ev, 4);
    if (act) {
        float ls = mv + __logf(ev);
        float4* dp = (float4*)&out[(size_t)n * 40 + lane * 8];
        dp[0] = make_float4(l[0] - ls, l[1] - ls, l[2] - ls, l[3] - ls);
        dp[1] = make_float4(l[4] - ls, l[5] - ls, l[6] - ls, l[7] - ls);
    }
}

extern "C" void kernel_launch(void* const* d_in, const int* in_sizes, int n_in,
                              void* d_out, int out_size, void* d_ws, size_t ws_size,
                              hipStream_t stream) {
    const float* x    = (const float*)d_in[0];
    const float* topo = (const float*)d_in[1];
    const int*   ei   = (const int*)d_in[2];
    const float* W1   = (const float*)d_in[3];
    const float* a_s1 = (const float*)d_in[4];
    const float* a_d1 = (const float*)d_in[5];
    const float* b1   = (const float*)d_in[6];
    const float* W2   = (const float*)d_in[7];
    const float* a_s2 = (const float*)d_in[8];
    const float* a_d2 = (const float*)d_in[9];
    const float* b2   = (const float*)d_in[10];
    float* out = (float*)d_out;

    int N = in_sizes[0] / 128;
    int E = in_sizes[2] / 2;
    const int* esrc = ei;
    const int* edst = ei + E;
    int NBUK = (N + 255) / 256;
    size_t cap = (size_t)NBUK * BUK_CAP;

    char* ws = (char*)d_ws;
    size_t off = 0;
    auto alloc = [&](size_t bytes) -> void* {
        void* p = ws + off;
        off = (off + bytes + 255) & ~(size_t)255;
        return p;
    };
    ushort_t* h1b  = (ushort_t*)alloc((size_t)N * 64 * 2);
    float* as1     = (float*)alloc((size_t)N * 8 * 4);
    float* ad1     = (float*)alloc((size_t)N * 8 * 4);
    float* h2      = (float*)alloc((size_t)N * 64 * 4);
    ushort_t* gb   = (ushort_t*)alloc((size_t)N * 40 * 2);  // 80B rows
    float* as2     = (float*)alloc((size_t)N * 4);
    float* ad2     = (float*)alloc((size_t)N * 4);
    int*   rowptr  = (int*)alloc((size_t)N * 4);
    int*   rowEnd  = (int*)alloc((size_t)N * 4);
    int*   csr     = (int*)alloc(cap * 4);
    unsigned int* tmp = (unsigned int*)alloc(cap * 4);
    int* gCursor   = (int*)alloc((size_t)NBUK * 4);

    hipMemsetAsync(gCursor, 0, (size_t)NBUK * 4, stream);  // count-based cursors
    int nbin = (E + BIN_CHUNK - 1) / BIN_CHUNK;
    k_bin<<<nbin, 256, 0, stream>>>(esrc, edst, gCursor, tmp, E, NBUK);
    k_fill2<<<NBUK, 512, 0, stream>>>(tmp, gCursor, rowptr, rowEnd, csr, N);

    int nbg = (N + 63) / 64;  // 64-node GEMM tiles
    int nb4 = (N + 3) / 4;    // 1 node/wave x 4 waves/block
    k_xform1<<<nbg, 256, 0, stream>>>(x, topo, W1, a_s1, a_d1, h1b, as1, ad1, N);
    k_agg1<<<nb4, 256, 0, stream>>>(h1b, as1, ad1, b1, rowptr, rowEnd, csr, h2, N);
    k_xform2<<<nbg, 256, 0, stream>>>(h2, W2, a_s2, a_d2, gb, as2, ad2, N);
    k_agg2<<<nb4, 256, 0, stream>>>(gb, as2, ad2, b2, rowptr, rowEnd, csr, out, N);
}

// Round 6
// 308.834 us; speedup vs baseline: 1.0246x; 1.0246x over previous
//
#include <hip/hip_runtime.h>
#include <math.h>

// ---------------------------------------------------------------------------
// TopoGAT: 2-layer GAT on MI355X.
// R10: fixed-capacity bucket CSR build; padded CSR with rowptr/rowEnd.
// R5:  gather tables h1/g in bf16.
// R7/R12: xform = LDS-tiled GEMM, node-minor staging (conflict-free).
// R14: CSR build — k_bin at BIN_CHUNK=4096; k_fill2 512 threads + uint4
//      count pass; gCursor memset-based.
// R16/R17: k_agg1 -> 8 groups x 8 lanes, one dwordx4 gather per 8 rows,
//      weight-lane == compute-lane, 16-edge unroll. Measured ~47us (was 61).
// R18: k_agg2 12x5-uint4 experiment: 66.4us — REGRESSED vs R16's 62.4 and
//      R1's ~46. Lesson (with R16): at avg degree ~16, k_agg2's per-NODE
//      fixed cost (8-acc shfl-tree reduce + 8-exp epilogue + uint4 self
//      loop) outweighs per-edge gather efficiency. The 40-col layer wants
//      the cheap-reduce mapping.
// R20: k_agg2 restored to the R1-verified 3 groups x 20 lanes dword mapping
//      (measured ~46us inside the 311us baseline). k_agg1 stays at R16/R17.
//      Both components individually harness-verified.
// ---------------------------------------------------------------------------

#define NBUK_MAX 512
#define BIN_CHUNK 4096
#define BUK_CAP 4608

typedef unsigned short ushort_t;

__device__ inline unsigned int f2bf(float f) {  // RNE fp32->bf16
    unsigned int u = __float_as_uint(f);
    u += 0x7FFFu + ((u >> 16) & 1u);
    return u >> 16;
}
__device__ inline float bf_lo(unsigned int u) {
    return __uint_as_float(u << 16);
}
__device__ inline float bf_hi(unsigned int u) {
    return __uint_as_float(u & 0xFFFF0000u);
}
__device__ inline float lrelu_exp(float q) {
    return __expf(q >= 0.f ? q : 0.2f * q);
}

__device__ inline int wave_incl_scan(int v, int lane) {
    #pragma unroll
    for (int ofs = 1; ofs < 64; ofs <<= 1) {
        int t = __shfl_up(v, ofs);
        if (lane >= ofs) v += t;
    }
    return v;
}

// Bin edges into fixed-capacity bucket regions of tmp. One global atomic per
// (block,bucket); packed word = (src<<8) | (dst&255). 16 edges/thread via
// int4 loads; dst stashed in registers across the reservation barrier.
__global__ __launch_bounds__(256) void k_bin(const int* __restrict__ src,
                                             const int* __restrict__ dst,
                                             int* __restrict__ gCursor,
                                             unsigned int* __restrict__ tmp,
                                             int E, int NBUK) {
    __shared__ int lcnt[NBUK_MAX];
    __shared__ int lcur[NBUK_MAX];
    int tid = threadIdx.x;
    int base = blockIdx.x * BIN_CHUNK;
    for (int i = tid; i < NBUK; i += 256) lcnt[i] = 0;
    __syncthreads();
    int d[16];
    #pragma unroll
    for (int q = 0; q < 4; q++) {
        int e = base + q * 1024 + 4 * tid;
        if (e + 3 < E) {
            int4 v = *(const int4*)&dst[e];
            d[4 * q + 0] = v.x; d[4 * q + 1] = v.y;
            d[4 * q + 2] = v.z; d[4 * q + 3] = v.w;
        } else {
            #pragma unroll
            for (int k = 0; k < 4; k++)
                d[4 * q + k] = (e + k < E) ? dst[e + k] : -1;
        }
    }
    #pragma unroll
    for (int k = 0; k < 16; k++)
        if (d[k] >= 0) atomicAdd(&lcnt[d[k] >> 8], 1);
    __syncthreads();
    for (int b = tid; b < NBUK; b += 256) {
        int c = lcnt[b];
        lcur[b] = c ? b * BUK_CAP + atomicAdd(&gCursor[b], c) : 0;
    }
    __syncthreads();
    #pragma unroll
    for (int q = 0; q < 4; q++) {
        int e = base + q * 1024 + 4 * tid;
        int s[4];
        if (e + 3 < E) {
            int4 v = *(const int4*)&src[e];
            s[0] = v.x; s[1] = v.y; s[2] = v.z; s[3] = v.w;
        } else {
            #pragma unroll
            for (int k = 0; k < 4; k++)
                s[k] = (e + k < E) ? src[e + k] : 0;
        }
        #pragma unroll
        for (int k = 0; k < 4; k++) {
            int dd = d[4 * q + k];
            if (dd >= 0) {
                int p = atomicAdd(&lcur[dd >> 8], 1);
                tmp[p] = ((unsigned int)s[k] << 8) | (unsigned int)(dd & 255);
            }
        }
    }
}

// Exact CSR fill within a bucket (padded layout, base = b*BUK_CAP).
// 512 threads; count pass reads tmp as uint4.
__global__ __launch_bounds__(512) void k_fill2(const unsigned int* __restrict__ tmp,
                                               const int* __restrict__ gCursor,
                                               int* __restrict__ rowptr,
                                               int* __restrict__ rowEnd,
                                               int* __restrict__ csr, int N) {
    __shared__ int cnt[256];
    __shared__ int cur[256];
    __shared__ int wsum[4];
    int b = blockIdx.x, tid = threadIdx.x;
    int e0 = b * BUK_CAP;
    int cnt_e = gCursor[b];       // bucket edge count
    int e1 = e0 + cnt_e;
    if (tid < 256) cnt[tid] = 0;
    __syncthreads();
    {   // count pass: uint4 over the bulk (e0 is 16B-aligned: BUK_CAP*4 % 16 == 0)
        int nq = cnt_e >> 2;
        const uint4* t4 = (const uint4*)(tmp + e0);
        for (int q = tid; q < nq; q += 512) {
            uint4 v = t4[q];
            atomicAdd(&cnt[v.x & 255u], 1);
            atomicAdd(&cnt[v.y & 255u], 1);
            atomicAdd(&cnt[v.z & 255u], 1);
            atomicAdd(&cnt[v.w & 255u], 1);
        }
        for (int i = (nq << 2) + tid; i < cnt_e; i += 512)
            atomicAdd(&cnt[tmp[e0 + i] & 255u], 1);
    }
    __syncthreads();
    if (tid < 256) {
        int lane = tid & 63, wv = tid >> 6;
        int v = cnt[tid];
        int incl = wave_incl_scan(v, lane);
        if (lane == 63) wsum[wv] = incl;
        cnt[tid] = incl - v;  // stash exclusive-within-wave
    }
    __syncthreads();
    if (tid < 256) {
        int wv = tid >> 6;
        int woff = 0;
        for (int i = 0; i < wv; i++) woff += wsum[i];
        int excl = woff + cnt[tid];
        int node = b * 256 + tid;
        int start = e0 + excl;
        cur[tid] = start;
        if (node < N) {
            rowptr[node] = start;
        }
    }
    __syncthreads();
    // rowEnd[node] = next start (cur of tid+1) or e1 for the last
    if (tid < 256) {
        int node = b * 256 + tid;
        if (node < N) rowEnd[node] = (tid < 255) ? cur[tid + 1] : e1;
    }
    __syncthreads();
    for (int i = e0 + tid; i < e1; i += 512) {
        unsigned int t = tmp[i];
        int p = atomicAdd(&cur[t & 255u], 1);
        csr[p] = (int)(t >> 8);
    }
}

// h1b[n][64](bf16) = [x[n]|topo[n]] @ W1 ; as1/ad1 from fp32 accumulators.
// Block = 64 nodes x 64 cols GEMM tile, K=136. W1 + xT staged in LDS,
// node-minor (conflict-free transpose writes).
__global__ __launch_bounds__(256) void k_xform1(const float* __restrict__ x,
                                                const float* __restrict__ topo,
                                                const float* __restrict__ W1,
                                                const float* __restrict__ asrc,
                                                const float* __restrict__ adst,
                                                ushort_t* __restrict__ h1b,
                                                float* __restrict__ as1,
                                                float* __restrict__ ad1, int N) {
    __shared__ float XT[136 * 64];  // XT[k][node]
    __shared__ float WS[136 * 64];  // WS[k][col]
    int tid = threadIdx.x;
    int n0 = blockIdx.x * 64;
    {   // stage W1: 8704 floats = 2176 float4 (once per block)
        const float4* W4 = (const float4*)W1;
        float4* WS4 = (float4*)WS;
        for (int i = tid; i < 2176; i += 256) WS4[i] = W4[i];
    }
    {   // stage x transposed, node-minor: i = k4*64 + node
        const float4* x4 = (const float4*)x;
        for (int i = tid; i < 2048; i += 256) {
            int node = i & 63, k4 = i >> 6;
            int gn = n0 + node; if (gn > N - 1) gn = N - 1;
            float4 v = x4[(size_t)gn * 32 + k4];
            int k = k4 * 4;
            XT[(k + 0) * 64 + node] = v.x;
            XT[(k + 1) * 64 + node] = v.y;
            XT[(k + 2) * 64 + node] = v.z;
            XT[(k + 3) * 64 + node] = v.w;
        }
        // topo rows 128..135: i = j4*64 + node, j4 in {0,1}
        const float4* t4 = (const float4*)topo;
        if (tid < 128) {
            int node = tid & 63, j4 = tid >> 6;
            int gn = n0 + node; if (gn > N - 1) gn = N - 1;
            float4 v = t4[(size_t)gn * 2 + j4];
            int k = 128 + j4 * 4;
            XT[(k + 0) * 64 + node] = v.x;
            XT[(k + 1) * 64 + node] = v.y;
            XT[(k + 2) * 64 + node] = v.z;
            XT[(k + 3) * 64 + node] = v.w;
        }
    }
    __syncthreads();
    int ci = tid & 15, ni = tid >> 4;
    int nb = ni * 4, cb = ci * 4;
    float acc[16];
    #pragma unroll
    for (int i = 0; i < 16; i++) acc[i] = 0.f;
    #pragma unroll 4
    for (int k = 0; k < 136; k++) {
        float4 xv = *(const float4*)&XT[k * 64 + nb];
        float4 wv = *(const float4*)&WS[k * 64 + cb];
        acc[0]  = fmaf(xv.x, wv.x, acc[0]);  acc[1]  = fmaf(xv.x, wv.y, acc[1]);
        acc[2]  = fmaf(xv.x, wv.z, acc[2]);  acc[3]  = fmaf(xv.x, wv.w, acc[3]);
        acc[4]  = fmaf(xv.y, wv.x, acc[4]);  acc[5]  = fmaf(xv.y, wv.y, acc[5]);
        acc[6]  = fmaf(xv.y, wv.z, acc[6]);  acc[7]  = fmaf(xv.y, wv.w, acc[7]);
        acc[8]  = fmaf(xv.z, wv.x, acc[8]);  acc[9]  = fmaf(xv.z, wv.y, acc[9]);
        acc[10] = fmaf(xv.z, wv.z, acc[10]); acc[11] = fmaf(xv.z, wv.w, acc[11]);
        acc[12] = fmaf(xv.w, wv.x, acc[12]); acc[13] = fmaf(xv.w, wv.y, acc[13]);
        acc[14] = fmaf(xv.w, wv.z, acc[14]); acc[15] = fmaf(xv.w, wv.w, acc[15]);
    }
    int head = cb >> 3;  // cols cb..cb+3 lie in one head (cb multiple of 4)
    #pragma unroll
    for (int i = 0; i < 4; i++) {
        int n = n0 + nb + i;
        unsigned int p0 = f2bf(acc[i * 4 + 0]) | (f2bf(acc[i * 4 + 1]) << 16);
        unsigned int p1 = f2bf(acc[i * 4 + 2]) | (f2bf(acc[i * 4 + 3]) << 16);
        if (n < N) *(uint2*)&h1b[(size_t)n * 64 + cb] = make_uint2(p0, p1);
        float s = 0.f, d = 0.f;
        #pragma unroll
        for (int j = 0; j < 4; j++) {
            s = fmaf(acc[i * 4 + j], asrc[cb + j], s);
            d = fmaf(acc[i * 4 + j], adst[cb + j], d);
        }
        s += __shfl_xor(s, 1);  // combine the two half-head threads
        d += __shfl_xor(d, 1);
        if ((ci & 1) == 0 && n < N) {
            as1[n * 8 + head] = s;
            ad1[n * 8 + head] = d;
        }
    }
}

// NOTE: parameter names W_/U_ must not collide with vector members .x/.y/.z/.w
#define AGG_FMA(W_, U_)                                           \
    {                                                             \
        acc[0] = fmaf(W_, bf_lo(U_.x), acc[0]);                   \
        acc[1] = fmaf(W_, bf_hi(U_.x), acc[1]);                   \
        acc[2] = fmaf(W_, bf_lo(U_.y), acc[2]);                   \
        acc[3] = fmaf(W_, bf_hi(U_.y), acc[3]);                   \
        acc[4] = fmaf(W_, bf_lo(U_.z), acc[4]);                   \
        acc[5] = fmaf(W_, bf_hi(U_.z), acc[5]);                   \
        acc[6] = fmaf(W_, bf_lo(U_.w), acc[6]);                   \
        acc[7] = fmaf(W_, bf_hi(U_.w), acc[7]);                   \
        z += W_;                                                  \
    }

// Per-dst softmax-weighted aggregation, layer 1 (+ implicit self loop).
// 8 groups x 8 lanes: ONE dwordx4 gather instruction moves 8 full 128B rows.
// lane = (edge_slot<<3)|head: the weight each lane computes from its as1
// gather IS the weight it consumes — zero weight shuffles. 16-edge unroll
// keeps 16 rows in flight.
__global__ __launch_bounds__(256) void k_agg1(const ushort_t* __restrict__ h1b,
                                              const float* __restrict__ as1,
                                              const float* __restrict__ ad1,
                                              const float* __restrict__ b1,
                                              const int* __restrict__ rowptr,
                                              const int* __restrict__ rowEnd,
                                              const int* __restrict__ csr,
                                              float* __restrict__ h2, int N) {
    int tid = threadIdx.x, lane = tid & 63;
    int n = blockIdx.x * 4 + (tid >> 6);
    if (n >= N) return;
    int g = lane >> 3;      // edge slot 0..7
    int head = lane & 7;    // head (cols 8h..8h+7)
    const char* h1c = (const char*)h1b;
    unsigned hoff = (unsigned)head << 4;   // 16B per head block
    float adv = ad1[n * 8 + head];
    float acc[8];
    #pragma unroll
    for (int k = 0; k < 8; k++) acc[k] = 0.f;
    float z = 0.f;
    {   // self loop (group 0 only)
        float w = lrelu_exp(as1[n * 8 + head] + adv);
        if (g == 0) {
            uint4 u = *(const uint4*)(h1c + (((unsigned)n << 7) + hoff));
            acc[0] = w * bf_lo(u.x); acc[1] = w * bf_hi(u.x);
            acc[2] = w * bf_lo(u.y); acc[3] = w * bf_hi(u.y);
            acc[4] = w * bf_lo(u.z); acc[5] = w * bf_hi(u.z);
            acc[6] = w * bf_lo(u.w); acc[7] = w * bf_hi(u.w);
            z = w;
        }
    }
    int j = rowptr[n], j1 = rowEnd[n];
    for (; j + 16 <= j1; j += 16) {   // 16 rows in flight
        int cv = csr[j + (lane & 15)];
        int se0 = __shfl(cv, g);
        int se1 = __shfl(cv, 8 + g);
        float av0 = as1[se0 * 8 + head];
        float av1 = as1[se1 * 8 + head];
        uint4 u0 = *(const uint4*)(h1c + (((unsigned)se0 << 7) + hoff));
        uint4 u1 = *(const uint4*)(h1c + (((unsigned)se1 << 7) + hoff));
        float w0 = lrelu_exp(av0 + adv);
        float w1 = lrelu_exp(av1 + adv);
        AGG_FMA(w0, u0);
        AGG_FMA(w1, u1);
    }
    if (j + 8 <= j1) {
        int cv = csr[j + (lane & 7)];
        int se = __shfl(cv, g);
        float av = as1[se * 8 + head];
        uint4 u = *(const uint4*)(h1c + (((unsigned)se << 7) + hoff));
        float w = lrelu_exp(av + adv);
        AGG_FMA(w, u);
        j += 8;
    }
    int t = j1 - j;
    if (t > 0) {  // masked tail: clamped index, zeroed weights
        int idx = (lane & 7); idx = idx < t ? idx : t - 1;
        int cv = csr[j + idx];
        int ge = g < t ? g : t - 1;
        int se = __shfl(cv, ge);
        float w = (g < t) ? lrelu_exp(as1[se * 8 + head] + adv) : 0.f;
        uint4 u = *(const uint4*)(h1c + (((unsigned)se << 7) + hoff));
        AGG_FMA(w, u);
    }
    // reduce across the 8 edge-slot groups (lanes differing in bits 3..5)
    #pragma unroll
    for (int k = 0; k < 8; k++) {
        acc[k] += __shfl_xor(acc[k], 8);
        acc[k] += __shfl_xor(acc[k], 16);
        acc[k] += __shfl_xor(acc[k], 32);
    }
    z += __shfl_xor(z, 8); z += __shfl_xor(z, 16); z += __shfl_xor(z, 32);
    if (g == 0) {
        float inv = 1.f / (z + 1e-16f);
        float o[8];
        #pragma unroll
        for (int k = 0; k < 8; k++) {
            float v = acc[k] * inv + b1[head * 8 + k];
            o[k] = v > 0.f ? v : (__expf(v) - 1.f);
        }
        float4* dp = (float4*)&h2[(size_t)n * 64 + head * 8];
        dp[0] = make_float4(o[0], o[1], o[2], o[3]);
        dp[1] = make_float4(o[4], o[5], o[6], o[7]);
    }
}

// gb[n][40](bf16) = h2[n] @ W2 ; as2/ad2 from fp32 accumulators.
// Block = 64 nodes x 40 cols GEMM tile, K=64. Node-minor staging.
__global__ __launch_bounds__(256) void k_xform2(const float* __restrict__ h2,
                                                const float* __restrict__ W2,
                                                const float* __restrict__ asrc2,
                                                const float* __restrict__ adst2,
                                                ushort_t* __restrict__ gb,
                                                float* __restrict__ as2,
                                                float* __restrict__ ad2, int N) {
    __shared__ float XT[64 * 64];  // h2T[k][node]
    __shared__ float WS[64 * 40];  // WS[k][col]
    int tid = threadIdx.x;
    int n0 = blockIdx.x * 64;
    {   // stage W2: 2560 floats = 640 float4
        const float4* W4 = (const float4*)W2;
        float4* WS4 = (float4*)WS;
        for (int i = tid; i < 640; i += 256) WS4[i] = W4[i];
    }
    {   // stage h2 transposed, node-minor: i = k4*64 + node
        const float4* h4 = (const float4*)h2;
        for (int i = tid; i < 1024; i += 256) {
            int node = i & 63, k4 = i >> 6;
            int gn = n0 + node; if (gn > N - 1) gn = N - 1;
            float4 v = h4[(size_t)gn * 16 + k4];
            int k = k4 * 4;
            XT[(k + 0) * 64 + node] = v.x;
            XT[(k + 1) * 64 + node] = v.y;
            XT[(k + 2) * 64 + node] = v.z;
            XT[(k + 3) * 64 + node] = v.w;
        }
    }
    __syncthreads();
    int ci = tid & 15, ni = tid >> 4;
    int nb = ni * 4, cb = ci * 4;
    float acc[16];
    #pragma unroll
    for (int i = 0; i < 16; i++) acc[i] = 0.f;
    if (ci < 10) {
        #pragma unroll 4
        for (int k = 0; k < 64; k++) {
            float4 xv = *(const float4*)&XT[k * 64 + nb];
            float4 wv = *(const float4*)&WS[k * 40 + cb];
            acc[0]  = fmaf(xv.x, wv.x, acc[0]);  acc[1]  = fmaf(xv.x, wv.y, acc[1]);
            acc[2]  = fmaf(xv.x, wv.z, acc[2]);  acc[3]  = fmaf(xv.x, wv.w, acc[3]);
            acc[4]  = fmaf(xv.y, wv.x, acc[4]);  acc[5]  = fmaf(xv.y, wv.y, acc[5]);
            acc[6]  = fmaf(xv.y, wv.z, acc[6]);  acc[7]  = fmaf(xv.y, wv.w, acc[7]);
            acc[8]  = fmaf(xv.z, wv.x, acc[8]);  acc[9]  = fmaf(xv.z, wv.y, acc[9]);
            acc[10] = fmaf(xv.z, wv.z, acc[10]); acc[11] = fmaf(xv.z, wv.w, acc[11]);
            acc[12] = fmaf(xv.w, wv.x, acc[12]); acc[13] = fmaf(xv.w, wv.y, acc[13]);
            acc[14] = fmaf(xv.w, wv.z, acc[14]); acc[15] = fmaf(xv.w, wv.w, acc[15]);
        }
    }
    #pragma unroll
    for (int i = 0; i < 4; i++) {
        int n = n0 + nb + i;
        if (ci < 10 && n < N) {
            unsigned int p0 = f2bf(acc[i * 4 + 0]) | (f2bf(acc[i * 4 + 1]) << 16);
            unsigned int p1 = f2bf(acc[i * 4 + 2]) | (f2bf(acc[i * 4 + 3]) << 16);
            *(uint2*)&gb[(size_t)n * 40 + cb] = make_uint2(p0, p1);  // 80B rows
        }
        float s = 0.f, d = 0.f;
        if (ci < 10) {
            #pragma unroll
            for (int j = 0; j < 4; j++) {
                s = fmaf(acc[i * 4 + j], asrc2[cb + j], s);
                d = fmaf(acc[i * 4 + j], adst2[cb + j], d);
            }
        }
        // reduce over the 16-lane ci group (ci>=10 contribute 0)
        s += __shfl_xor(s, 1); s += __shfl_xor(s, 2);
        s += __shfl_xor(s, 4); s += __shfl_xor(s, 8);
        d += __shfl_xor(d, 1); d += __shfl_xor(d, 2);
        d += __shfl_xor(d, 4); d += __shfl_xor(d, 8);
        if (ci == 0 && n < N) { as2[n] = s; ad2[n] = d; }
    }
}

// Layer-2 aggregation + bias + log_softmax. (R1-verified mapping.)
// 3 groups x 20 lanes -> THREE 80B rows per gather instruction.
// ONE as2 load + ONE exp per 12-edge chunk; weights via shfl.
// Cheap per-node fixed cost: 2-shfl reduce per value, 2-exp epilogue.
__global__ __launch_bounds__(256) void k_agg2(const ushort_t* __restrict__ gb,
                                              const float* __restrict__ as2,
                                              const float* __restrict__ ad2,
                                              const float* __restrict__ b2,
                                              const int* __restrict__ rowptr,
                                              const int* __restrict__ rowEnd,
                                              const int* __restrict__ csr,
                                              float* __restrict__ out, int N) {
    int tid = threadIdx.x, lane = tid & 63;
    int n = blockIdx.x * 4 + (tid >> 6);
    if (n >= N) return;
    int g = lane / 20, p = lane % 20;  // g==3 for lanes 60-63 (results unread)
    int c0 = 2 * p;
    const char* gbc = (const char*)gb;
    unsigned coff = (unsigned)(p << 2);
    int lm12 = lane % 12;
    float add = ad2[n];
    float acc0 = 0.f, acc1 = 0.f, zl = 0.f;
    {   // self loop (group 0 only)
        float e0 = as2[n] + add;
        float w = lrelu_exp(e0);
        if (g == 0) {
            unsigned int u = *(const unsigned int*)(gbc + ((unsigned)n * 80u + coff));
            acc0 = w * bf_lo(u); acc1 = w * bf_hi(u); zl = w;
        }
    }
    int j0 = rowptr[n], j1 = rowEnd[n];
    int j = j0;
    int gi0 = (0 + g) < 12 ? (0 + g) : 11;   // clamp for g==3 lanes
    int gi1 = (3 + g) < 12 ? (3 + g) : 11;
    int gi2 = (6 + g) < 12 ? (6 + g) : 11;
    int gi3 = (9 + g) < 12 ? (9 + g) : 11;
    for (; j + 12 <= j1; j += 12) {
        int cv = csr[j + lm12];          // coalesced, then bpermute
        float av = as2[cv];
        float wall = lrelu_exp(av + add);
        int s0 = __shfl(cv, gi0);
        int s1 = __shfl(cv, gi1);
        int s2 = __shfl(cv, gi2);
        int s3 = __shfl(cv, gi3);
        unsigned int u0 = *(const unsigned int*)(gbc + ((unsigned)s0 * 80u + coff));
        unsigned int u1 = *(const unsigned int*)(gbc + ((unsigned)s1 * 80u + coff));
        unsigned int u2 = *(const unsigned int*)(gbc + ((unsigned)s2 * 80u + coff));
        unsigned int u3 = *(const unsigned int*)(gbc + ((unsigned)s3 * 80u + coff));
        float w0 = __shfl(wall, gi0);
        float w1 = __shfl(wall, gi1);
        float w2 = __shfl(wall, gi2);
        float w3 = __shfl(wall, gi3);
        acc0 = fmaf(w0, bf_lo(u0), acc0); acc1 = fmaf(w0, bf_hi(u0), acc1); zl += w0;
        acc0 = fmaf(w1, bf_lo(u1), acc0); acc1 = fmaf(w1, bf_hi(u1), acc1); zl += w1;
        acc0 = fmaf(w2, bf_lo(u2), acc0); acc1 = fmaf(w2, bf_hi(u2), acc1); zl += w2;
        acc0 = fmaf(w3, bf_lo(u3), acc0); acc1 = fmaf(w3, bf_hi(u3), acc1); zl += w3;
    }
    int t = j1 - j;
    if (t > 0) {  // masked 12-wide tail (t in 1..11 -> lane 11's wall is 0)
        int idx = lm12 < t ? lm12 : t - 1;
        int cv = csr[j + idx];
        float av = as2[cv];
        float wall = (lm12 < t) ? lrelu_exp(av + add) : 0.f;
        #pragma unroll
        for (int i = 0; i < 4; i++) {
            int e = 3 * i + g;
            int gi = e < 12 ? e : 11;
            int s = __shfl(cv, gi);
            unsigned int u = *(const unsigned int*)(gbc + ((unsigned)s * 80u + coff));
            float w = __shfl(wall, gi);  // 0 for e >= t
            acc0 = fmaf(w, bf_lo(u), acc0); acc1 = fmaf(w, bf_hi(u), acc1); zl += w;
        }
    }
    // combine the 3 groups (valid at lanes 0..19)
    float A0 = acc0 + __shfl(acc0, (lane + 20) & 63) + __shfl(acc0, (lane + 40) & 63);
    float A1 = acc1 + __shfl(acc1, (lane + 20) & 63) + __shfl(acc1, (lane + 40) & 63);
    float Z  = zl + __shfl(zl, (lane + 20) & 63) + __shfl(zl, (lane + 40) & 63);
    float l0 = 0.f, l1 = 0.f;
    bool active = (lane < 20);
    if (active) {
        float inv = 1.f / (Z + 1e-16f);
        l0 = A0 * inv + b2[c0];
        l1 = A1 * inv + b2[c0 + 1];
    }
    // masked 32-lane butterfly for max and sum-exp over the 40 logits
    float mv = active ? fmaxf(l0, l1) : -INFINITY;
    #pragma unroll
    for (int ofs = 1; ofs < 32; ofs <<= 1) mv = fmaxf(mv, __shfl_xor(mv, ofs));
    float ev = active ? (__expf(l0 - mv) + __expf(l1 - mv)) : 0.f;
    #pragma unroll
    for (int ofs = 1; ofs < 32; ofs <<= 1) ev += __shfl_xor(ev, ofs);
    if (active) {
        float ls = mv + __logf(ev);
        *(float2*)&out[(size_t)n * 40 + c0] = make_float2(l0 - ls, l1 - ls);
    }
}

extern "C" void kernel_launch(void* const* d_in, const int* in_sizes, int n_in,
                              void* d_out, int out_size, void* d_ws, size_t ws_size,
                              hipStream_t stream) {
    const float* x    = (const float*)d_in[0];
    const float* topo = (const float*)d_in[1];
    const int*   ei   = (const int*)d_in[2];
    const float* W1   = (const float*)d_in[3];
    const float* a_s1 = (const float*)d_in[4];
    const float* a_d1 = (const float*)d_in[5];
    const float* b1   = (const float*)d_in[6];
    const float* W2   = (const float*)d_in[7];
    const float* a_s2 = (const float*)d_in[8];
    const float* a_d2 = (const float*)d_in[9];
    const float* b2   = (const float*)d_in[10];
    float* out = (float*)d_out;

    int N = in_sizes[0] / 128;
    int E = in_sizes[2] / 2;
    const int* esrc = ei;
    const int* edst = ei + E;
    int NBUK = (N + 255) / 256;
    size_t cap = (size_t)NBUK * BUK_CAP;

    char* ws = (char*)d_ws;
    size_t off = 0;
    auto alloc = [&](size_t bytes) -> void* {
        void* p = ws + off;
        off = (off + bytes + 255) & ~(size_t)255;
        return p;
    };
    ushort_t* h1b  = (ushort_t*)alloc((size_t)N * 64 * 2);
    float* as1     = (float*)alloc((size_t)N * 8 * 4);
    float* ad1     = (float*)alloc((size_t)N * 8 * 4);
    float* h2      = (float*)alloc((size_t)N * 64 * 4);
    ushort_t* gb   = (ushort_t*)alloc((size_t)N * 40 * 2);  // 80B rows
    float* as2     = (float*)alloc((size_t)N * 4);
    float* ad2     = (float*)alloc((size_t)N * 4);
    int*   rowptr  = (int*)alloc((size_t)N * 4);
    int*   rowEnd  = (int*)alloc((size_t)N * 4);
    int*   csr     = (int*)alloc(cap * 4);
    unsigned int* tmp = (unsigned int*)alloc(cap * 4);
    int* gCursor   = (int*)alloc((size_t)NBUK * 4);

    hipMemsetAsync(gCursor, 0, (size_t)NBUK * 4, stream);  // count-based cursors
    int nbin = (E + BIN_CHUNK - 1) / BIN_CHUNK;
    k_bin<<<nbin, 256, 0, stream>>>(esrc, edst, gCursor, tmp, E, NBUK);
    k_fill2<<<NBUK, 512, 0, stream>>>(tmp, gCursor, rowptr, rowEnd, csr, N);

    int nbg = (N + 63) / 64;  // 64-node GEMM tiles
    int nb4 = (N + 3) / 4;    // 1 node/wave x 4 waves/block
    k_xform1<<<nbg, 256, 0, stream>>>(x, topo, W1, a_s1, a_d1, h1b, as1, ad1, N);
    k_agg1<<<nb4, 256, 0, stream>>>(h1b, as1, ad1, b1, rowptr, rowEnd, csr, h2, N);
    k_xform2<<<nbg, 256, 0, stream>>>(h2, W2, a_s2, a_d2, gb, as2, ad2, N);
    k_agg2<<<nb4, 256, 0, stream>>>(gb, as2, ad2, b2, rowptr, rowEnd, csr, out, N);
}

// Round 7
// 300.034 us; speedup vs baseline: 1.0547x; 1.0293x over previous
//
#include <hip/hip_runtime.h>
#include <math.h>

// ---------------------------------------------------------------------------
// TopoGAT: 2-layer GAT on MI355X.
// R10: fixed-capacity bucket CSR build; padded CSR with rowptr/rowEnd.
// R5:  gather tables h1/g in bf16.
// R7/R12: xform = LDS-tiled GEMM, node-minor staging (conflict-free).
// R14: CSR build — k_bin BIN_CHUNK=4096; k_fill2 512thr + uint4 count pass.
// R16-R20 lessons: k_agg1 pinned at ~61us across TWO different instruction
//      mixes (R1 2x32-dword vs R16 8x8-uint4, VALUBusy 49 vs 58%) => it is
//      LATENCY-bound on serialized memory round trips (~3.6us/wave for ~17
//      edges = 3-4 dependent RTs: each chunk loop re-loads csr then waits).
//      k_agg2: cheap-reduce 3x20 mapping is the verified best (~46us).
// R21: k_agg1 restructured to 2 round trips: ONE wave-wide csr load covers
//      the whole adjacency row (<=64 edges; deg~Poisson(16)); then ALL
//      as1+h1b gathers for up to 3 masked chunks (24 edges) issue before
//      any exp/FMA. Wave-uniform branches add chunks 3..5, 6..7, and a
//      fallback loop for d>64 (correctness). Masked lanes clamp to the
//      last edge (valid row, w=0). k_agg2/xforms/CSR untouched.
// ---------------------------------------------------------------------------

#define NBUK_MAX 512
#define BIN_CHUNK 4096
#define BUK_CAP 4608

typedef unsigned short ushort_t;

__device__ inline unsigned int f2bf(float f) {  // RNE fp32->bf16
    unsigned int u = __float_as_uint(f);
    u += 0x7FFFu + ((u >> 16) & 1u);
    return u >> 16;
}
__device__ inline float bf_lo(unsigned int u) {
    return __uint_as_float(u << 16);
}
__device__ inline float bf_hi(unsigned int u) {
    return __uint_as_float(u & 0xFFFF0000u);
}
__device__ inline float lrelu_exp(float q) {
    return __expf(q >= 0.f ? q : 0.2f * q);
}

__device__ inline int wave_incl_scan(int v, int lane) {
    #pragma unroll
    for (int ofs = 1; ofs < 64; ofs <<= 1) {
        int t = __shfl_up(v, ofs);
        if (lane >= ofs) v += t;
    }
    return v;
}

// Bin edges into fixed-capacity bucket regions of tmp. One global atomic per
// (block,bucket); packed word = (src<<8) | (dst&255). 16 edges/thread via
// int4 loads; dst stashed in registers across the reservation barrier.
__global__ __launch_bounds__(256) void k_bin(const int* __restrict__ src,
                                             const int* __restrict__ dst,
                                             int* __restrict__ gCursor,
                                             unsigned int* __restrict__ tmp,
                                             int E, int NBUK) {
    __shared__ int lcnt[NBUK_MAX];
    __shared__ int lcur[NBUK_MAX];
    int tid = threadIdx.x;
    int base = blockIdx.x * BIN_CHUNK;
    for (int i = tid; i < NBUK; i += 256) lcnt[i] = 0;
    __syncthreads();
    int d[16];
    #pragma unroll
    for (int q = 0; q < 4; q++) {
        int e = base + q * 1024 + 4 * tid;
        if (e + 3 < E) {
            int4 v = *(const int4*)&dst[e];
            d[4 * q + 0] = v.x; d[4 * q + 1] = v.y;
            d[4 * q + 2] = v.z; d[4 * q + 3] = v.w;
        } else {
            #pragma unroll
            for (int k = 0; k < 4; k++)
                d[4 * q + k] = (e + k < E) ? dst[e + k] : -1;
        }
    }
    #pragma unroll
    for (int k = 0; k < 16; k++)
        if (d[k] >= 0) atomicAdd(&lcnt[d[k] >> 8], 1);
    __syncthreads();
    for (int b = tid; b < NBUK; b += 256) {
        int c = lcnt[b];
        lcur[b] = c ? b * BUK_CAP + atomicAdd(&gCursor[b], c) : 0;
    }
    __syncthreads();
    #pragma unroll
    for (int q = 0; q < 4; q++) {
        int e = base + q * 1024 + 4 * tid;
        int s[4];
        if (e + 3 < E) {
            int4 v = *(const int4*)&src[e];
            s[0] = v.x; s[1] = v.y; s[2] = v.z; s[3] = v.w;
        } else {
            #pragma unroll
            for (int k = 0; k < 4; k++)
                s[k] = (e + k < E) ? src[e + k] : 0;
        }
        #pragma unroll
        for (int k = 0; k < 4; k++) {
            int dd = d[4 * q + k];
            if (dd >= 0) {
                int p = atomicAdd(&lcur[dd >> 8], 1);
                tmp[p] = ((unsigned int)s[k] << 8) | (unsigned int)(dd & 255);
            }
        }
    }
}

// Exact CSR fill within a bucket (padded layout, base = b*BUK_CAP).
// 512 threads; count pass reads tmp as uint4.
__global__ __launch_bounds__(512) void k_fill2(const unsigned int* __restrict__ tmp,
                                               const int* __restrict__ gCursor,
                                               int* __restrict__ rowptr,
                                               int* __restrict__ rowEnd,
                                               int* __restrict__ csr, int N) {
    __shared__ int cnt[256];
    __shared__ int cur[256];
    __shared__ int wsum[4];
    int b = blockIdx.x, tid = threadIdx.x;
    int e0 = b * BUK_CAP;
    int cnt_e = gCursor[b];       // bucket edge count
    int e1 = e0 + cnt_e;
    if (tid < 256) cnt[tid] = 0;
    __syncthreads();
    {   // count pass: uint4 over the bulk (e0 is 16B-aligned: BUK_CAP*4 % 16 == 0)
        int nq = cnt_e >> 2;
        const uint4* t4 = (const uint4*)(tmp + e0);
        for (int q = tid; q < nq; q += 512) {
            uint4 v = t4[q];
            atomicAdd(&cnt[v.x & 255u], 1);
            atomicAdd(&cnt[v.y & 255u], 1);
            atomicAdd(&cnt[v.z & 255u], 1);
            atomicAdd(&cnt[v.w & 255u], 1);
        }
        for (int i = (nq << 2) + tid; i < cnt_e; i += 512)
            atomicAdd(&cnt[tmp[e0 + i] & 255u], 1);
    }
    __syncthreads();
    if (tid < 256) {
        int lane = tid & 63, wv = tid >> 6;
        int v = cnt[tid];
        int incl = wave_incl_scan(v, lane);
        if (lane == 63) wsum[wv] = incl;
        cnt[tid] = incl - v;  // stash exclusive-within-wave
    }
    __syncthreads();
    if (tid < 256) {
        int wv = tid >> 6;
        int woff = 0;
        for (int i = 0; i < wv; i++) woff += wsum[i];
        int excl = woff + cnt[tid];
        int node = b * 256 + tid;
        int start = e0 + excl;
        cur[tid] = start;
        if (node < N) {
            rowptr[node] = start;
        }
    }
    __syncthreads();
    // rowEnd[node] = next start (cur of tid+1) or e1 for the last
    if (tid < 256) {
        int node = b * 256 + tid;
        if (node < N) rowEnd[node] = (tid < 255) ? cur[tid + 1] : e1;
    }
    __syncthreads();
    for (int i = e0 + tid; i < e1; i += 512) {
        unsigned int t = tmp[i];
        int p = atomicAdd(&cur[t & 255u], 1);
        csr[p] = (int)(t >> 8);
    }
}

// h1b[n][64](bf16) = [x[n]|topo[n]] @ W1 ; as1/ad1 from fp32 accumulators.
// Block = 64 nodes x 64 cols GEMM tile, K=136. W1 + xT staged in LDS,
// node-minor (conflict-free transpose writes).
__global__ __launch_bounds__(256) void k_xform1(const float* __restrict__ x,
                                                const float* __restrict__ topo,
                                                const float* __restrict__ W1,
                                                const float* __restrict__ asrc,
                                                const float* __restrict__ adst,
                                                ushort_t* __restrict__ h1b,
                                                float* __restrict__ as1,
                                                float* __restrict__ ad1, int N) {
    __shared__ float XT[136 * 64];  // XT[k][node]
    __shared__ float WS[136 * 64];  // WS[k][col]
    int tid = threadIdx.x;
    int n0 = blockIdx.x * 64;
    {   // stage W1: 8704 floats = 2176 float4 (once per block)
        const float4* W4 = (const float4*)W1;
        float4* WS4 = (float4*)WS;
        for (int i = tid; i < 2176; i += 256) WS4[i] = W4[i];
    }
    {   // stage x transposed, node-minor: i = k4*64 + node
        const float4* x4 = (const float4*)x;
        for (int i = tid; i < 2048; i += 256) {
            int node = i & 63, k4 = i >> 6;
            int gn = n0 + node; if (gn > N - 1) gn = N - 1;
            float4 v = x4[(size_t)gn * 32 + k4];
            int k = k4 * 4;
            XT[(k + 0) * 64 + node] = v.x;
            XT[(k + 1) * 64 + node] = v.y;
            XT[(k + 2) * 64 + node] = v.z;
            XT[(k + 3) * 64 + node] = v.w;
        }
        // topo rows 128..135: i = j4*64 + node, j4 in {0,1}
        const float4* t4 = (const float4*)topo;
        if (tid < 128) {
            int node = tid & 63, j4 = tid >> 6;
            int gn = n0 + node; if (gn > N - 1) gn = N - 1;
            float4 v = t4[(size_t)gn * 2 + j4];
            int k = 128 + j4 * 4;
            XT[(k + 0) * 64 + node] = v.x;
            XT[(k + 1) * 64 + node] = v.y;
            XT[(k + 2) * 64 + node] = v.z;
            XT[(k + 3) * 64 + node] = v.w;
        }
    }
    __syncthreads();
    int ci = tid & 15, ni = tid >> 4;
    int nb = ni * 4, cb = ci * 4;
    float acc[16];
    #pragma unroll
    for (int i = 0; i < 16; i++) acc[i] = 0.f;
    #pragma unroll 4
    for (int k = 0; k < 136; k++) {
        float4 xv = *(const float4*)&XT[k * 64 + nb];
        float4 wv = *(const float4*)&WS[k * 64 + cb];
        acc[0]  = fmaf(xv.x, wv.x, acc[0]);  acc[1]  = fmaf(xv.x, wv.y, acc[1]);
        acc[2]  = fmaf(xv.x, wv.z, acc[2]);  acc[3]  = fmaf(xv.x, wv.w, acc[3]);
        acc[4]  = fmaf(xv.y, wv.x, acc[4]);  acc[5]  = fmaf(xv.y, wv.y, acc[5]);
        acc[6]  = fmaf(xv.y, wv.z, acc[6]);  acc[7]  = fmaf(xv.y, wv.w, acc[7]);
        acc[8]  = fmaf(xv.z, wv.x, acc[8]);  acc[9]  = fmaf(xv.z, wv.y, acc[9]);
        acc[10] = fmaf(xv.z, wv.z, acc[10]); acc[11] = fmaf(xv.z, wv.w, acc[11]);
        acc[12] = fmaf(xv.w, wv.x, acc[12]); acc[13] = fmaf(xv.w, wv.y, acc[13]);
        acc[14] = fmaf(xv.w, wv.z, acc[14]); acc[15] = fmaf(xv.w, wv.w, acc[15]);
    }
    int head = cb >> 3;  // cols cb..cb+3 lie in one head (cb multiple of 4)
    #pragma unroll
    for (int i = 0; i < 4; i++) {
        int n = n0 + nb + i;
        unsigned int p0 = f2bf(acc[i * 4 + 0]) | (f2bf(acc[i * 4 + 1]) << 16);
        unsigned int p1 = f2bf(acc[i * 4 + 2]) | (f2bf(acc[i * 4 + 3]) << 16);
        if (n < N) *(uint2*)&h1b[(size_t)n * 64 + cb] = make_uint2(p0, p1);
        float s = 0.f, d = 0.f;
        #pragma unroll
        for (int j = 0; j < 4; j++) {
            s = fmaf(acc[i * 4 + j], asrc[cb + j], s);
            d = fmaf(acc[i * 4 + j], adst[cb + j], d);
        }
        s += __shfl_xor(s, 1);  // combine the two half-head threads
        d += __shfl_xor(d, 1);
        if ((ci & 1) == 0 && n < N) {
            as1[n * 8 + head] = s;
            ad1[n * 8 + head] = d;
        }
    }
}

// NOTE: parameter names W_/U_ must not collide with vector members .x/.y/.z/.w
#define AGG_FMA(W_, U_)                                           \
    {                                                             \
        acc[0] = fmaf(W_, bf_lo(U_.x), acc[0]);                   \
        acc[1] = fmaf(W_, bf_hi(U_.x), acc[1]);                   \
        acc[2] = fmaf(W_, bf_lo(U_.y), acc[2]);                   \
        acc[3] = fmaf(W_, bf_hi(U_.y), acc[3]);                   \
        acc[4] = fmaf(W_, bf_lo(U_.z), acc[4]);                   \
        acc[5] = fmaf(W_, bf_hi(U_.z), acc[5]);                   \
        acc[6] = fmaf(W_, bf_lo(U_.w), acc[6]);                   \
        acc[7] = fmaf(W_, bf_hi(U_.w), acc[7]);                   \
        z += W_;                                                  \
    }

// Three masked 8-edge chunks (base chunk B_, B_+1, B_+2): all se/av/u gathers
// issue before any exp/FMA — one memory round trip for 24 edges.
#define AGG1_C3(B_)                                                        \
    {                                                                      \
        int e0 = (B_) * 8 + g, e1 = e0 + 8, e2 = e0 + 16;                  \
        int se0 = __shfl(cv, e0 < d ? e0 : dm1);                           \
        int se1 = __shfl(cv, e1 < d ? e1 : dm1);                           \
        int se2 = __shfl(cv, e2 < d ? e2 : dm1);                           \
        float av0 = as1[se0 * 8 + head];                                   \
        float av1 = as1[se1 * 8 + head];                                   \
        float av2 = as1[se2 * 8 + head];                                   \
        uint4 u0 = *(const uint4*)(h1c + (((unsigned)se0 << 7) + hoff));   \
        uint4 u1 = *(const uint4*)(h1c + (((unsigned)se1 << 7) + hoff));   \
        uint4 u2 = *(const uint4*)(h1c + (((unsigned)se2 << 7) + hoff));   \
        float w0 = e0 < d ? lrelu_exp(av0 + adv) : 0.f;                    \
        float w1 = e1 < d ? lrelu_exp(av1 + adv) : 0.f;                    \
        float w2 = e2 < d ? lrelu_exp(av2 + adv) : 0.f;                    \
        AGG_FMA(w0, u0);                                                   \
        AGG_FMA(w1, u1);                                                   \
        AGG_FMA(w2, u2);                                                   \
    }

// Per-dst softmax-weighted aggregation, layer 1 (+ implicit self loop).
// 8 groups x 8 lanes on 128B rows; TWO memory round trips total:
// (1) one wave-wide csr load covering the whole adjacency row (<=64 edges),
// (2) all as1 + h1b gathers for the masked chunks issued back-to-back.
// Wave-uniform deg branches: 0..24 / 24..48 / 48..64 / >64 fallback loop.
__global__ __launch_bounds__(256) void k_agg1(const ushort_t* __restrict__ h1b,
                                              const float* __restrict__ as1,
                                              const float* __restrict__ ad1,
                                              const float* __restrict__ b1,
                                              const int* __restrict__ rowptr,
                                              const int* __restrict__ rowEnd,
                                              const int* __restrict__ csr,
                                              float* __restrict__ h2, int N) {
    int tid = threadIdx.x, lane = tid & 63;
    int n = blockIdx.x * 4 + (tid >> 6);
    if (n >= N) return;
    int g = lane >> 3;      // edge slot within chunk
    int head = lane & 7;    // head (cols 8h..8h+7)
    const char* h1c = (const char*)h1b;
    unsigned hoff = (unsigned)head << 4;   // 16B per head block
    float adv = ad1[n * 8 + head];
    float acc[8];
    #pragma unroll
    for (int k = 0; k < 8; k++) acc[k] = 0.f;
    float z = 0.f;

    int j0 = rowptr[n], j1 = rowEnd[n];
    int d = j1 - j0;
    int dm1 = d > 0 ? d - 1 : 0;
    // ONE wave-wide csr load covers up to 64 edges (clamped duplicates ok)
    int cv = (d > 0) ? csr[j0 + (lane < d ? lane : dm1)] : 0;

    {   // self loop (group 0 only)
        float w = lrelu_exp(as1[n * 8 + head] + adv);
        if (g == 0) {
            uint4 u = *(const uint4*)(h1c + (((unsigned)n << 7) + hoff));
            acc[0] = w * bf_lo(u.x); acc[1] = w * bf_hi(u.x);
            acc[2] = w * bf_lo(u.y); acc[3] = w * bf_hi(u.y);
            acc[4] = w * bf_lo(u.z); acc[5] = w * bf_hi(u.z);
            acc[6] = w * bf_lo(u.w); acc[7] = w * bf_hi(u.w);
            z = w;
        }
    }
    if (d > 0) {
        AGG1_C3(0);                    // edges 0..23 (covers ~98% of nodes)
        if (d > 24) {
            AGG1_C3(3);                // edges 24..47
            if (d > 48) {              // edges 48..63 from cv
                int e0 = 48 + g, e1 = 56 + g;
                int se0 = __shfl(cv, e0 < d ? e0 : dm1);
                int se1 = __shfl(cv, e1 < d ? e1 : dm1);
                float av0 = as1[se0 * 8 + head];
                float av1 = as1[se1 * 8 + head];
                uint4 u0 = *(const uint4*)(h1c + (((unsigned)se0 << 7) + hoff));
                uint4 u1 = *(const uint4*)(h1c + (((unsigned)se1 << 7) + hoff));
                float w0 = e0 < d ? lrelu_exp(av0 + adv) : 0.f;
                float w1 = e1 < d ? lrelu_exp(av1 + adv) : 0.f;
                AGG_FMA(w0, u0);
                AGG_FMA(w1, u1);
                // d > 64: fallback loop with fresh csr loads (correctness)
                for (int j = j0 + 64; j < j1; j += 8) {
                    int m = j1 - j;
                    int idx = (lane & 7); idx = idx < m ? idx : m - 1;
                    int cvt = csr[j + idx];
                    int ge = g < m ? g : m - 1;
                    int se = __shfl(cvt, ge);
                    float av = as1[se * 8 + head];
                    uint4 u = *(const uint4*)(h1c + (((unsigned)se << 7) + hoff));
                    float w = (g < m) ? lrelu_exp(av + adv) : 0.f;
                    AGG_FMA(w, u);
                }
            }
        }
    }
    // reduce across the 8 edge-slot groups (lanes differing in bits 3..5)
    #pragma unroll
    for (int k = 0; k < 8; k++) {
        acc[k] += __shfl_xor(acc[k], 8);
        acc[k] += __shfl_xor(acc[k], 16);
        acc[k] += __shfl_xor(acc[k], 32);
    }
    z += __shfl_xor(z, 8); z += __shfl_xor(z, 16); z += __shfl_xor(z, 32);
    if (g == 0) {
        float inv = 1.f / (z + 1e-16f);
        float o[8];
        #pragma unroll
        for (int k = 0; k < 8; k++) {
            float v = acc[k] * inv + b1[head * 8 + k];
            o[k] = v > 0.f ? v : (__expf(v) - 1.f);
        }
        float4* dp = (float4*)&h2[(size_t)n * 64 + head * 8];
        dp[0] = make_float4(o[0], o[1], o[2], o[3]);
        dp[1] = make_float4(o[4], o[5], o[6], o[7]);
    }
}

// gb[n][40](bf16) = h2[n] @ W2 ; as2/ad2 from fp32 accumulators.
// Block = 64 nodes x 40 cols GEMM tile, K=64. Node-minor staging.
__global__ __launch_bounds__(256) void k_xform2(const float* __restrict__ h2,
                                                const float* __restrict__ W2,
                                                const float* __restrict__ asrc2,
                                                const float* __restrict__ adst2,
                                                ushort_t* __restrict__ gb,
                                                float* __restrict__ as2,
                                                float* __restrict__ ad2, int N) {
    __shared__ float XT[64 * 64];  // h2T[k][node]
    __shared__ float WS[64 * 40];  // WS[k][col]
    int tid = threadIdx.x;
    int n0 = blockIdx.x * 64;
    {   // stage W2: 2560 floats = 640 float4
        const float4* W4 = (const float4*)W2;
        float4* WS4 = (float4*)WS;
        for (int i = tid; i < 640; i += 256) WS4[i] = W4[i];
    }
    {   // stage h2 transposed, node-minor: i = k4*64 + node
        const float4* h4 = (const float4*)h2;
        for (int i = tid; i < 1024; i += 256) {
            int node = i & 63, k4 = i >> 6;
            int gn = n0 + node; if (gn > N - 1) gn = N - 1;
            float4 v = h4[(size_t)gn * 16 + k4];
            int k = k4 * 4;
            XT[(k + 0) * 64 + node] = v.x;
            XT[(k + 1) * 64 + node] = v.y;
            XT[(k + 2) * 64 + node] = v.z;
            XT[(k + 3) * 64 + node] = v.w;
        }
    }
    __syncthreads();
    int ci = tid & 15, ni = tid >> 4;
    int nb = ni * 4, cb = ci * 4;
    float acc[16];
    #pragma unroll
    for (int i = 0; i < 16; i++) acc[i] = 0.f;
    if (ci < 10) {
        #pragma unroll 4
        for (int k = 0; k < 64; k++) {
            float4 xv = *(const float4*)&XT[k * 64 + nb];
            float4 wv = *(const float4*)&WS[k * 40 + cb];
            acc[0]  = fmaf(xv.x, wv.x, acc[0]);  acc[1]  = fmaf(xv.x, wv.y, acc[1]);
            acc[2]  = fmaf(xv.x, wv.z, acc[2]);  acc[3]  = fmaf(xv.x, wv.w, acc[3]);
            acc[4]  = fmaf(xv.y, wv.x, acc[4]);  acc[5]  = fmaf(xv.y, wv.y, acc[5]);
            acc[6]  = fmaf(xv.y, wv.z, acc[6]);  acc[7]  = fmaf(xv.y, wv.w, acc[7]);
            acc[8]  = fmaf(xv.z, wv.x, acc[8]);  acc[9]  = fmaf(xv.z, wv.y, acc[9]);
            acc[10] = fmaf(xv.z, wv.z, acc[10]); acc[11] = fmaf(xv.z, wv.w, acc[11]);
            acc[12] = fmaf(xv.w, wv.x, acc[12]); acc[13] = fmaf(xv.w, wv.y, acc[13]);
            acc[14] = fmaf(xv.w, wv.z, acc[14]); acc[15] = fmaf(xv.w, wv.w, acc[15]);
        }
    }
    #pragma unroll
    for (int i = 0; i < 4; i++) {
        int n = n0 + nb + i;
        if (ci < 10 && n < N) {
            unsigned int p0 = f2bf(acc[i * 4 + 0]) | (f2bf(acc[i * 4 + 1]) << 16);
            unsigned int p1 = f2bf(acc[i * 4 + 2]) | (f2bf(acc[i * 4 + 3]) << 16);
            *(uint2*)&gb[(size_t)n * 40 + cb] = make_uint2(p0, p1);  // 80B rows
        }
        float s = 0.f, d = 0.f;
        if (ci < 10) {
            #pragma unroll
            for (int j = 0; j < 4; j++) {
                s = fmaf(acc[i * 4 + j], asrc2[cb + j], s);
                d = fmaf(acc[i * 4 + j], adst2[cb + j], d);
            }
        }
        // reduce over the 16-lane ci group (ci>=10 contribute 0)
        s += __shfl_xor(s, 1); s += __shfl_xor(s, 2);
        s += __shfl_xor(s, 4); s += __shfl_xor(s, 8);
        d += __shfl_xor(d, 1); d += __shfl_xor(d, 2);
        d += __shfl_xor(d, 4); d += __shfl_xor(d, 8);
        if (ci == 0 && n < N) { as2[n] = s; ad2[n] = d; }
    }
}

// Layer-2 aggregation + bias + log_softmax. (R1-verified mapping.)
// 3 groups x 20 lanes -> THREE 80B rows per gather instruction.
// ONE as2 load + ONE exp per 12-edge chunk; weights via shfl.
// Cheap per-node fixed cost: 2-shfl reduce per value, 2-exp epilogue.
__global__ __launch_bounds__(256) void k_agg2(const ushort_t* __restrict__ gb,
                                              const float* __restrict__ as2,
                                              const float* __restrict__ ad2,
                                              const float* __restrict__ b2,
                                              const int* __restrict__ rowptr,
                                              const int* __restrict__ rowEnd,
                                              const int* __restrict__ csr,
                                              float* __restrict__ out, int N) {
    int tid = threadIdx.x, lane = tid & 63;
    int n = blockIdx.x * 4 + (tid >> 6);
    if (n >= N) return;
    int g = lane / 20, p = lane % 20;  // g==3 for lanes 60-63 (results unread)
    int c0 = 2 * p;
    const char* gbc = (const char*)gb;
    unsigned coff = (unsigned)(p << 2);
    int lm12 = lane % 12;
    float add = ad2[n];
    float acc0 = 0.f, acc1 = 0.f, zl = 0.f;
    {   // self loop (group 0 only)
        float e0 = as2[n] + add;
        float w = lrelu_exp(e0);
        if (g == 0) {
            unsigned int u = *(const unsigned int*)(gbc + ((unsigned)n * 80u + coff));
            acc0 = w * bf_lo(u); acc1 = w * bf_hi(u); zl = w;
        }
    }
    int j0 = rowptr[n], j1 = rowEnd[n];
    int j = j0;
    int gi0 = (0 + g) < 12 ? (0 + g) : 11;   // clamp for g==3 lanes
    int gi1 = (3 + g) < 12 ? (3 + g) : 11;
    int gi2 = (6 + g) < 12 ? (6 + g) : 11;
    int gi3 = (9 + g) < 12 ? (9 + g) : 11;
    for (; j + 12 <= j1; j += 12) {
        int cv = csr[j + lm12];          // coalesced, then bpermute
        float av = as2[cv];
        float wall = lrelu_exp(av + add);
        int s0 = __shfl(cv, gi0);
        int s1 = __shfl(cv, gi1);
        int s2 = __shfl(cv, gi2);
        int s3 = __shfl(cv, gi3);
        unsigned int u0 = *(const unsigned int*)(gbc + ((unsigned)s0 * 80u + coff));
        unsigned int u1 = *(const unsigned int*)(gbc + ((unsigned)s1 * 80u + coff));
        unsigned int u2 = *(const unsigned int*)(gbc + ((unsigned)s2 * 80u + coff));
        unsigned int u3 = *(const unsigned int*)(gbc + ((unsigned)s3 * 80u + coff));
        float w0 = __shfl(wall, gi0);
        float w1 = __shfl(wall, gi1);
        float w2 = __shfl(wall, gi2);
        float w3 = __shfl(wall, gi3);
        acc0 = fmaf(w0, bf_lo(u0), acc0); acc1 = fmaf(w0, bf_hi(u0), acc1); zl += w0;
        acc0 = fmaf(w1, bf_lo(u1), acc0); acc1 = fmaf(w1, bf_hi(u1), acc1); zl += w1;
        acc0 = fmaf(w2, bf_lo(u2), acc0); acc1 = fmaf(w2, bf_hi(u2), acc1); zl += w2;
        acc0 = fmaf(w3, bf_lo(u3), acc0); acc1 = fmaf(w3, bf_hi(u3), acc1); zl += w3;
    }
    int t = j1 - j;
    if (t > 0) {  // masked 12-wide tail (t in 1..11 -> lane 11's wall is 0)
        int idx = lm12 < t ? lm12 : t - 1;
        int cv = csr[j + idx];
        float av = as2[cv];
        float wall = (lm12 < t) ? lrelu_exp(av + add) : 0.f;
        #pragma unroll
        for (int i = 0; i < 4; i++) {
            int e = 3 * i + g;
            int gi = e < 12 ? e : 11;
            int s = __shfl(cv, gi);
            unsigned int u = *(const unsigned int*)(gbc + ((unsigned)s * 80u + coff));
            float w = __shfl(wall, gi);  // 0 for e >= t
            acc0 = fmaf(w, bf_lo(u), acc0); acc1 = fmaf(w, bf_hi(u), acc1); zl += w;
        }
    }
    // combine the 3 groups (valid at lanes 0..19)
    float A0 = acc0 + __shfl(acc0, (lane + 20) & 63) + __shfl(acc0, (lane + 40) & 63);
    float A1 = acc1 + __shfl(acc1, (lane + 20) & 63) + __shfl(acc1, (lane + 40) & 63);
    float Z  = zl + __shfl(zl, (lane + 20) & 63) + __shfl(zl, (lane + 40) & 63);
    float l0 = 0.f, l1 = 0.f;
    bool active = (lane < 20);
    if (active) {
        float inv = 1.f / (Z + 1e-16f);
        l0 = A0 * inv + b2[c0];
        l1 = A1 * inv + b2[c0 + 1];
    }
    // masked 32-lane butterfly for max and sum-exp over the 40 logits
    float mv = active ? fmaxf(l0, l1) : -INFINITY;
    #pragma unroll
    for (int ofs = 1; ofs < 32; ofs <<= 1) mv = fmaxf(mv, __shfl_xor(mv, ofs));
    float ev = active ? (__expf(l0 - mv) + __expf(l1 - mv)) : 0.f;
    #pragma unroll
    for (int ofs = 1; ofs < 32; ofs <<= 1) ev += __shfl_xor(ev, ofs);
    if (active) {
        float ls = mv + __logf(ev);
        *(float2*)&out[(size_t)n * 40 + c0] = make_float2(l0 - ls, l1 - ls);
    }
}

extern "C" void kernel_launch(void* const* d_in, const int* in_sizes, int n_in,
                              void* d_out, int out_size, void* d_ws, size_t ws_size,
                              hipStream_t stream) {
    const float* x    = (const float*)d_in[0];
    const float* topo = (const float*)d_in[1];
    const int*   ei   = (const int*)d_in[2];
    const float* W1   = (const float*)d_in[3];
    const float* a_s1 = (const float*)d_in[4];
    const float* a_d1 = (const float*)d_in[5];
    const float* b1   = (const float*)d_in[6];
    const float* W2   = (const float*)d_in[7];
    const float* a_s2 = (const float*)d_in[8];
    const float* a_d2 = (const float*)d_in[9];
    const float* b2   = (const float*)d_in[10];
    float* out = (float*)d_out;

    int N = in_sizes[0] / 128;
    int E = in_sizes[2] / 2;
    const int* esrc = ei;
    const int* edst = ei + E;
    int NBUK = (N + 255) / 256;
    size_t cap = (size_t)NBUK * BUK_CAP;

    char* ws = (char*)d_ws;
    size_t off = 0;
    auto alloc = [&](size_t bytes) -> void* {
        void* p = ws + off;
        off = (off + bytes + 255) & ~(size_t)255;
        return p;
    };
    ushort_t* h1b  = (ushort_t*)alloc((size_t)N * 64 * 2);
    float* as1     = (float*)alloc((size_t)N * 8 * 4);
    float* ad1     = (float*)alloc((size_t)N * 8 * 4);
    float* h2      = (float*)alloc((size_t)N * 64 * 4);
    ushort_t* gb   = (ushort_t*)alloc((size_t)N * 40 * 2);  // 80B rows
    float* as2     = (float*)alloc((size_t)N * 4);
    float* ad2     = (float*)alloc((size_t)N * 4);
    int*   rowptr  = (int*)alloc((size_t)N * 4);
    int*   rowEnd  = (int*)alloc((size_t)N * 4);
    int*   csr     = (int*)alloc(cap * 4);
    unsigned int* tmp = (unsigned int*)alloc(cap * 4);
    int* gCursor   = (int*)alloc((size_t)NBUK * 4);

    hipMemsetAsync(gCursor, 0, (size_t)NBUK * 4, stream);  // count-based cursors
    int nbin = (E + BIN_CHUNK - 1) / BIN_CHUNK;
    k_bin<<<nbin, 256, 0, stream>>>(esrc, edst, gCursor, tmp, E, NBUK);
    k_fill2<<<NBUK, 512, 0, stream>>>(tmp, gCursor, rowptr, rowEnd, csr, N);

    int nbg = (N + 63) / 64;  // 64-node GEMM tiles
    int nb4 = (N + 3) / 4;    // 1 node/wave x 4 waves/block
    k_xform1<<<nbg, 256, 0, stream>>>(x, topo, W1, a_s1, a_d1, h1b, as1, ad1, N);
    k_agg1<<<nb4, 256, 0, stream>>>(h1b, as1, ad1, b1, rowptr, rowEnd, csr, h2, N);
    k_xform2<<<nbg, 256, 0, stream>>>(h2, W2, a_s2, a_d2, gb, as2, ad2, N);
    k_agg2<<<nb4, 256, 0, stream>>>(gb, as2, ad2, b2, rowptr, rowEnd, csr, out, N);
}

// Round 8
// 294.134 us; speedup vs baseline: 1.0758x; 1.0201x over previous
//
#include <hip/hip_runtime.h>
#include <math.h>

// ---------------------------------------------------------------------------
// TopoGAT: 2-layer GAT on MI355X.
// R10: fixed-capacity bucket CSR build; padded CSR with rowptr/rowEnd.
// R5:  gather tables h1/g in bf16.
// R7/R12: xform = LDS-tiled GEMM, node-minor staging (conflict-free).
// R14: CSR build — k_bin BIN_CHUNK=4096; k_fill2 512thr + uint4 count pass.
// R16-R20: agg kernels are LATENCY-bound (same dur across different
//      instruction mixes). k_agg2 3x20 mapping verified best for 40 cols.
// R21: k_agg1 -> 2 round trips (one wave-wide csr load + all gathers
//      up-front): 61.4 -> ~52us, total 308.8 -> 300.0. VERIFIED WIN.
// R22: same technique ported to k_agg2 (was 59.4us, same serialized-chunk
//      disease): one wave-wide csr load covers the row; two 12-edge chunks
//      issue ALL as2+gb gathers before any exp/FMA; wave-uniform branches
//      for chunks 2-3 (d>24) and fresh-load fallback (d>48, ~never).
//      Mapping/layout (3x20, 80B rows, lm12 weight-lane) unchanged.
// ---------------------------------------------------------------------------

#define NBUK_MAX 512
#define BIN_CHUNK 4096
#define BUK_CAP 4608

typedef unsigned short ushort_t;

__device__ inline unsigned int f2bf(float f) {  // RNE fp32->bf16
    unsigned int u = __float_as_uint(f);
    u += 0x7FFFu + ((u >> 16) & 1u);
    return u >> 16;
}
__device__ inline float bf_lo(unsigned int u) {
    return __uint_as_float(u << 16);
}
__device__ inline float bf_hi(unsigned int u) {
    return __uint_as_float(u & 0xFFFF0000u);
}
__device__ inline float lrelu_exp(float q) {
    return __expf(q >= 0.f ? q : 0.2f * q);
}

__device__ inline int wave_incl_scan(int v, int lane) {
    #pragma unroll
    for (int ofs = 1; ofs < 64; ofs <<= 1) {
        int t = __shfl_up(v, ofs);
        if (lane >= ofs) v += t;
    }
    return v;
}

// Bin edges into fixed-capacity bucket regions of tmp. One global atomic per
// (block,bucket); packed word = (src<<8) | (dst&255). 16 edges/thread via
// int4 loads; dst stashed in registers across the reservation barrier.
__global__ __launch_bounds__(256) void k_bin(const int* __restrict__ src,
                                             const int* __restrict__ dst,
                                             int* __restrict__ gCursor,
                                             unsigned int* __restrict__ tmp,
                                             int E, int NBUK) {
    __shared__ int lcnt[NBUK_MAX];
    __shared__ int lcur[NBUK_MAX];
    int tid = threadIdx.x;
    int base = blockIdx.x * BIN_CHUNK;
    for (int i = tid; i < NBUK; i += 256) lcnt[i] = 0;
    __syncthreads();
    int d[16];
    #pragma unroll
    for (int q = 0; q < 4; q++) {
        int e = base + q * 1024 + 4 * tid;
        if (e + 3 < E) {
            int4 v = *(const int4*)&dst[e];
            d[4 * q + 0] = v.x; d[4 * q + 1] = v.y;
            d[4 * q + 2] = v.z; d[4 * q + 3] = v.w;
        } else {
            #pragma unroll
            for (int k = 0; k < 4; k++)
                d[4 * q + k] = (e + k < E) ? dst[e + k] : -1;
        }
    }
    #pragma unroll
    for (int k = 0; k < 16; k++)
        if (d[k] >= 0) atomicAdd(&lcnt[d[k] >> 8], 1);
    __syncthreads();
    for (int b = tid; b < NBUK; b += 256) {
        int c = lcnt[b];
        lcur[b] = c ? b * BUK_CAP + atomicAdd(&gCursor[b], c) : 0;
    }
    __syncthreads();
    #pragma unroll
    for (int q = 0; q < 4; q++) {
        int e = base + q * 1024 + 4 * tid;
        int s[4];
        if (e + 3 < E) {
            int4 v = *(const int4*)&src[e];
            s[0] = v.x; s[1] = v.y; s[2] = v.z; s[3] = v.w;
        } else {
            #pragma unroll
            for (int k = 0; k < 4; k++)
                s[k] = (e + k < E) ? src[e + k] : 0;
        }
        #pragma unroll
        for (int k = 0; k < 4; k++) {
            int dd = d[4 * q + k];
            if (dd >= 0) {
                int p = atomicAdd(&lcur[dd >> 8], 1);
                tmp[p] = ((unsigned int)s[k] << 8) | (unsigned int)(dd & 255);
            }
        }
    }
}

// Exact CSR fill within a bucket (padded layout, base = b*BUK_CAP).
// 512 threads; count pass reads tmp as uint4.
__global__ __launch_bounds__(512) void k_fill2(const unsigned int* __restrict__ tmp,
                                               const int* __restrict__ gCursor,
                                               int* __restrict__ rowptr,
                                               int* __restrict__ rowEnd,
                                               int* __restrict__ csr, int N) {
    __shared__ int cnt[256];
    __shared__ int cur[256];
    __shared__ int wsum[4];
    int b = blockIdx.x, tid = threadIdx.x;
    int e0 = b * BUK_CAP;
    int cnt_e = gCursor[b];       // bucket edge count
    int e1 = e0 + cnt_e;
    if (tid < 256) cnt[tid] = 0;
    __syncthreads();
    {   // count pass: uint4 over the bulk (e0 is 16B-aligned: BUK_CAP*4 % 16 == 0)
        int nq = cnt_e >> 2;
        const uint4* t4 = (const uint4*)(tmp + e0);
        for (int q = tid; q < nq; q += 512) {
            uint4 v = t4[q];
            atomicAdd(&cnt[v.x & 255u], 1);
            atomicAdd(&cnt[v.y & 255u], 1);
            atomicAdd(&cnt[v.z & 255u], 1);
            atomicAdd(&cnt[v.w & 255u], 1);
        }
        for (int i = (nq << 2) + tid; i < cnt_e; i += 512)
            atomicAdd(&cnt[tmp[e0 + i] & 255u], 1);
    }
    __syncthreads();
    if (tid < 256) {
        int lane = tid & 63, wv = tid >> 6;
        int v = cnt[tid];
        int incl = wave_incl_scan(v, lane);
        if (lane == 63) wsum[wv] = incl;
        cnt[tid] = incl - v;  // stash exclusive-within-wave
    }
    __syncthreads();
    if (tid < 256) {
        int wv = tid >> 6;
        int woff = 0;
        for (int i = 0; i < wv; i++) woff += wsum[i];
        int excl = woff + cnt[tid];
        int node = b * 256 + tid;
        int start = e0 + excl;
        cur[tid] = start;
        if (node < N) {
            rowptr[node] = start;
        }
    }
    __syncthreads();
    // rowEnd[node] = next start (cur of tid+1) or e1 for the last
    if (tid < 256) {
        int node = b * 256 + tid;
        if (node < N) rowEnd[node] = (tid < 255) ? cur[tid + 1] : e1;
    }
    __syncthreads();
    for (int i = e0 + tid; i < e1; i += 512) {
        unsigned int t = tmp[i];
        int p = atomicAdd(&cur[t & 255u], 1);
        csr[p] = (int)(t >> 8);
    }
}

// h1b[n][64](bf16) = [x[n]|topo[n]] @ W1 ; as1/ad1 from fp32 accumulators.
// Block = 64 nodes x 64 cols GEMM tile, K=136. W1 + xT staged in LDS,
// node-minor (conflict-free transpose writes).
__global__ __launch_bounds__(256) void k_xform1(const float* __restrict__ x,
                                                const float* __restrict__ topo,
                                                const float* __restrict__ W1,
                                                const float* __restrict__ asrc,
                                                const float* __restrict__ adst,
                                                ushort_t* __restrict__ h1b,
                                                float* __restrict__ as1,
                                                float* __restrict__ ad1, int N) {
    __shared__ float XT[136 * 64];  // XT[k][node]
    __shared__ float WS[136 * 64];  // WS[k][col]
    int tid = threadIdx.x;
    int n0 = blockIdx.x * 64;
    {   // stage W1: 8704 floats = 2176 float4 (once per block)
        const float4* W4 = (const float4*)W1;
        float4* WS4 = (float4*)WS;
        for (int i = tid; i < 2176; i += 256) WS4[i] = W4[i];
    }
    {   // stage x transposed, node-minor: i = k4*64 + node
        const float4* x4 = (const float4*)x;
        for (int i = tid; i < 2048; i += 256) {
            int node = i & 63, k4 = i >> 6;
            int gn = n0 + node; if (gn > N - 1) gn = N - 1;
            float4 v = x4[(size_t)gn * 32 + k4];
            int k = k4 * 4;
            XT[(k + 0) * 64 + node] = v.x;
            XT[(k + 1) * 64 + node] = v.y;
            XT[(k + 2) * 64 + node] = v.z;
            XT[(k + 3) * 64 + node] = v.w;
        }
        // topo rows 128..135: i = j4*64 + node, j4 in {0,1}
        const float4* t4 = (const float4*)topo;
        if (tid < 128) {
            int node = tid & 63, j4 = tid >> 6;
            int gn = n0 + node; if (gn > N - 1) gn = N - 1;
            float4 v = t4[(size_t)gn * 2 + j4];
            int k = 128 + j4 * 4;
            XT[(k + 0) * 64 + node] = v.x;
            XT[(k + 1) * 64 + node] = v.y;
            XT[(k + 2) * 64 + node] = v.z;
            XT[(k + 3) * 64 + node] = v.w;
        }
    }
    __syncthreads();
    int ci = tid & 15, ni = tid >> 4;
    int nb = ni * 4, cb = ci * 4;
    float acc[16];
    #pragma unroll
    for (int i = 0; i < 16; i++) acc[i] = 0.f;
    #pragma unroll 4
    for (int k = 0; k < 136; k++) {
        float4 xv = *(const float4*)&XT[k * 64 + nb];
        float4 wv = *(const float4*)&WS[k * 64 + cb];
        acc[0]  = fmaf(xv.x, wv.x, acc[0]);  acc[1]  = fmaf(xv.x, wv.y, acc[1]);
        acc[2]  = fmaf(xv.x, wv.z, acc[2]);  acc[3]  = fmaf(xv.x, wv.w, acc[3]);
        acc[4]  = fmaf(xv.y, wv.x, acc[4]);  acc[5]  = fmaf(xv.y, wv.y, acc[5]);
        acc[6]  = fmaf(xv.y, wv.z, acc[6]);  acc[7]  = fmaf(xv.y, wv.w, acc[7]);
        acc[8]  = fmaf(xv.z, wv.x, acc[8]);  acc[9]  = fmaf(xv.z, wv.y, acc[9]);
        acc[10] = fmaf(xv.z, wv.z, acc[10]); acc[11] = fmaf(xv.z, wv.w, acc[11]);
        acc[12] = fmaf(xv.w, wv.x, acc[12]); acc[13] = fmaf(xv.w, wv.y, acc[13]);
        acc[14] = fmaf(xv.w, wv.z, acc[14]); acc[15] = fmaf(xv.w, wv.w, acc[15]);
    }
    int head = cb >> 3;  // cols cb..cb+3 lie in one head (cb multiple of 4)
    #pragma unroll
    for (int i = 0; i < 4; i++) {
        int n = n0 + nb + i;
        unsigned int p0 = f2bf(acc[i * 4 + 0]) | (f2bf(acc[i * 4 + 1]) << 16);
        unsigned int p1 = f2bf(acc[i * 4 + 2]) | (f2bf(acc[i * 4 + 3]) << 16);
        if (n < N) *(uint2*)&h1b[(size_t)n * 64 + cb] = make_uint2(p0, p1);
        float s = 0.f, d = 0.f;
        #pragma unroll
        for (int j = 0; j < 4; j++) {
            s = fmaf(acc[i * 4 + j], asrc[cb + j], s);
            d = fmaf(acc[i * 4 + j], adst[cb + j], d);
        }
        s += __shfl_xor(s, 1);  // combine the two half-head threads
        d += __shfl_xor(d, 1);
        if ((ci & 1) == 0 && n < N) {
            as1[n * 8 + head] = s;
            ad1[n * 8 + head] = d;
        }
    }
}

// NOTE: parameter names W_/U_ must not collide with vector members .x/.y/.z/.w
#define AGG_FMA(W_, U_)                                           \
    {                                                             \
        acc[0] = fmaf(W_, bf_lo(U_.x), acc[0]);                   \
        acc[1] = fmaf(W_, bf_hi(U_.x), acc[1]);                   \
        acc[2] = fmaf(W_, bf_lo(U_.y), acc[2]);                   \
        acc[3] = fmaf(W_, bf_hi(U_.y), acc[3]);                   \
        acc[4] = fmaf(W_, bf_lo(U_.z), acc[4]);                   \
        acc[5] = fmaf(W_, bf_hi(U_.z), acc[5]);                   \
        acc[6] = fmaf(W_, bf_lo(U_.w), acc[6]);                   \
        acc[7] = fmaf(W_, bf_hi(U_.w), acc[7]);                   \
        z += W_;                                                  \
    }

// Three masked 8-edge chunks (base chunk B_, B_+1, B_+2): all se/av/u gathers
// issue before any exp/FMA — one memory round trip for 24 edges.
#define AGG1_C3(B_)                                                        \
    {                                                                      \
        int e0 = (B_) * 8 + g, e1 = e0 + 8, e2 = e0 + 16;                  \
        int se0 = __shfl(cv, e0 < d ? e0 : dm1);                           \
        int se1 = __shfl(cv, e1 < d ? e1 : dm1);                           \
        int se2 = __shfl(cv, e2 < d ? e2 : dm1);                           \
        float av0 = as1[se0 * 8 + head];                                   \
        float av1 = as1[se1 * 8 + head];                                   \
        float av2 = as1[se2 * 8 + head];                                   \
        uint4 u0 = *(const uint4*)(h1c + (((unsigned)se0 << 7) + hoff));   \
        uint4 u1 = *(const uint4*)(h1c + (((unsigned)se1 << 7) + hoff));   \
        uint4 u2 = *(const uint4*)(h1c + (((unsigned)se2 << 7) + hoff));   \
        float w0 = e0 < d ? lrelu_exp(av0 + adv) : 0.f;                    \
        float w1 = e1 < d ? lrelu_exp(av1 + adv) : 0.f;                    \
        float w2 = e2 < d ? lrelu_exp(av2 + adv) : 0.f;                    \
        AGG_FMA(w0, u0);                                                   \
        AGG_FMA(w1, u1);                                                   \
        AGG_FMA(w2, u2);                                                   \
    }

// Per-dst softmax-weighted aggregation, layer 1 (+ implicit self loop).
// 8 groups x 8 lanes on 128B rows; TWO memory round trips total:
// (1) one wave-wide csr load covering the whole adjacency row (<=64 edges),
// (2) all as1 + h1b gathers for the masked chunks issued back-to-back.
// Wave-uniform deg branches: 0..24 / 24..48 / 48..64 / >64 fallback loop.
__global__ __launch_bounds__(256) void k_agg1(const ushort_t* __restrict__ h1b,
                                              const float* __restrict__ as1,
                                              const float* __restrict__ ad1,
                                              const float* __restrict__ b1,
                                              const int* __restrict__ rowptr,
                                              const int* __restrict__ rowEnd,
                                              const int* __restrict__ csr,
                                              float* __restrict__ h2, int N) {
    int tid = threadIdx.x, lane = tid & 63;
    int n = blockIdx.x * 4 + (tid >> 6);
    if (n >= N) return;
    int g = lane >> 3;      // edge slot within chunk
    int head = lane & 7;    // head (cols 8h..8h+7)
    const char* h1c = (const char*)h1b;
    unsigned hoff = (unsigned)head << 4;   // 16B per head block
    float adv = ad1[n * 8 + head];
    float acc[8];
    #pragma unroll
    for (int k = 0; k < 8; k++) acc[k] = 0.f;
    float z = 0.f;

    int j0 = rowptr[n], j1 = rowEnd[n];
    int d = j1 - j0;
    int dm1 = d > 0 ? d - 1 : 0;
    // ONE wave-wide csr load covers up to 64 edges (clamped duplicates ok)
    int cv = (d > 0) ? csr[j0 + (lane < d ? lane : dm1)] : 0;

    {   // self loop (group 0 only)
        float w = lrelu_exp(as1[n * 8 + head] + adv);
        if (g == 0) {
            uint4 u = *(const uint4*)(h1c + (((unsigned)n << 7) + hoff));
            acc[0] = w * bf_lo(u.x); acc[1] = w * bf_hi(u.x);
            acc[2] = w * bf_lo(u.y); acc[3] = w * bf_hi(u.y);
            acc[4] = w * bf_lo(u.z); acc[5] = w * bf_hi(u.z);
            acc[6] = w * bf_lo(u.w); acc[7] = w * bf_hi(u.w);
            z = w;
        }
    }
    if (d > 0) {
        AGG1_C3(0);                    // edges 0..23 (covers ~98% of nodes)
        if (d > 24) {
            AGG1_C3(3);                // edges 24..47
            if (d > 48) {              // edges 48..63 from cv
                int e0 = 48 + g, e1 = 56 + g;
                int se0 = __shfl(cv, e0 < d ? e0 : dm1);
                int se1 = __shfl(cv, e1 < d ? e1 : dm1);
                float av0 = as1[se0 * 8 + head];
                float av1 = as1[se1 * 8 + head];
                uint4 u0 = *(const uint4*)(h1c + (((unsigned)se0 << 7) + hoff));
                uint4 u1 = *(const uint4*)(h1c + (((unsigned)se1 << 7) + hoff));
                float w0 = e0 < d ? lrelu_exp(av0 + adv) : 0.f;
                float w1 = e1 < d ? lrelu_exp(av1 + adv) : 0.f;
                AGG_FMA(w0, u0);
                AGG_FMA(w1, u1);
                // d > 64: fallback loop with fresh csr loads (correctness)
                for (int j = j0 + 64; j < j1; j += 8) {
                    int m = j1 - j;
                    int idx = (lane & 7); idx = idx < m ? idx : m - 1;
                    int cvt = csr[j + idx];
                    int ge = g < m ? g : m - 1;
                    int se = __shfl(cvt, ge);
                    float av = as1[se * 8 + head];
                    uint4 u = *(const uint4*)(h1c + (((unsigned)se << 7) + hoff));
                    float w = (g < m) ? lrelu_exp(av + adv) : 0.f;
                    AGG_FMA(w, u);
                }
            }
        }
    }
    // reduce across the 8 edge-slot groups (lanes differing in bits 3..5)
    #pragma unroll
    for (int k = 0; k < 8; k++) {
        acc[k] += __shfl_xor(acc[k], 8);
        acc[k] += __shfl_xor(acc[k], 16);
        acc[k] += __shfl_xor(acc[k], 32);
    }
    z += __shfl_xor(z, 8); z += __shfl_xor(z, 16); z += __shfl_xor(z, 32);
    if (g == 0) {
        float inv = 1.f / (z + 1e-16f);
        float o[8];
        #pragma unroll
        for (int k = 0; k < 8; k++) {
            float v = acc[k] * inv + b1[head * 8 + k];
            o[k] = v > 0.f ? v : (__expf(v) - 1.f);
        }
        float4* dp = (float4*)&h2[(size_t)n * 64 + head * 8];
        dp[0] = make_float4(o[0], o[1], o[2], o[3]);
        dp[1] = make_float4(o[4], o[5], o[6], o[7]);
    }
}

// gb[n][40](bf16) = h2[n] @ W2 ; as2/ad2 from fp32 accumulators.
// Block = 64 nodes x 40 cols GEMM tile, K=64. Node-minor staging.
__global__ __launch_bounds__(256) void k_xform2(const float* __restrict__ h2,
                                                const float* __restrict__ W2,
                                                const float* __restrict__ asrc2,
                                                const float* __restrict__ adst2,
                                                ushort_t* __restrict__ gb,
                                                float* __restrict__ as2,
                                                float* __restrict__ ad2, int N) {
    __shared__ float XT[64 * 64];  // h2T[k][node]
    __shared__ float WS[64 * 40];  // WS[k][col]
    int tid = threadIdx.x;
    int n0 = blockIdx.x * 64;
    {   // stage W2: 2560 floats = 640 float4
        const float4* W4 = (const float4*)W2;
        float4* WS4 = (float4*)WS;
        for (int i = tid; i < 640; i += 256) WS4[i] = W4[i];
    }
    {   // stage h2 transposed, node-minor: i = k4*64 + node
        const float4* h4 = (const float4*)h2;
        for (int i = tid; i < 1024; i += 256) {
            int node = i & 63, k4 = i >> 6;
            int gn = n0 + node; if (gn > N - 1) gn = N - 1;
            float4 v = h4[(size_t)gn * 16 + k4];
            int k = k4 * 4;
            XT[(k + 0) * 64 + node] = v.x;
            XT[(k + 1) * 64 + node] = v.y;
            XT[(k + 2) * 64 + node] = v.z;
            XT[(k + 3) * 64 + node] = v.w;
        }
    }
    __syncthreads();
    int ci = tid & 15, ni = tid >> 4;
    int nb = ni * 4, cb = ci * 4;
    float acc[16];
    #pragma unroll
    for (int i = 0; i < 16; i++) acc[i] = 0.f;
    if (ci < 10) {
        #pragma unroll 4
        for (int k = 0; k < 64; k++) {
            float4 xv = *(const float4*)&XT[k * 64 + nb];
            float4 wv = *(const float4*)&WS[k * 40 + cb];
            acc[0]  = fmaf(xv.x, wv.x, acc[0]);  acc[1]  = fmaf(xv.x, wv.y, acc[1]);
            acc[2]  = fmaf(xv.x, wv.z, acc[2]);  acc[3]  = fmaf(xv.x, wv.w, acc[3]);
            acc[4]  = fmaf(xv.y, wv.x, acc[4]);  acc[5]  = fmaf(xv.y, wv.y, acc[5]);
            acc[6]  = fmaf(xv.y, wv.z, acc[6]);  acc[7]  = fmaf(xv.y, wv.w, acc[7]);
            acc[8]  = fmaf(xv.z, wv.x, acc[8]);  acc[9]  = fmaf(xv.z, wv.y, acc[9]);
            acc[10] = fmaf(xv.z, wv.z, acc[10]); acc[11] = fmaf(xv.z, wv.w, acc[11]);
            acc[12] = fmaf(xv.w, wv.x, acc[12]); acc[13] = fmaf(xv.w, wv.y, acc[13]);
            acc[14] = fmaf(xv.w, wv.z, acc[14]); acc[15] = fmaf(xv.w, wv.w, acc[15]);
        }
    }
    #pragma unroll
    for (int i = 0; i < 4; i++) {
        int n = n0 + nb + i;
        if (ci < 10 && n < N) {
            unsigned int p0 = f2bf(acc[i * 4 + 0]) | (f2bf(acc[i * 4 + 1]) << 16);
            unsigned int p1 = f2bf(acc[i * 4 + 2]) | (f2bf(acc[i * 4 + 3]) << 16);
            *(uint2*)&gb[(size_t)n * 40 + cb] = make_uint2(p0, p1);  // 80B rows
        }
        float s = 0.f, d = 0.f;
        if (ci < 10) {
            #pragma unroll
            for (int j = 0; j < 4; j++) {
                s = fmaf(acc[i * 4 + j], asrc2[cb + j], s);
                d = fmaf(acc[i * 4 + j], adst2[cb + j], d);
            }
        }
        // reduce over the 16-lane ci group (ci>=10 contribute 0)
        s += __shfl_xor(s, 1); s += __shfl_xor(s, 2);
        s += __shfl_xor(s, 4); s += __shfl_xor(s, 8);
        d += __shfl_xor(d, 1); d += __shfl_xor(d, 2);
        d += __shfl_xor(d, 4); d += __shfl_xor(d, 8);
        if (ci == 0 && n < N) { as2[n] = s; ad2[n] = d; }
    }
}

// Two masked 12-edge chunks (chunks B_, B_+1): ONE as2 gather per chunk per
// lane + all 8 gb row gathers issue before any exp/FMA.
#define AGG2_C2(B_)                                                            \
    {                                                                          \
        int ew0 = (B_) * 12 + lm12, ew1 = ew0 + 12;                            \
        int sw0 = __shfl(cv, ew0 < d ? ew0 : dm1);                             \
        int sw1 = __shfl(cv, ew1 < d ? ew1 : dm1);                             \
        float av0 = as2[sw0];                                                  \
        float av1 = as2[sw1];                                                  \
        int e00 = (B_) * 12 + gi0, e01 = (B_) * 12 + gi1;                      \
        int e02 = (B_) * 12 + gi2, e03 = (B_) * 12 + gi3;                      \
        int s00 = __shfl(cv, e00 < d ? e00 : dm1);                             \
        int s01 = __shfl(cv, e01 < d ? e01 : dm1);                             \
        int s02 = __shfl(cv, e02 < d ? e02 : dm1);                             \
        int s03 = __shfl(cv, e03 < d ? e03 : dm1);                             \
        int s10 = __shfl(cv, e00 + 12 < d ? e00 + 12 : dm1);                   \
        int s11 = __shfl(cv, e01 + 12 < d ? e01 + 12 : dm1);                   \
        int s12 = __shfl(cv, e02 + 12 < d ? e02 + 12 : dm1);                   \
        int s13 = __shfl(cv, e03 + 12 < d ? e03 + 12 : dm1);                   \
        unsigned int u00 = *(const unsigned int*)(gbc + ((unsigned)s00 * 80u + coff)); \
        unsigned int u01 = *(const unsigned int*)(gbc + ((unsigned)s01 * 80u + coff)); \
        unsigned int u02 = *(const unsigned int*)(gbc + ((unsigned)s02 * 80u + coff)); \
        unsigned int u03 = *(const unsigned int*)(gbc + ((unsigned)s03 * 80u + coff)); \
        unsigned int u10 = *(const unsigned int*)(gbc + ((unsigned)s10 * 80u + coff)); \
        unsigned int u11 = *(const unsigned int*)(gbc + ((unsigned)s11 * 80u + coff)); \
        unsigned int u12 = *(const unsigned int*)(gbc + ((unsigned)s12 * 80u + coff)); \
        unsigned int u13 = *(const unsigned int*)(gbc + ((unsigned)s13 * 80u + coff)); \
        float wall0 = (ew0 < d) ? lrelu_exp(av0 + add) : 0.f;                  \
        float wall1 = (ew1 < d) ? lrelu_exp(av1 + add) : 0.f;                  \
        float w00 = __shfl(wall0, gi0), w01 = __shfl(wall0, gi1);              \
        float w02 = __shfl(wall0, gi2), w03 = __shfl(wall0, gi3);              \
        float w10 = __shfl(wall1, gi0), w11 = __shfl(wall1, gi1);              \
        float w12 = __shfl(wall1, gi2), w13 = __shfl(wall1, gi3);              \
        acc0 = fmaf(w00, bf_lo(u00), acc0); acc1 = fmaf(w00, bf_hi(u00), acc1); zl += w00; \
        acc0 = fmaf(w01, bf_lo(u01), acc0); acc1 = fmaf(w01, bf_hi(u01), acc1); zl += w01; \
        acc0 = fmaf(w02, bf_lo(u02), acc0); acc1 = fmaf(w02, bf_hi(u02), acc1); zl += w02; \
        acc0 = fmaf(w03, bf_lo(u03), acc0); acc1 = fmaf(w03, bf_hi(u03), acc1); zl += w03; \
        acc0 = fmaf(w10, bf_lo(u10), acc0); acc1 = fmaf(w10, bf_hi(u10), acc1); zl += w10; \
        acc0 = fmaf(w11, bf_lo(u11), acc0); acc1 = fmaf(w11, bf_hi(u11), acc1); zl += w11; \
        acc0 = fmaf(w12, bf_lo(u12), acc0); acc1 = fmaf(w12, bf_hi(u12), acc1); zl += w12; \
        acc0 = fmaf(w13, bf_lo(u13), acc0); acc1 = fmaf(w13, bf_hi(u13), acc1); zl += w13; \
    }

// Layer-2 aggregation + bias + log_softmax. 3 groups x 20 lanes on 80B rows
// (R1-verified mapping) + R21 round-trip collapse: one wave-wide csr load
// covers the whole row; masked 24-edge double-chunks issue all gathers
// before compute. Wave-uniform branches: 0..24 / 24..48 / >48 fallback.
__global__ __launch_bounds__(256) void k_agg2(const ushort_t* __restrict__ gb,
                                              const float* __restrict__ as2,
                                              const float* __restrict__ ad2,
                                              const float* __restrict__ b2,
                                              const int* __restrict__ rowptr,
                                              const int* __restrict__ rowEnd,
                                              const int* __restrict__ csr,
                                              float* __restrict__ out, int N) {
    int tid = threadIdx.x, lane = tid & 63;
    int n = blockIdx.x * 4 + (tid >> 6);
    if (n >= N) return;
    int g = lane / 20, p = lane % 20;  // g==3 for lanes 60-63 (results unread)
    int c0 = 2 * p;
    const char* gbc = (const char*)gb;
    unsigned coff = (unsigned)(p << 2);
    int lm12 = lane % 12;
    int gi0 = (0 + g) < 12 ? (0 + g) : 11;   // clamp for g==3 lanes
    int gi1 = (3 + g) < 12 ? (3 + g) : 11;
    int gi2 = (6 + g) < 12 ? (6 + g) : 11;
    int gi3 = (9 + g) < 12 ? (9 + g) : 11;
    float add = ad2[n];
    float acc0 = 0.f, acc1 = 0.f, zl = 0.f;

    int j0 = rowptr[n], j1 = rowEnd[n];
    int d = j1 - j0;
    int dm1 = d > 0 ? d - 1 : 0;
    // ONE wave-wide csr load covers up to 64 edges
    int cv = (d > 0) ? csr[j0 + (lane < d ? lane : dm1)] : 0;

    {   // self loop (group 0 only)
        float e0 = as2[n] + add;
        float w = lrelu_exp(e0);
        if (g == 0) {
            unsigned int u = *(const unsigned int*)(gbc + ((unsigned)n * 80u + coff));
            acc0 = w * bf_lo(u); acc1 = w * bf_hi(u); zl = w;
        }
    }
    if (d > 0) {
        AGG2_C2(0);                    // edges 0..23 (covers ~98% of nodes)
        if (d > 24) {
            AGG2_C2(2);                // edges 24..47
            if (d > 48) {
                // edges 48.. : fallback loop with fresh csr loads (~never)
                for (int j = j0 + 48; j < j1; j += 12) {
                    int m = j1 - j;
                    int idx = lm12 < m ? lm12 : m - 1;
                    int cvt = csr[j + idx];
                    float av = as2[cvt];
                    float wall = (lm12 < m) ? lrelu_exp(av + add) : 0.f;
                    #pragma unroll
                    for (int i = 0; i < 4; i++) {
                        int e = 3 * i + g;
                        int gi = e < 12 ? e : 11;
                        int gim = gi < m ? gi : m - 1;
                        int s = __shfl(cvt, gim);
                        unsigned int u = *(const unsigned int*)(gbc + ((unsigned)s * 80u + coff));
                        float w = __shfl(wall, gi);  // 0 for e >= m
                        acc0 = fmaf(w, bf_lo(u), acc0);
                        acc1 = fmaf(w, bf_hi(u), acc1);
                        zl += w;
                    }
                }
            }
        }
    }
    // combine the 3 groups (valid at lanes 0..19)
    float A0 = acc0 + __shfl(acc0, (lane + 20) & 63) + __shfl(acc0, (lane + 40) & 63);
    float A1 = acc1 + __shfl(acc1, (lane + 20) & 63) + __shfl(acc1, (lane + 40) & 63);
    float Z  = zl + __shfl(zl, (lane + 20) & 63) + __shfl(zl, (lane + 40) & 63);
    float l0 = 0.f, l1 = 0.f;
    bool active = (lane < 20);
    if (active) {
        float inv = 1.f / (Z + 1e-16f);
        l0 = A0 * inv + b2[c0];
        l1 = A1 * inv + b2[c0 + 1];
    }
    // masked 32-lane butterfly for max and sum-exp over the 40 logits
    float mv = active ? fmaxf(l0, l1) : -INFINITY;
    #pragma unroll
    for (int ofs = 1; ofs < 32; ofs <<= 1) mv = fmaxf(mv, __shfl_xor(mv, ofs));
    float ev = active ? (__expf(l0 - mv) + __expf(l1 - mv)) : 0.f;
    #pragma unroll
    for (int ofs = 1; ofs < 32; ofs <<= 1) ev += __shfl_xor(ev, ofs);
    if (active) {
        float ls = mv + __logf(ev);
        *(float2*)&out[(size_t)n * 40 + c0] = make_float2(l0 - ls, l1 - ls);
    }
}

extern "C" void kernel_launch(void* const* d_in, const int* in_sizes, int n_in,
                              void* d_out, int out_size, void* d_ws, size_t ws_size,
                              hipStream_t stream) {
    const float* x    = (const float*)d_in[0];
    const float* topo = (const float*)d_in[1];
    const int*   ei   = (const int*)d_in[2];
    const float* W1   = (const float*)d_in[3];
    const float* a_s1 = (const float*)d_in[4];
    const float* a_d1 = (const float*)d_in[5];
    const float* b1   = (const float*)d_in[6];
    const float* W2   = (const float*)d_in[7];
    const float* a_s2 = (const float*)d_in[8];
    const float* a_d2 = (const float*)d_in[9];
    const float* b2   = (const float*)d_in[10];
    float* out = (float*)d_out;

    int N = in_sizes[0] / 128;
    int E = in_sizes[2] / 2;
    const int* esrc = ei;
    const int* edst = ei + E;
    int NBUK = (N + 255) / 256;
    size_t cap = (size_t)NBUK * BUK_CAP;

    char* ws = (char*)d_ws;
    size_t off = 0;
    auto alloc = [&](size_t bytes) -> void* {
        void* p = ws + off;
        off = (off + bytes + 255) & ~(size_t)255;
        return p;
    };
    ushort_t* h1b  = (ushort_t*)alloc((size_t)N * 64 * 2);
    float* as1     = (float*)alloc((size_t)N * 8 * 4);
    float* ad1     = (float*)alloc((size_t)N * 8 * 4);
    float* h2      = (float*)alloc((size_t)N * 64 * 4);
    ushort_t* gb   = (ushort_t*)alloc((size_t)N * 40 * 2);  // 80B rows
    float* as2     = (float*)alloc((size_t)N * 4);
    float* ad2     = (float*)alloc((size_t)N * 4);
    int*   rowptr  = (int*)alloc((size_t)N * 4);
    int*   rowEnd  = (int*)alloc((size_t)N * 4);
    int*   csr     = (int*)alloc(cap * 4);
    unsigned int* tmp = (unsigned int*)alloc(cap * 4);
    int* gCursor   = (int*)alloc((size_t)NBUK * 4);

    hipMemsetAsync(gCursor, 0, (size_t)NBUK * 4, stream);  // count-based cursors
    int nbin = (E + BIN_CHUNK - 1) / BIN_CHUNK;
    k_bin<<<nbin, 256, 0, stream>>>(esrc, edst, gCursor, tmp, E, NBUK);
    k_fill2<<<NBUK, 512, 0, stream>>>(tmp, gCursor, rowptr, rowEnd, csr, N);

    int nbg = (N + 63) / 64;  // 64-node GEMM tiles
    int nb4 = (N + 3) / 4;    // 1 node/wave x 4 waves/block
    k_xform1<<<nbg, 256, 0, stream>>>(x, topo, W1, a_s1, a_d1, h1b, as1, ad1, N);
    k_agg1<<<nb4, 256, 0, stream>>>(h1b, as1, ad1, b1, rowptr, rowEnd, csr, h2, N);
    k_xform2<<<nbg, 256, 0, stream>>>(h2, W2, a_s2, a_d2, gb, as2, ad2, N);
    k_agg2<<<nb4, 256, 0, stream>>>(gb, as2, ad2, b2, rowptr, rowEnd, csr, out, N);
}

// Round 9
// 291.602 us; speedup vs baseline: 1.0852x; 1.0087x over previous
//
#include <hip/hip_runtime.h>
#include <math.h>

// ---------------------------------------------------------------------------
// TopoGAT: 2-layer GAT on MI355X.
// R10: fixed-capacity bucket CSR build; padded CSR with rowptr/rowEnd.
// R5:  gather tables h1/g in bf16.
// R7/R12: xform = LDS-tiled GEMM, node-minor staging (conflict-free).
// R14: CSR build — k_bin BIN_CHUNK=4096; k_fill2 512thr + uint4 count pass.
// R21: k_agg1 -> 2 round trips (one wave-wide csr load + all gathers
//      up-front): 61.4 -> 54.0us, total 308.8 -> 300.0. VERIFIED.
// R22: same collapse in k_agg2: 59.4 -> <54us, total -> 294.1. VERIFIED.
//      Post-R22 profile: k_agg1 top at 54.0us, VALUBusy 72-74% => now
//      VALU-BOUND. Straight-line 24-edge path wastes ~35% of edge VALU on
//      clamped w=0 slots (deg~Poisson(16): avg useful 16, processed ~25).
// R23: k_agg1 keeps the 1-RT gather structure (all 9 gathers up front,
//      unconditional) but the exp+FMA blocks for chunks 1/2 go behind
//      wave-uniform d>8 / d>16 branches (d known before gathers return —
//      no added round trip). Same treatment inside the rare d>24 region.
//      RISK: if LLVM sinks u1/u2 gathers into the branches the RT chain
//      returns (dur -> ~61); counters will show it.
// ---------------------------------------------------------------------------

#define NBUK_MAX 512
#define BIN_CHUNK 4096
#define BUK_CAP 4608

typedef unsigned short ushort_t;

__device__ inline unsigned int f2bf(float f) {  // RNE fp32->bf16
    unsigned int u = __float_as_uint(f);
    u += 0x7FFFu + ((u >> 16) & 1u);
    return u >> 16;
}
__device__ inline float bf_lo(unsigned int u) {
    return __uint_as_float(u << 16);
}
__device__ inline float bf_hi(unsigned int u) {
    return __uint_as_float(u & 0xFFFF0000u);
}
__device__ inline float lrelu_exp(float q) {
    return __expf(q >= 0.f ? q : 0.2f * q);
}

__device__ inline int wave_incl_scan(int v, int lane) {
    #pragma unroll
    for (int ofs = 1; ofs < 64; ofs <<= 1) {
        int t = __shfl_up(v, ofs);
        if (lane >= ofs) v += t;
    }
    return v;
}

// Bin edges into fixed-capacity bucket regions of tmp. One global atomic per
// (block,bucket); packed word = (src<<8) | (dst&255). 16 edges/thread via
// int4 loads; dst stashed in registers across the reservation barrier.
__global__ __launch_bounds__(256) void k_bin(const int* __restrict__ src,
                                             const int* __restrict__ dst,
                                             int* __restrict__ gCursor,
                                             unsigned int* __restrict__ tmp,
                                             int E, int NBUK) {
    __shared__ int lcnt[NBUK_MAX];
    __shared__ int lcur[NBUK_MAX];
    int tid = threadIdx.x;
    int base = blockIdx.x * BIN_CHUNK;
    for (int i = tid; i < NBUK; i += 256) lcnt[i] = 0;
    __syncthreads();
    int d[16];
    #pragma unroll
    for (int q = 0; q < 4; q++) {
        int e = base + q * 1024 + 4 * tid;
        if (e + 3 < E) {
            int4 v = *(const int4*)&dst[e];
            d[4 * q + 0] = v.x; d[4 * q + 1] = v.y;
            d[4 * q + 2] = v.z; d[4 * q + 3] = v.w;
        } else {
            #pragma unroll
            for (int k = 0; k < 4; k++)
                d[4 * q + k] = (e + k < E) ? dst[e + k] : -1;
        }
    }
    #pragma unroll
    for (int k = 0; k < 16; k++)
        if (d[k] >= 0) atomicAdd(&lcnt[d[k] >> 8], 1);
    __syncthreads();
    for (int b = tid; b < NBUK; b += 256) {
        int c = lcnt[b];
        lcur[b] = c ? b * BUK_CAP + atomicAdd(&gCursor[b], c) : 0;
    }
    __syncthreads();
    #pragma unroll
    for (int q = 0; q < 4; q++) {
        int e = base + q * 1024 + 4 * tid;
        int s[4];
        if (e + 3 < E) {
            int4 v = *(const int4*)&src[e];
            s[0] = v.x; s[1] = v.y; s[2] = v.z; s[3] = v.w;
        } else {
            #pragma unroll
            for (int k = 0; k < 4; k++)
                s[k] = (e + k < E) ? src[e + k] : 0;
        }
        #pragma unroll
        for (int k = 0; k < 4; k++) {
            int dd = d[4 * q + k];
            if (dd >= 0) {
                int p = atomicAdd(&lcur[dd >> 8], 1);
                tmp[p] = ((unsigned int)s[k] << 8) | (unsigned int)(dd & 255);
            }
        }
    }
}

// Exact CSR fill within a bucket (padded layout, base = b*BUK_CAP).
// 512 threads; count pass reads tmp as uint4.
__global__ __launch_bounds__(512) void k_fill2(const unsigned int* __restrict__ tmp,
                                               const int* __restrict__ gCursor,
                                               int* __restrict__ rowptr,
                                               int* __restrict__ rowEnd,
                                               int* __restrict__ csr, int N) {
    __shared__ int cnt[256];
    __shared__ int cur[256];
    __shared__ int wsum[4];
    int b = blockIdx.x, tid = threadIdx.x;
    int e0 = b * BUK_CAP;
    int cnt_e = gCursor[b];       // bucket edge count
    int e1 = e0 + cnt_e;
    if (tid < 256) cnt[tid] = 0;
    __syncthreads();
    {   // count pass: uint4 over the bulk (e0 is 16B-aligned: BUK_CAP*4 % 16 == 0)
        int nq = cnt_e >> 2;
        const uint4* t4 = (const uint4*)(tmp + e0);
        for (int q = tid; q < nq; q += 512) {
            uint4 v = t4[q];
            atomicAdd(&cnt[v.x & 255u], 1);
            atomicAdd(&cnt[v.y & 255u], 1);
            atomicAdd(&cnt[v.z & 255u], 1);
            atomicAdd(&cnt[v.w & 255u], 1);
        }
        for (int i = (nq << 2) + tid; i < cnt_e; i += 512)
            atomicAdd(&cnt[tmp[e0 + i] & 255u], 1);
    }
    __syncthreads();
    if (tid < 256) {
        int lane = tid & 63, wv = tid >> 6;
        int v = cnt[tid];
        int incl = wave_incl_scan(v, lane);
        if (lane == 63) wsum[wv] = incl;
        cnt[tid] = incl - v;  // stash exclusive-within-wave
    }
    __syncthreads();
    if (tid < 256) {
        int wv = tid >> 6;
        int woff = 0;
        for (int i = 0; i < wv; i++) woff += wsum[i];
        int excl = woff + cnt[tid];
        int node = b * 256 + tid;
        int start = e0 + excl;
        cur[tid] = start;
        if (node < N) {
            rowptr[node] = start;
        }
    }
    __syncthreads();
    // rowEnd[node] = next start (cur of tid+1) or e1 for the last
    if (tid < 256) {
        int node = b * 256 + tid;
        if (node < N) rowEnd[node] = (tid < 255) ? cur[tid + 1] : e1;
    }
    __syncthreads();
    for (int i = e0 + tid; i < e1; i += 512) {
        unsigned int t = tmp[i];
        int p = atomicAdd(&cur[t & 255u], 1);
        csr[p] = (int)(t >> 8);
    }
}

// h1b[n][64](bf16) = [x[n]|topo[n]] @ W1 ; as1/ad1 from fp32 accumulators.
// Block = 64 nodes x 64 cols GEMM tile, K=136. W1 + xT staged in LDS,
// node-minor (conflict-free transpose writes).
__global__ __launch_bounds__(256) void k_xform1(const float* __restrict__ x,
                                                const float* __restrict__ topo,
                                                const float* __restrict__ W1,
                                                const float* __restrict__ asrc,
                                                const float* __restrict__ adst,
                                                ushort_t* __restrict__ h1b,
                                                float* __restrict__ as1,
                                                float* __restrict__ ad1, int N) {
    __shared__ float XT[136 * 64];  // XT[k][node]
    __shared__ float WS[136 * 64];  // WS[k][col]
    int tid = threadIdx.x;
    int n0 = blockIdx.x * 64;
    {   // stage W1: 8704 floats = 2176 float4 (once per block)
        const float4* W4 = (const float4*)W1;
        float4* WS4 = (float4*)WS;
        for (int i = tid; i < 2176; i += 256) WS4[i] = W4[i];
    }
    {   // stage x transposed, node-minor: i = k4*64 + node
        const float4* x4 = (const float4*)x;
        for (int i = tid; i < 2048; i += 256) {
            int node = i & 63, k4 = i >> 6;
            int gn = n0 + node; if (gn > N - 1) gn = N - 1;
            float4 v = x4[(size_t)gn * 32 + k4];
            int k = k4 * 4;
            XT[(k + 0) * 64 + node] = v.x;
            XT[(k + 1) * 64 + node] = v.y;
            XT[(k + 2) * 64 + node] = v.z;
            XT[(k + 3) * 64 + node] = v.w;
        }
        // topo rows 128..135: i = j4*64 + node, j4 in {0,1}
        const float4* t4 = (const float4*)topo;
        if (tid < 128) {
            int node = tid & 63, j4 = tid >> 6;
            int gn = n0 + node; if (gn > N - 1) gn = N - 1;
            float4 v = t4[(size_t)gn * 2 + j4];
            int k = 128 + j4 * 4;
            XT[(k + 0) * 64 + node] = v.x;
            XT[(k + 1) * 64 + node] = v.y;
            XT[(k + 2) * 64 + node] = v.z;
            XT[(k + 3) * 64 + node] = v.w;
        }
    }
    __syncthreads();
    int ci = tid & 15, ni = tid >> 4;
    int nb = ni * 4, cb = ci * 4;
    float acc[16];
    #pragma unroll
    for (int i = 0; i < 16; i++) acc[i] = 0.f;
    #pragma unroll 4
    for (int k = 0; k < 136; k++) {
        float4 xv = *(const float4*)&XT[k * 64 + nb];
        float4 wv = *(const float4*)&WS[k * 64 + cb];
        acc[0]  = fmaf(xv.x, wv.x, acc[0]);  acc[1]  = fmaf(xv.x, wv.y, acc[1]);
        acc[2]  = fmaf(xv.x, wv.z, acc[2]);  acc[3]  = fmaf(xv.x, wv.w, acc[3]);
        acc[4]  = fmaf(xv.y, wv.x, acc[4]);  acc[5]  = fmaf(xv.y, wv.y, acc[5]);
        acc[6]  = fmaf(xv.y, wv.z, acc[6]);  acc[7]  = fmaf(xv.y, wv.w, acc[7]);
        acc[8]  = fmaf(xv.z, wv.x, acc[8]);  acc[9]  = fmaf(xv.z, wv.y, acc[9]);
        acc[10] = fmaf(xv.z, wv.z, acc[10]); acc[11] = fmaf(xv.z, wv.w, acc[11]);
        acc[12] = fmaf(xv.w, wv.x, acc[12]); acc[13] = fmaf(xv.w, wv.y, acc[13]);
        acc[14] = fmaf(xv.w, wv.z, acc[14]); acc[15] = fmaf(xv.w, wv.w, acc[15]);
    }
    int head = cb >> 3;  // cols cb..cb+3 lie in one head (cb multiple of 4)
    #pragma unroll
    for (int i = 0; i < 4; i++) {
        int n = n0 + nb + i;
        unsigned int p0 = f2bf(acc[i * 4 + 0]) | (f2bf(acc[i * 4 + 1]) << 16);
        unsigned int p1 = f2bf(acc[i * 4 + 2]) | (f2bf(acc[i * 4 + 3]) << 16);
        if (n < N) *(uint2*)&h1b[(size_t)n * 64 + cb] = make_uint2(p0, p1);
        float s = 0.f, d = 0.f;
        #pragma unroll
        for (int j = 0; j < 4; j++) {
            s = fmaf(acc[i * 4 + j], asrc[cb + j], s);
            d = fmaf(acc[i * 4 + j], adst[cb + j], d);
        }
        s += __shfl_xor(s, 1);  // combine the two half-head threads
        d += __shfl_xor(d, 1);
        if ((ci & 1) == 0 && n < N) {
            as1[n * 8 + head] = s;
            ad1[n * 8 + head] = d;
        }
    }
}

// NOTE: parameter names W_/U_ must not collide with vector members .x/.y/.z/.w
#define AGG_FMA(W_, U_)                                           \
    {                                                             \
        acc[0] = fmaf(W_, bf_lo(U_.x), acc[0]);                   \
        acc[1] = fmaf(W_, bf_hi(U_.x), acc[1]);                   \
        acc[2] = fmaf(W_, bf_lo(U_.y), acc[2]);                   \
        acc[3] = fmaf(W_, bf_hi(U_.y), acc[3]);                   \
        acc[4] = fmaf(W_, bf_lo(U_.z), acc[4]);                   \
        acc[5] = fmaf(W_, bf_hi(U_.z), acc[5]);                   \
        acc[6] = fmaf(W_, bf_lo(U_.w), acc[6]);                   \
        acc[7] = fmaf(W_, bf_hi(U_.w), acc[7]);                   \
        z += W_;                                                  \
    }

// Per-dst softmax-weighted aggregation, layer 1 (+ implicit self loop).
// 8 groups x 8 lanes on 128B rows; ONE wave-wide csr load + all gathers
// up-front (R21). R23: exp+FMA blocks for chunks 1/2 behind wave-uniform
// d>8 / d>16 branches — gathers stay unconditional (no added round trip),
// dead-slot VALU work skipped.
__global__ __launch_bounds__(256) void k_agg1(const ushort_t* __restrict__ h1b,
                                              const float* __restrict__ as1,
                                              const float* __restrict__ ad1,
                                              const float* __restrict__ b1,
                                              const int* __restrict__ rowptr,
                                              const int* __restrict__ rowEnd,
                                              const int* __restrict__ csr,
                                              float* __restrict__ h2, int N) {
    int tid = threadIdx.x, lane = tid & 63;
    int n = blockIdx.x * 4 + (tid >> 6);
    if (n >= N) return;
    int g = lane >> 3;      // edge slot within chunk
    int head = lane & 7;    // head (cols 8h..8h+7)
    const char* h1c = (const char*)h1b;
    unsigned hoff = (unsigned)head << 4;   // 16B per head block
    float adv = ad1[n * 8 + head];
    float acc[8];
    #pragma unroll
    for (int k = 0; k < 8; k++) acc[k] = 0.f;
    float z = 0.f;

    int j0 = rowptr[n], j1 = rowEnd[n];
    int d = j1 - j0;
    int dm1 = d > 0 ? d - 1 : 0;
    // ONE wave-wide csr load covers up to 64 edges (clamped duplicates ok)
    int cv = (d > 0) ? csr[j0 + (lane < d ? lane : dm1)] : 0;

    {   // self loop (group 0 only)
        float w = lrelu_exp(as1[n * 8 + head] + adv);
        if (g == 0) {
            uint4 u = *(const uint4*)(h1c + (((unsigned)n << 7) + hoff));
            acc[0] = w * bf_lo(u.x); acc[1] = w * bf_hi(u.x);
            acc[2] = w * bf_lo(u.y); acc[3] = w * bf_hi(u.y);
            acc[4] = w * bf_lo(u.z); acc[5] = w * bf_hi(u.z);
            acc[6] = w * bf_lo(u.w); acc[7] = w * bf_hi(u.w);
            z = w;
        }
    }
    if (d > 0) {
        // --- gathers for edges 0..23, unconditional (1 RT) ---
        int e0 = g, e1 = 8 + g, e2 = 16 + g;
        int se0 = __shfl(cv, e0 < d ? e0 : dm1);
        int se1 = __shfl(cv, e1 < d ? e1 : dm1);
        int se2 = __shfl(cv, e2 < d ? e2 : dm1);
        float av0 = as1[se0 * 8 + head];
        float av1 = as1[se1 * 8 + head];
        float av2 = as1[se2 * 8 + head];
        uint4 u0 = *(const uint4*)(h1c + (((unsigned)se0 << 7) + hoff));
        uint4 u1 = *(const uint4*)(h1c + (((unsigned)se1 << 7) + hoff));
        uint4 u2 = *(const uint4*)(h1c + (((unsigned)se2 << 7) + hoff));
        // --- compute: chunk 0 always; chunks 1/2 only if live ---
        {
            float w0 = e0 < d ? lrelu_exp(av0 + adv) : 0.f;
            AGG_FMA(w0, u0);
        }
        if (d > 8) {
            float w1 = e1 < d ? lrelu_exp(av1 + adv) : 0.f;
            AGG_FMA(w1, u1);
        }
        if (d > 16) {
            float w2 = e2 < d ? lrelu_exp(av2 + adv) : 0.f;
            AGG_FMA(w2, u2);
        }
        if (d > 24) {
            // --- gathers for edges 24..47, unconditional within this path ---
            int f0 = 24 + g, f1 = 32 + g, f2 = 40 + g;
            int sf0 = __shfl(cv, f0 < d ? f0 : dm1);
            int sf1 = __shfl(cv, f1 < d ? f1 : dm1);
            int sf2 = __shfl(cv, f2 < d ? f2 : dm1);
            float bv0 = as1[sf0 * 8 + head];
            float bv1 = as1[sf1 * 8 + head];
            float bv2 = as1[sf2 * 8 + head];
            uint4 v0 = *(const uint4*)(h1c + (((unsigned)sf0 << 7) + hoff));
            uint4 v1 = *(const uint4*)(h1c + (((unsigned)sf1 << 7) + hoff));
            uint4 v2 = *(const uint4*)(h1c + (((unsigned)sf2 << 7) + hoff));
            {
                float w0 = f0 < d ? lrelu_exp(bv0 + adv) : 0.f;
                AGG_FMA(w0, v0);
            }
            if (d > 32) {
                float w1 = f1 < d ? lrelu_exp(bv1 + adv) : 0.f;
                AGG_FMA(w1, v1);
            }
            if (d > 40) {
                float w2 = f2 < d ? lrelu_exp(bv2 + adv) : 0.f;
                AGG_FMA(w2, v2);
            }
            if (d > 48) {              // edges 48..63 from cv
                int q0 = 48 + g, q1 = 56 + g;
                int sq0 = __shfl(cv, q0 < d ? q0 : dm1);
                int sq1 = __shfl(cv, q1 < d ? q1 : dm1);
                float cv0 = as1[sq0 * 8 + head];
                float cv1 = as1[sq1 * 8 + head];
                uint4 y0 = *(const uint4*)(h1c + (((unsigned)sq0 << 7) + hoff));
                uint4 y1 = *(const uint4*)(h1c + (((unsigned)sq1 << 7) + hoff));
                float w0 = q0 < d ? lrelu_exp(cv0 + adv) : 0.f;
                float w1 = q1 < d ? lrelu_exp(cv1 + adv) : 0.f;
                AGG_FMA(w0, y0);
                AGG_FMA(w1, y1);
                // d > 64: fallback loop with fresh csr loads (correctness)
                for (int j = j0 + 64; j < j1; j += 8) {
                    int m = j1 - j;
                    int idx = (lane & 7); idx = idx < m ? idx : m - 1;
                    int cvt = csr[j + idx];
                    int ge = g < m ? g : m - 1;
                    int se = __shfl(cvt, ge);
                    float av = as1[se * 8 + head];
                    uint4 u = *(const uint4*)(h1c + (((unsigned)se << 7) + hoff));
                    float w = (g < m) ? lrelu_exp(av + adv) : 0.f;
                    AGG_FMA(w, u);
                }
            }
        }
    }
    // reduce across the 8 edge-slot groups (lanes differing in bits 3..5)
    #pragma unroll
    for (int k = 0; k < 8; k++) {
        acc[k] += __shfl_xor(acc[k], 8);
        acc[k] += __shfl_xor(acc[k], 16);
        acc[k] += __shfl_xor(acc[k], 32);
    }
    z += __shfl_xor(z, 8); z += __shfl_xor(z, 16); z += __shfl_xor(z, 32);
    if (g == 0) {
        float inv = 1.f / (z + 1e-16f);
        float o[8];
        #pragma unroll
        for (int k = 0; k < 8; k++) {
            float v = acc[k] * inv + b1[head * 8 + k];
            o[k] = v > 0.f ? v : (__expf(v) - 1.f);
        }
        float4* dp = (float4*)&h2[(size_t)n * 64 + head * 8];
        dp[0] = make_float4(o[0], o[1], o[2], o[3]);
        dp[1] = make_float4(o[4], o[5], o[6], o[7]);
    }
}

// gb[n][40](bf16) = h2[n] @ W2 ; as2/ad2 from fp32 accumulators.
// Block = 64 nodes x 40 cols GEMM tile, K=64. Node-minor staging.
__global__ __launch_bounds__(256) void k_xform2(const float* __restrict__ h2,
                                                const float* __restrict__ W2,
                                                const float* __restrict__ asrc2,
                                                const float* __restrict__ adst2,
                                                ushort_t* __restrict__ gb,
                                                float* __restrict__ as2,
                                                float* __restrict__ ad2, int N) {
    __shared__ float XT[64 * 64];  // h2T[k][node]
    __shared__ float WS[64 * 40];  // WS[k][col]
    int tid = threadIdx.x;
    int n0 = blockIdx.x * 64;
    {   // stage W2: 2560 floats = 640 float4
        const float4* W4 = (const float4*)W2;
        float4* WS4 = (float4*)WS;
        for (int i = tid; i < 640; i += 256) WS4[i] = W4[i];
    }
    {   // stage h2 transposed, node-minor: i = k4*64 + node
        const float4* h4 = (const float4*)h2;
        for (int i = tid; i < 1024; i += 256) {
            int node = i & 63, k4 = i >> 6;
            int gn = n0 + node; if (gn > N - 1) gn = N - 1;
            float4 v = h4[(size_t)gn * 16 + k4];
            int k = k4 * 4;
            XT[(k + 0) * 64 + node] = v.x;
            XT[(k + 1) * 64 + node] = v.y;
            XT[(k + 2) * 64 + node] = v.z;
            XT[(k + 3) * 64 + node] = v.w;
        }
    }
    __syncthreads();
    int ci = tid & 15, ni = tid >> 4;
    int nb = ni * 4, cb = ci * 4;
    float acc[16];
    #pragma unroll
    for (int i = 0; i < 16; i++) acc[i] = 0.f;
    if (ci < 10) {
        #pragma unroll 4
        for (int k = 0; k < 64; k++) {
            float4 xv = *(const float4*)&XT[k * 64 + nb];
            float4 wv = *(const float4*)&WS[k * 40 + cb];
            acc[0]  = fmaf(xv.x, wv.x, acc[0]);  acc[1]  = fmaf(xv.x, wv.y, acc[1]);
            acc[2]  = fmaf(xv.x, wv.z, acc[2]);  acc[3]  = fmaf(xv.x, wv.w, acc[3]);
            acc[4]  = fmaf(xv.y, wv.x, acc[4]);  acc[5]  = fmaf(xv.y, wv.y, acc[5]);
            acc[6]  = fmaf(xv.y, wv.z, acc[6]);  acc[7]  = fmaf(xv.y, wv.w, acc[7]);
            acc[8]  = fmaf(xv.z, wv.x, acc[8]);  acc[9]  = fmaf(xv.z, wv.y, acc[9]);
            acc[10] = fmaf(xv.z, wv.z, acc[10]); acc[11] = fmaf(xv.z, wv.w, acc[11]);
            acc[12] = fmaf(xv.w, wv.x, acc[12]); acc[13] = fmaf(xv.w, wv.y, acc[13]);
            acc[14] = fmaf(xv.w, wv.z, acc[14]); acc[15] = fmaf(xv.w, wv.w, acc[15]);
        }
    }
    #pragma unroll
    for (int i = 0; i < 4; i++) {
        int n = n0 + nb + i;
        if (ci < 10 && n < N) {
            unsigned int p0 = f2bf(acc[i * 4 + 0]) | (f2bf(acc[i * 4 + 1]) << 16);
            unsigned int p1 = f2bf(acc[i * 4 + 2]) | (f2bf(acc[i * 4 + 3]) << 16);
            *(uint2*)&gb[(size_t)n * 40 + cb] = make_uint2(p0, p1);  // 80B rows
        }
        float s = 0.f, d = 0.f;
        if (ci < 10) {
            #pragma unroll
            for (int j = 0; j < 4; j++) {
                s = fmaf(acc[i * 4 + j], asrc2[cb + j], s);
                d = fmaf(acc[i * 4 + j], adst2[cb + j], d);
            }
        }
        // reduce over the 16-lane ci group (ci>=10 contribute 0)
        s += __shfl_xor(s, 1); s += __shfl_xor(s, 2);
        s += __shfl_xor(s, 4); s += __shfl_xor(s, 8);
        d += __shfl_xor(d, 1); d += __shfl_xor(d, 2);
        d += __shfl_xor(d, 4); d += __shfl_xor(d, 8);
        if (ci == 0 && n < N) { as2[n] = s; ad2[n] = d; }
    }
}

// Two masked 12-edge chunks (chunks B_, B_+1): ONE as2 gather per chunk per
// lane + all 8 gb row gathers issue before any exp/FMA.
#define AGG2_C2(B_)                                                            \
    {                                                                          \
        int ew0 = (B_) * 12 + lm12, ew1 = ew0 + 12;                            \
        int sw0 = __shfl(cv, ew0 < d ? ew0 : dm1);                             \
        int sw1 = __shfl(cv, ew1 < d ? ew1 : dm1);                             \
        float av0 = as2[sw0];                                                  \
        float av1 = as2[sw1];                                                  \
        int e00 = (B_) * 12 + gi0, e01 = (B_) * 12 + gi1;                      \
        int e02 = (B_) * 12 + gi2, e03 = (B_) * 12 + gi3;                      \
        int s00 = __shfl(cv, e00 < d ? e00 : dm1);                             \
        int s01 = __shfl(cv, e01 < d ? e01 : dm1);                             \
        int s02 = __shfl(cv, e02 < d ? e02 : dm1);                             \
        int s03 = __shfl(cv, e03 < d ? e03 : dm1);                             \
        int s10 = __shfl(cv, e00 + 12 < d ? e00 + 12 : dm1);                   \
        int s11 = __shfl(cv, e01 + 12 < d ? e01 + 12 : dm1);                   \
        int s12 = __shfl(cv, e02 + 12 < d ? e02 + 12 : dm1);                   \
        int s13 = __shfl(cv, e03 + 12 < d ? e03 + 12 : dm1);                   \
        unsigned int u00 = *(const unsigned int*)(gbc + ((unsigned)s00 * 80u + coff)); \
        unsigned int u01 = *(const unsigned int*)(gbc + ((unsigned)s01 * 80u + coff)); \
        unsigned int u02 = *(const unsigned int*)(gbc + ((unsigned)s02 * 80u + coff)); \
        unsigned int u03 = *(const unsigned int*)(gbc + ((unsigned)s03 * 80u + coff)); \
        unsigned int u10 = *(const unsigned int*)(gbc + ((unsigned)s10 * 80u + coff)); \
        unsigned int u11 = *(const unsigned int*)(gbc + ((unsigned)s11 * 80u + coff)); \
        unsigned int u12 = *(const unsigned int*)(gbc + ((unsigned)s12 * 80u + coff)); \
        unsigned int u13 = *(const unsigned int*)(gbc + ((unsigned)s13 * 80u + coff)); \
        float wall0 = (ew0 < d) ? lrelu_exp(av0 + add) : 0.f;                  \
        float wall1 = (ew1 < d) ? lrelu_exp(av1 + add) : 0.f;                  \
        float w00 = __shfl(wall0, gi0), w01 = __shfl(wall0, gi1);              \
        float w02 = __shfl(wall0, gi2), w03 = __shfl(wall0, gi3);              \
        float w10 = __shfl(wall1, gi0), w11 = __shfl(wall1, gi1);              \
        float w12 = __shfl(wall1, gi2), w13 = __shfl(wall1, gi3);              \
        acc0 = fmaf(w00, bf_lo(u00), acc0); acc1 = fmaf(w00, bf_hi(u00), acc1); zl += w00; \
        acc0 = fmaf(w01, bf_lo(u01), acc0); acc1 = fmaf(w01, bf_hi(u01), acc1); zl += w01; \
        acc0 = fmaf(w02, bf_lo(u02), acc0); acc1 = fmaf(w02, bf_hi(u02), acc1); zl += w02; \
        acc0 = fmaf(w03, bf_lo(u03), acc0); acc1 = fmaf(w03, bf_hi(u03), acc1); zl += w03; \
        acc0 = fmaf(w10, bf_lo(u10), acc0); acc1 = fmaf(w10, bf_hi(u10), acc1); zl += w10; \
        acc0 = fmaf(w11, bf_lo(u11), acc0); acc1 = fmaf(w11, bf_hi(u11), acc1); zl += w11; \
        acc0 = fmaf(w12, bf_lo(u12), acc0); acc1 = fmaf(w12, bf_hi(u12), acc1); zl += w12; \
        acc0 = fmaf(w13, bf_lo(u13), acc0); acc1 = fmaf(w13, bf_hi(u13), acc1); zl += w13; \
    }

// Layer-2 aggregation + bias + log_softmax. 3 groups x 20 lanes on 80B rows
// (R1-verified mapping) + R21 round-trip collapse: one wave-wide csr load
// covers the whole row; masked 24-edge double-chunks issue all gathers
// before compute. Wave-uniform branches: 0..24 / 24..48 / >48 fallback.
__global__ __launch_bounds__(256) void k_agg2(const ushort_t* __restrict__ gb,
                                              const float* __restrict__ as2,
                                              const float* __restrict__ ad2,
                                              const float* __restrict__ b2,
                                              const int* __restrict__ rowptr,
                                              const int* __restrict__ rowEnd,
                                              const int* __restrict__ csr,
                                              float* __restrict__ out, int N) {
    int tid = threadIdx.x, lane = tid & 63;
    int n = blockIdx.x * 4 + (tid >> 6);
    if (n >= N) return;
    int g = lane / 20, p = lane % 20;  // g==3 for lanes 60-63 (results unread)
    int c0 = 2 * p;
    const char* gbc = (const char*)gb;
    unsigned coff = (unsigned)(p << 2);
    int lm12 = lane % 12;
    int gi0 = (0 + g) < 12 ? (0 + g) : 11;   // clamp for g==3 lanes
    int gi1 = (3 + g) < 12 ? (3 + g) : 11;
    int gi2 = (6 + g) < 12 ? (6 + g) : 11;
    int gi3 = (9 + g) < 12 ? (9 + g) : 11;
    float add = ad2[n];
    float acc0 = 0.f, acc1 = 0.f, zl = 0.f;

    int j0 = rowptr[n], j1 = rowEnd[n];
    int d = j1 - j0;
    int dm1 = d > 0 ? d - 1 : 0;
    // ONE wave-wide csr load covers up to 64 edges
    int cv = (d > 0) ? csr[j0 + (lane < d ? lane : dm1)] : 0;

    {   // self loop (group 0 only)
        float e0 = as2[n] + add;
        float w = lrelu_exp(e0);
        if (g == 0) {
            unsigned int u = *(const unsigned int*)(gbc + ((unsigned)n * 80u + coff));
            acc0 = w * bf_lo(u); acc1 = w * bf_hi(u); zl = w;
        }
    }
    if (d > 0) {
        AGG2_C2(0);                    // edges 0..23 (covers ~98% of nodes)
        if (d > 24) {
            AGG2_C2(2);                // edges 24..47
            if (d > 48) {
                // edges 48.. : fallback loop with fresh csr loads (~never)
                for (int j = j0 + 48; j < j1; j += 12) {
                    int m = j1 - j;
                    int idx = lm12 < m ? lm12 : m - 1;
                    int cvt = csr[j + idx];
                    float av = as2[cvt];
                    float wall = (lm12 < m) ? lrelu_exp(av + add) : 0.f;
                    #pragma unroll
                    for (int i = 0; i < 4; i++) {
                        int e = 3 * i + g;
                        int gi = e < 12 ? e : 11;
                        int gim = gi < m ? gi : m - 1;
                        int s = __shfl(cvt, gim);
                        unsigned int u = *(const unsigned int*)(gbc + ((unsigned)s * 80u + coff));
                        float w = __shfl(wall, gi);  // 0 for e >= m
                        acc0 = fmaf(w, bf_lo(u), acc0);
                        acc1 = fmaf(w, bf_hi(u), acc1);
                        zl += w;
                    }
                }
            }
        }
    }
    // combine the 3 groups (valid at lanes 0..19)
    float A0 = acc0 + __shfl(acc0, (lane + 20) & 63) + __shfl(acc0, (lane + 40) & 63);
    float A1 = acc1 + __shfl(acc1, (lane + 20) & 63) + __shfl(acc1, (lane + 40) & 63);
    float Z  = zl + __shfl(zl, (lane + 20) & 63) + __shfl(zl, (lane + 40) & 63);
    float l0 = 0.f, l1 = 0.f;
    bool active = (lane < 20);
    if (active) {
        float inv = 1.f / (Z + 1e-16f);
        l0 = A0 * inv + b2[c0];
        l1 = A1 * inv + b2[c0 + 1];
    }
    // masked 32-lane butterfly for max and sum-exp over the 40 logits
    float mv = active ? fmaxf(l0, l1) : -INFINITY;
    #pragma unroll
    for (int ofs = 1; ofs < 32; ofs <<= 1) mv = fmaxf(mv, __shfl_xor(mv, ofs));
    float ev = active ? (__expf(l0 - mv) + __expf(l1 - mv)) : 0.f;
    #pragma unroll
    for (int ofs = 1; ofs < 32; ofs <<= 1) ev += __shfl_xor(ev, ofs);
    if (active) {
        float ls = mv + __logf(ev);
        *(float2*)&out[(size_t)n * 40 + c0] = make_float2(l0 - ls, l1 - ls);
    }
}

extern "C" void kernel_launch(void* const* d_in, const int* in_sizes, int n_in,
                              void* d_out, int out_size, void* d_ws, size_t ws_size,
                              hipStream_t stream) {
    const float* x    = (const float*)d_in[0];
    const float* topo = (const float*)d_in[1];
    const int*   ei   = (const int*)d_in[2];
    const float* W1   = (const float*)d_in[3];
    const float* a_s1 = (const float*)d_in[4];
    const float* a_d1 = (const float*)d_in[5];
    const float* b1   = (const float*)d_in[6];
    const float* W2   = (const float*)d_in[7];
    const float* a_s2 = (const float*)d_in[8];
    const float* a_d2 = (const float*)d_in[9];
    const float* b2   = (const float*)d_in[10];
    float* out = (float*)d_out;

    int N = in_sizes[0] / 128;
    int E = in_sizes[2] / 2;
    const int* esrc = ei;
    const int* edst = ei + E;
    int NBUK = (N + 255) / 256;
    size_t cap = (size_t)NBUK * BUK_CAP;

    char* ws = (char*)d_ws;
    size_t off = 0;
    auto alloc = [&](size_t bytes) -> void* {
        void* p = ws + off;
        off = (off + bytes + 255) & ~(size_t)255;
        return p;
    };
    ushort_t* h1b  = (ushort_t*)alloc((size_t)N * 64 * 2);
    float* as1     = (float*)alloc((size_t)N * 8 * 4);
    float* ad1     = (float*)alloc((size_t)N * 8 * 4);
    float* h2      = (float*)alloc((size_t)N * 64 * 4);
    ushort_t* gb   = (ushort_t*)alloc((size_t)N * 40 * 2);  // 80B rows
    float* as2     = (float*)alloc((size_t)N * 4);
    float* ad2     = (float*)alloc((size_t)N * 4);
    int*   rowptr  = (int*)alloc((size_t)N * 4);
    int*   rowEnd  = (int*)alloc((size_t)N * 4);
    int*   csr     = (int*)alloc(cap * 4);
    unsigned int* tmp = (unsigned int*)alloc(cap * 4);
    int* gCursor   = (int*)alloc((size_t)NBUK * 4);

    hipMemsetAsync(gCursor, 0, (size_t)NBUK * 4, stream);  // count-based cursors
    int nbin = (E + BIN_CHUNK - 1) / BIN_CHUNK;
    k_bin<<<nbin, 256, 0, stream>>>(esrc, edst, gCursor, tmp, E, NBUK);
    k_fill2<<<NBUK, 512, 0, stream>>>(tmp, gCursor, rowptr, rowEnd, csr, N);

    int nbg = (N + 63) / 64;  // 64-node GEMM tiles
    int nb4 = (N + 3) / 4;    // 1 node/wave x 4 waves/block
    k_xform1<<<nbg, 256, 0, stream>>>(x, topo, W1, a_s1, a_d1, h1b, as1, ad1, N);
    k_agg1<<<nb4, 256, 0, stream>>>(h1b, as1, ad1, b1, rowptr, rowEnd, csr, h2, N);
    k_xform2<<<nbg, 256, 0, stream>>>(h2, W2, a_s2, a_d2, gb, as2, ad2, N);
    k_agg2<<<nb4, 256, 0, stream>>>(gb, as2, ad2, b2, rowptr, rowEnd, csr, out, N);
}

// Round 10
// 289.150 us; speedup vs baseline: 1.0944x; 1.0085x over previous
//
#include <hip/hip_runtime.h>
#include <math.h>

// ---------------------------------------------------------------------------
// TopoGAT: 2-layer GAT on MI355X.
// R10: fixed-capacity bucket CSR build; padded CSR with rowptr/rowEnd.
// R5:  gather tables h1/g in bf16.
// R7/R12: xform = LDS-tiled GEMM, node-minor staging (conflict-free).
// R14: CSR build — k_bin BIN_CHUNK=4096; k_fill2 512thr + uint4 count pass.
// R21/R22: agg kernels -> 1 wave-wide csr load + all gathers up-front
//      (round-trip collapse): agg1 61.4->54.0, agg2 59.4-><54. VERIFIED.
// R23: dead-chunk FMA conditionals: 54.0 -> 53.0 only. LESSON: instruction
//      count shows per-NODE fixed cost dominates (~160/210 wave-instrs:
//      reduce 54 + epilogue 50 @ 8/64 lanes + self-loop 22); per-edge
//      trimming is exhausted.
// R24: k_agg1 -> TWO nodes per wave (lanes 0-31 node A, 32-63 node B;
//      4 edge slots x 8 heads per half). Halves all per-node fixed cost:
//      reduce 3->2 shfl levels (xor8/16 stay in-half), epilogue/self-loop
//      cover 2 nodes per issue. Chunk work unchanged per wave (4-edge x
//      2-node chunk = same 8 slots). Branches wave-uniform on
//      dmax=max(dA,dB). csr load covers 32 edges/node; chunks 6-7 +
//      fallback for d>24/32. d==0 halves: se masked to 0 (no OOB gather).
// ---------------------------------------------------------------------------

#define NBUK_MAX 512
#define BIN_CHUNK 4096
#define BUK_CAP 4608

typedef unsigned short ushort_t;

__device__ inline unsigned int f2bf(float f) {  // RNE fp32->bf16
    unsigned int u = __float_as_uint(f);
    u += 0x7FFFu + ((u >> 16) & 1u);
    return u >> 16;
}
__device__ inline float bf_lo(unsigned int u) {
    return __uint_as_float(u << 16);
}
__device__ inline float bf_hi(unsigned int u) {
    return __uint_as_float(u & 0xFFFF0000u);
}
__device__ inline float lrelu_exp(float q) {
    return __expf(q >= 0.f ? q : 0.2f * q);
}

__device__ inline int wave_incl_scan(int v, int lane) {
    #pragma unroll
    for (int ofs = 1; ofs < 64; ofs <<= 1) {
        int t = __shfl_up(v, ofs);
        if (lane >= ofs) v += t;
    }
    return v;
}

// Bin edges into fixed-capacity bucket regions of tmp. One global atomic per
// (block,bucket); packed word = (src<<8) | (dst&255). 16 edges/thread via
// int4 loads; dst stashed in registers across the reservation barrier.
__global__ __launch_bounds__(256) void k_bin(const int* __restrict__ src,
                                             const int* __restrict__ dst,
                                             int* __restrict__ gCursor,
                                             unsigned int* __restrict__ tmp,
                                             int E, int NBUK) {
    __shared__ int lcnt[NBUK_MAX];
    __shared__ int lcur[NBUK_MAX];
    int tid = threadIdx.x;
    int base = blockIdx.x * BIN_CHUNK;
    for (int i = tid; i < NBUK; i += 256) lcnt[i] = 0;
    __syncthreads();
    int d[16];
    #pragma unroll
    for (int q = 0; q < 4; q++) {
        int e = base + q * 1024 + 4 * tid;
        if (e + 3 < E) {
            int4 v = *(const int4*)&dst[e];
            d[4 * q + 0] = v.x; d[4 * q + 1] = v.y;
            d[4 * q + 2] = v.z; d[4 * q + 3] = v.w;
        } else {
            #pragma unroll
            for (int k = 0; k < 4; k++)
                d[4 * q + k] = (e + k < E) ? dst[e + k] : -1;
        }
    }
    #pragma unroll
    for (int k = 0; k < 16; k++)
        if (d[k] >= 0) atomicAdd(&lcnt[d[k] >> 8], 1);
    __syncthreads();
    for (int b = tid; b < NBUK; b += 256) {
        int c = lcnt[b];
        lcur[b] = c ? b * BUK_CAP + atomicAdd(&gCursor[b], c) : 0;
    }
    __syncthreads();
    #pragma unroll
    for (int q = 0; q < 4; q++) {
        int e = base + q * 1024 + 4 * tid;
        int s[4];
        if (e + 3 < E) {
            int4 v = *(const int4*)&src[e];
            s[0] = v.x; s[1] = v.y; s[2] = v.z; s[3] = v.w;
        } else {
            #pragma unroll
            for (int k = 0; k < 4; k++)
                s[k] = (e + k < E) ? src[e + k] : 0;
        }
        #pragma unroll
        for (int k = 0; k < 4; k++) {
            int dd = d[4 * q + k];
            if (dd >= 0) {
                int p = atomicAdd(&lcur[dd >> 8], 1);
                tmp[p] = ((unsigned int)s[k] << 8) | (unsigned int)(dd & 255);
            }
        }
    }
}

// Exact CSR fill within a bucket (padded layout, base = b*BUK_CAP).
// 512 threads; count pass reads tmp as uint4.
__global__ __launch_bounds__(512) void k_fill2(const unsigned int* __restrict__ tmp,
                                               const int* __restrict__ gCursor,
                                               int* __restrict__ rowptr,
                                               int* __restrict__ rowEnd,
                                               int* __restrict__ csr, int N) {
    __shared__ int cnt[256];
    __shared__ int cur[256];
    __shared__ int wsum[4];
    int b = blockIdx.x, tid = threadIdx.x;
    int e0 = b * BUK_CAP;
    int cnt_e = gCursor[b];       // bucket edge count
    int e1 = e0 + cnt_e;
    if (tid < 256) cnt[tid] = 0;
    __syncthreads();
    {   // count pass: uint4 over the bulk (e0 is 16B-aligned: BUK_CAP*4 % 16 == 0)
        int nq = cnt_e >> 2;
        const uint4* t4 = (const uint4*)(tmp + e0);
        for (int q = tid; q < nq; q += 512) {
            uint4 v = t4[q];
            atomicAdd(&cnt[v.x & 255u], 1);
            atomicAdd(&cnt[v.y & 255u], 1);
            atomicAdd(&cnt[v.z & 255u], 1);
            atomicAdd(&cnt[v.w & 255u], 1);
        }
        for (int i = (nq << 2) + tid; i < cnt_e; i += 512)
            atomicAdd(&cnt[tmp[e0 + i] & 255u], 1);
    }
    __syncthreads();
    if (tid < 256) {
        int lane = tid & 63, wv = tid >> 6;
        int v = cnt[tid];
        int incl = wave_incl_scan(v, lane);
        if (lane == 63) wsum[wv] = incl;
        cnt[tid] = incl - v;  // stash exclusive-within-wave
    }
    __syncthreads();
    if (tid < 256) {
        int wv = tid >> 6;
        int woff = 0;
        for (int i = 0; i < wv; i++) woff += wsum[i];
        int excl = woff + cnt[tid];
        int node = b * 256 + tid;
        int start = e0 + excl;
        cur[tid] = start;
        if (node < N) {
            rowptr[node] = start;
        }
    }
    __syncthreads();
    // rowEnd[node] = next start (cur of tid+1) or e1 for the last
    if (tid < 256) {
        int node = b * 256 + tid;
        if (node < N) rowEnd[node] = (tid < 255) ? cur[tid + 1] : e1;
    }
    __syncthreads();
    for (int i = e0 + tid; i < e1; i += 512) {
        unsigned int t = tmp[i];
        int p = atomicAdd(&cur[t & 255u], 1);
        csr[p] = (int)(t >> 8);
    }
}

// h1b[n][64](bf16) = [x[n]|topo[n]] @ W1 ; as1/ad1 from fp32 accumulators.
// Block = 64 nodes x 64 cols GEMM tile, K=136. W1 + xT staged in LDS,
// node-minor (conflict-free transpose writes).
__global__ __launch_bounds__(256) void k_xform1(const float* __restrict__ x,
                                                const float* __restrict__ topo,
                                                const float* __restrict__ W1,
                                                const float* __restrict__ asrc,
                                                const float* __restrict__ adst,
                                                ushort_t* __restrict__ h1b,
                                                float* __restrict__ as1,
                                                float* __restrict__ ad1, int N) {
    __shared__ float XT[136 * 64];  // XT[k][node]
    __shared__ float WS[136 * 64];  // WS[k][col]
    int tid = threadIdx.x;
    int n0 = blockIdx.x * 64;
    {   // stage W1: 8704 floats = 2176 float4 (once per block)
        const float4* W4 = (const float4*)W1;
        float4* WS4 = (float4*)WS;
        for (int i = tid; i < 2176; i += 256) WS4[i] = W4[i];
    }
    {   // stage x transposed, node-minor: i = k4*64 + node
        const float4* x4 = (const float4*)x;
        for (int i = tid; i < 2048; i += 256) {
            int node = i & 63, k4 = i >> 6;
            int gn = n0 + node; if (gn > N - 1) gn = N - 1;
            float4 v = x4[(size_t)gn * 32 + k4];
            int k = k4 * 4;
            XT[(k + 0) * 64 + node] = v.x;
            XT[(k + 1) * 64 + node] = v.y;
            XT[(k + 2) * 64 + node] = v.z;
            XT[(k + 3) * 64 + node] = v.w;
        }
        // topo rows 128..135: i = j4*64 + node, j4 in {0,1}
        const float4* t4 = (const float4*)topo;
        if (tid < 128) {
            int node = tid & 63, j4 = tid >> 6;
            int gn = n0 + node; if (gn > N - 1) gn = N - 1;
            float4 v = t4[(size_t)gn * 2 + j4];
            int k = 128 + j4 * 4;
            XT[(k + 0) * 64 + node] = v.x;
            XT[(k + 1) * 64 + node] = v.y;
            XT[(k + 2) * 64 + node] = v.z;
            XT[(k + 3) * 64 + node] = v.w;
        }
    }
    __syncthreads();
    int ci = tid & 15, ni = tid >> 4;
    int nb = ni * 4, cb = ci * 4;
    float acc[16];
    #pragma unroll
    for (int i = 0; i < 16; i++) acc[i] = 0.f;
    #pragma unroll 4
    for (int k = 0; k < 136; k++) {
        float4 xv = *(const float4*)&XT[k * 64 + nb];
        float4 wv = *(const float4*)&WS[k * 64 + cb];
        acc[0]  = fmaf(xv.x, wv.x, acc[0]);  acc[1]  = fmaf(xv.x, wv.y, acc[1]);
        acc[2]  = fmaf(xv.x, wv.z, acc[2]);  acc[3]  = fmaf(xv.x, wv.w, acc[3]);
        acc[4]  = fmaf(xv.y, wv.x, acc[4]);  acc[5]  = fmaf(xv.y, wv.y, acc[5]);
        acc[6]  = fmaf(xv.y, wv.z, acc[6]);  acc[7]  = fmaf(xv.y, wv.w, acc[7]);
        acc[8]  = fmaf(xv.z, wv.x, acc[8]);  acc[9]  = fmaf(xv.z, wv.y, acc[9]);
        acc[10] = fmaf(xv.z, wv.z, acc[10]); acc[11] = fmaf(xv.z, wv.w, acc[11]);
        acc[12] = fmaf(xv.w, wv.x, acc[12]); acc[13] = fmaf(xv.w, wv.y, acc[13]);
        acc[14] = fmaf(xv.w, wv.z, acc[14]); acc[15] = fmaf(xv.w, wv.w, acc[15]);
    }
    int head = cb >> 3;  // cols cb..cb+3 lie in one head (cb multiple of 4)
    #pragma unroll
    for (int i = 0; i < 4; i++) {
        int n = n0 + nb + i;
        unsigned int p0 = f2bf(acc[i * 4 + 0]) | (f2bf(acc[i * 4 + 1]) << 16);
        unsigned int p1 = f2bf(acc[i * 4 + 2]) | (f2bf(acc[i * 4 + 3]) << 16);
        if (n < N) *(uint2*)&h1b[(size_t)n * 64 + cb] = make_uint2(p0, p1);
        float s = 0.f, d = 0.f;
        #pragma unroll
        for (int j = 0; j < 4; j++) {
            s = fmaf(acc[i * 4 + j], asrc[cb + j], s);
            d = fmaf(acc[i * 4 + j], adst[cb + j], d);
        }
        s += __shfl_xor(s, 1);  // combine the two half-head threads
        d += __shfl_xor(d, 1);
        if ((ci & 1) == 0 && n < N) {
            as1[n * 8 + head] = s;
            ad1[n * 8 + head] = d;
        }
    }
}

// NOTE: parameter names W_/U_ must not collide with vector members .x/.y/.z/.w
#define AGG_FMA(W_, U_)                                           \
    {                                                             \
        acc[0] = fmaf(W_, bf_lo(U_.x), acc[0]);                   \
        acc[1] = fmaf(W_, bf_hi(U_.x), acc[1]);                   \
        acc[2] = fmaf(W_, bf_lo(U_.y), acc[2]);                   \
        acc[3] = fmaf(W_, bf_hi(U_.y), acc[3]);                   \
        acc[4] = fmaf(W_, bf_lo(U_.z), acc[4]);                   \
        acc[5] = fmaf(W_, bf_hi(U_.z), acc[5]);                   \
        acc[6] = fmaf(W_, bf_lo(U_.w), acc[6]);                   \
        acc[7] = fmaf(W_, bf_hi(U_.w), acc[7]);                   \
        z += W_;                                                  \
    }

// 2-node gather: shfl within this half (nbase = nid*32); se masked to 0 when
// the half's row is empty (d==0) so no garbage-index OOB gather.
#define AGG1_GATHER(EIDX, SE_, AV_, UU_)                                     \
    int SE_ = __shfl(cv, nbase + ((EIDX) < d ? (EIDX) : dm1));               \
    SE_ = d > 0 ? SE_ : 0;                                                   \
    float AV_ = as1[SE_ * 8 + head];                                         \
    uint4 UU_ = *(const uint4*)(h1c + (((unsigned)SE_ << 7) + hoff));

#define AGG1_COMP(EIDX, AV_, UU_)                                            \
    {                                                                        \
        float w_ = (EIDX) < d ? lrelu_exp(AV_ + adv) : 0.f;                  \
        AGG_FMA(w_, UU_);                                                    \
    }

// Per-dst softmax-weighted aggregation, layer 1 (+ implicit self loop).
// R24: TWO nodes per wave. Lanes 0-31 = node A, 32-63 = node B; within a
// half: 4 edge slots x 8 heads on 128B rows. One wave-wide csr load covers
// 32 edges/node; gathers for chunks 0-5 (24 edges) issue up-front; compute
// chunks gated by wave-uniform dmax. Reduce = 2 shfl levels (xor 8/16).
__global__ __launch_bounds__(256) void k_agg1(const ushort_t* __restrict__ h1b,
                                              const float* __restrict__ as1,
                                              const float* __restrict__ ad1,
                                              const float* __restrict__ b1,
                                              const int* __restrict__ rowptr,
                                              const int* __restrict__ rowEnd,
                                              const int* __restrict__ csr,
                                              float* __restrict__ h2, int N) {
    int tid = threadIdx.x, lane = tid & 63;
    int nbase0 = blockIdx.x * 8 + ((tid >> 6) << 1);
    if (nbase0 >= N) return;              // wave-uniform
    int nid = lane >> 5;                  // node within wave (0/1)
    int nbase = nid << 5;                 // shfl base for this half
    int l32 = lane & 31;
    int g = (lane >> 3) & 3;              // edge slot 0..3
    int head = lane & 7;                  // head (cols 8h..8h+7)
    int n = nbase0 + nid;
    bool valid = n < N;
    int nc = valid ? n : N - 1;
    const char* h1c = (const char*)h1b;
    unsigned hoff = (unsigned)head << 4;  // 16B per head block
    float adv = ad1[nc * 8 + head];
    float acc[8];
    #pragma unroll
    for (int k = 0; k < 8; k++) acc[k] = 0.f;
    float z = 0.f;

    int j0 = rowptr[nc], j1 = rowEnd[nc];
    int d = valid ? (j1 - j0) : 0;
    int dm1 = d > 0 ? d - 1 : 0;
    int dx = __shfl_xor(d, 32);
    int dmax = d > dx ? d : dx;           // wave-uniform branch driver
    // ONE wave-wide csr load: 32 edges per node (value garbage if d==0;
    // address always in-bounds; masked at se stage)
    int cv = csr[j0 + (l32 < d ? l32 : dm1)];

    {   // self loop (g==0 lanes of each half: 16/64 active)
        float w = lrelu_exp(as1[nc * 8 + head] + adv);
        if (g == 0 && valid) {
            uint4 u = *(const uint4*)(h1c + (((unsigned)nc << 7) + hoff));
            acc[0] = w * bf_lo(u.x); acc[1] = w * bf_hi(u.x);
            acc[2] = w * bf_lo(u.y); acc[3] = w * bf_hi(u.y);
            acc[4] = w * bf_lo(u.z); acc[5] = w * bf_hi(u.z);
            acc[6] = w * bf_lo(u.w); acc[7] = w * bf_hi(u.w);
            z = w;
        }
    }
    if (dmax > 0) {
        // gathers for chunks 0..5 (edges 0..23 per node), 1 round trip
        int e0 = g, e1 = 4 + g, e2 = 8 + g, e3 = 12 + g, e4 = 16 + g, e5 = 20 + g;
        AGG1_GATHER(e0, s0, a0, u0)
        AGG1_GATHER(e1, s1, a1, u1)
        AGG1_GATHER(e2, s2, a2, u2)
        AGG1_GATHER(e3, s3, a3, u3)
        AGG1_GATHER(e4, s4, a4, u4)
        AGG1_GATHER(e5, s5, a5, u5)
        AGG1_COMP(e0, a0, u0)
        if (dmax > 4)  AGG1_COMP(e1, a1, u1)
        if (dmax > 8)  AGG1_COMP(e2, a2, u2)
        if (dmax > 12) AGG1_COMP(e3, a3, u3)
        if (dmax > 16) AGG1_COMP(e4, a4, u4)
        if (dmax > 20) AGG1_COMP(e5, a5, u5)
        if (dmax > 24) {                  // chunks 6/7 (edges 24..31)
            int e6 = 24 + g, e7 = 28 + g;
            AGG1_GATHER(e6, s6, a6, u6)
            AGG1_GATHER(e7, s7, a7, u7)
            AGG1_COMP(e6, a6, u6)
            if (dmax > 28) AGG1_COMP(e7, a7, u7)
            if (dmax > 32) {              // rare fallback: direct per-lane loads
                for (int eb = 32; eb < dmax; eb += 4) {
                    int e = eb + g;
                    int idx = e < d ? e : dm1;
                    int se = csr[j0 + idx];
                    se = d > 0 ? se : 0;
                    float av = as1[se * 8 + head];
                    uint4 u = *(const uint4*)(h1c + (((unsigned)se << 7) + hoff));
                    float w = e < d ? lrelu_exp(av + adv) : 0.f;
                    AGG_FMA(w, u);
                }
            }
        }
    }
    // reduce across the 4 edge-slot groups of each half (xor 8, 16 stay in-half)
    #pragma unroll
    for (int k = 0; k < 8; k++) {
        acc[k] += __shfl_xor(acc[k], 8);
        acc[k] += __shfl_xor(acc[k], 16);
    }
    z += __shfl_xor(z, 8); z += __shfl_xor(z, 16);
    if (g == 0 && valid) {
        float inv = 1.f / (z + 1e-16f);
        float o[8];
        #pragma unroll
        for (int k = 0; k < 8; k++) {
            float v = acc[k] * inv + b1[head * 8 + k];
            o[k] = v > 0.f ? v : (__expf(v) - 1.f);
        }
        float4* dp = (float4*)&h2[(size_t)n * 64 + head * 8];
        dp[0] = make_float4(o[0], o[1], o[2], o[3]);
        dp[1] = make_float4(o[4], o[5], o[6], o[7]);
    }
}

// gb[n][40](bf16) = h2[n] @ W2 ; as2/ad2 from fp32 accumulators.
// Block = 64 nodes x 40 cols GEMM tile, K=64. Node-minor staging.
__global__ __launch_bounds__(256) void k_xform2(const float* __restrict__ h2,
                                                const float* __restrict__ W2,
                                                const float* __restrict__ asrc2,
                                                const float* __restrict__ adst2,
                                                ushort_t* __restrict__ gb,
                                                float* __restrict__ as2,
                                                float* __restrict__ ad2, int N) {
    __shared__ float XT[64 * 64];  // h2T[k][node]
    __shared__ float WS[64 * 40];  // WS[k][col]
    int tid = threadIdx.x;
    int n0 = blockIdx.x * 64;
    {   // stage W2: 2560 floats = 640 float4
        const float4* W4 = (const float4*)W2;
        float4* WS4 = (float4*)WS;
        for (int i = tid; i < 640; i += 256) WS4[i] = W4[i];
    }
    {   // stage h2 transposed, node-minor: i = k4*64 + node
        const float4* h4 = (const float4*)h2;
        for (int i = tid; i < 1024; i += 256) {
            int node = i & 63, k4 = i >> 6;
            int gn = n0 + node; if (gn > N - 1) gn = N - 1;
            float4 v = h4[(size_t)gn * 16 + k4];
            int k = k4 * 4;
            XT[(k + 0) * 64 + node] = v.x;
            XT[(k + 1) * 64 + node] = v.y;
            XT[(k + 2) * 64 + node] = v.z;
            XT[(k + 3) * 64 + node] = v.w;
        }
    }
    __syncthreads();
    int ci = tid & 15, ni = tid >> 4;
    int nb = ni * 4, cb = ci * 4;
    float acc[16];
    #pragma unroll
    for (int i = 0; i < 16; i++) acc[i] = 0.f;
    if (ci < 10) {
        #pragma unroll 4
        for (int k = 0; k < 64; k++) {
            float4 xv = *(const float4*)&XT[k * 64 + nb];
            float4 wv = *(const float4*)&WS[k * 40 + cb];
            acc[0]  = fmaf(xv.x, wv.x, acc[0]);  acc[1]  = fmaf(xv.x, wv.y, acc[1]);
            acc[2]  = fmaf(xv.x, wv.z, acc[2]);  acc[3]  = fmaf(xv.x, wv.w, acc[3]);
            acc[4]  = fmaf(xv.y, wv.x, acc[4]);  acc[5]  = fmaf(xv.y, wv.y, acc[5]);
            acc[6]  = fmaf(xv.y, wv.z, acc[6]);  acc[7]  = fmaf(xv.y, wv.w, acc[7]);
            acc[8]  = fmaf(xv.z, wv.x, acc[8]);  acc[9]  = fmaf(xv.z, wv.y, acc[9]);
            acc[10] = fmaf(xv.z, wv.z, acc[10]); acc[11] = fmaf(xv.z, wv.w, acc[11]);
            acc[12] = fmaf(xv.w, wv.x, acc[12]); acc[13] = fmaf(xv.w, wv.y, acc[13]);
            acc[14] = fmaf(xv.w, wv.z, acc[14]); acc[15] = fmaf(xv.w, wv.w, acc[15]);
        }
    }
    #pragma unroll
    for (int i = 0; i < 4; i++) {
        int n = n0 + nb + i;
        if (ci < 10 && n < N) {
            unsigned int p0 = f2bf(acc[i * 4 + 0]) | (f2bf(acc[i * 4 + 1]) << 16);
            unsigned int p1 = f2bf(acc[i * 4 + 2]) | (f2bf(acc[i * 4 + 3]) << 16);
            *(uint2*)&gb[(size_t)n * 40 + cb] = make_uint2(p0, p1);  // 80B rows
        }
        float s = 0.f, d = 0.f;
        if (ci < 10) {
            #pragma unroll
            for (int j = 0; j < 4; j++) {
                s = fmaf(acc[i * 4 + j], asrc2[cb + j], s);
                d = fmaf(acc[i * 4 + j], adst2[cb + j], d);
            }
        }
        // reduce over the 16-lane ci group (ci>=10 contribute 0)
        s += __shfl_xor(s, 1); s += __shfl_xor(s, 2);
        s += __shfl_xor(s, 4); s += __shfl_xor(s, 8);
        d += __shfl_xor(d, 1); d += __shfl_xor(d, 2);
        d += __shfl_xor(d, 4); d += __shfl_xor(d, 8);
        if (ci == 0 && n < N) { as2[n] = s; ad2[n] = d; }
    }
}

// Two masked 12-edge chunks (chunks B_, B_+1): ONE as2 gather per chunk per
// lane + all 8 gb row gathers issue before any exp/FMA.
#define AGG2_C2(B_)                                                            \
    {                                                                          \
        int ew0 = (B_) * 12 + lm12, ew1 = ew0 + 12;                            \
        int sw0 = __shfl(cv, ew0 < d ? ew0 : dm1);                             \
        int sw1 = __shfl(cv, ew1 < d ? ew1 : dm1);                             \
        float av0 = as2[sw0];                                                  \
        float av1 = as2[sw1];                                                  \
        int e00 = (B_) * 12 + gi0, e01 = (B_) * 12 + gi1;                      \
        int e02 = (B_) * 12 + gi2, e03 = (B_) * 12 + gi3;                      \
        int s00 = __shfl(cv, e00 < d ? e00 : dm1);                             \
        int s01 = __shfl(cv, e01 < d ? e01 : dm1);                             \
        int s02 = __shfl(cv, e02 < d ? e02 : dm1);                             \
        int s03 = __shfl(cv, e03 < d ? e03 : dm1);                             \
        int s10 = __shfl(cv, e00 + 12 < d ? e00 + 12 : dm1);                   \
        int s11 = __shfl(cv, e01 + 12 < d ? e01 + 12 : dm1);                   \
        int s12 = __shfl(cv, e02 + 12 < d ? e02 + 12 : dm1);                   \
        int s13 = __shfl(cv, e03 + 12 < d ? e03 + 12 : dm1);                   \
        unsigned int u00 = *(const unsigned int*)(gbc + ((unsigned)s00 * 80u + coff)); \
        unsigned int u01 = *(const unsigned int*)(gbc + ((unsigned)s01 * 80u + coff)); \
        unsigned int u02 = *(const unsigned int*)(gbc + ((unsigned)s02 * 80u + coff)); \
        unsigned int u03 = *(const unsigned int*)(gbc + ((unsigned)s03 * 80u + coff)); \
        unsigned int u10 = *(const unsigned int*)(gbc + ((unsigned)s10 * 80u + coff)); \
        unsigned int u11 = *(const unsigned int*)(gbc + ((unsigned)s11 * 80u + coff)); \
        unsigned int u12 = *(const unsigned int*)(gbc + ((unsigned)s12 * 80u + coff)); \
        unsigned int u13 = *(const unsigned int*)(gbc + ((unsigned)s13 * 80u + coff)); \
        float wall0 = (ew0 < d) ? lrelu_exp(av0 + add) : 0.f;                  \
        float wall1 = (ew1 < d) ? lrelu_exp(av1 + add) : 0.f;                  \
        float w00 = __shfl(wall0, gi0), w01 = __shfl(wall0, gi1);              \
        float w02 = __shfl(wall0, gi2), w03 = __shfl(wall0, gi3);              \
        float w10 = __shfl(wall1, gi0), w11 = __shfl(wall1, gi1);              \
        float w12 = __shfl(wall1, gi2), w13 = __shfl(wall1, gi3);              \
        acc0 = fmaf(w00, bf_lo(u00), acc0); acc1 = fmaf(w00, bf_hi(u00), acc1); zl += w00; \
        acc0 = fmaf(w01, bf_lo(u01), acc0); acc1 = fmaf(w01, bf_hi(u01), acc1); zl += w01; \
        acc0 = fmaf(w02, bf_lo(u02), acc0); acc1 = fmaf(w02, bf_hi(u02), acc1); zl += w02; \
        acc0 = fmaf(w03, bf_lo(u03), acc0); acc1 = fmaf(w03, bf_hi(u03), acc1); zl += w03; \
        acc0 = fmaf(w10, bf_lo(u10), acc0); acc1 = fmaf(w10, bf_hi(u10), acc1); zl += w10; \
        acc0 = fmaf(w11, bf_lo(u11), acc0); acc1 = fmaf(w11, bf_hi(u11), acc1); zl += w11; \
        acc0 = fmaf(w12, bf_lo(u12), acc0); acc1 = fmaf(w12, bf_hi(u12), acc1); zl += w12; \
        acc0 = fmaf(w13, bf_lo(u13), acc0); acc1 = fmaf(w13, bf_hi(u13), acc1); zl += w13; \
    }

// Layer-2 aggregation + bias + log_softmax. 3 groups x 20 lanes on 80B rows
// (R1-verified mapping) + R21 round-trip collapse: one wave-wide csr load
// covers the whole row; masked 24-edge double-chunks issue all gathers
// before compute. Wave-uniform branches: 0..24 / 24..48 / >48 fallback.
__global__ __launch_bounds__(256) void k_agg2(const ushort_t* __restrict__ gb,
                                              const float* __restrict__ as2,
                                              const float* __restrict__ ad2,
                                              const float* __restrict__ b2,
                                              const int* __restrict__ rowptr,
                                              const int* __restrict__ rowEnd,
                                              const int* __restrict__ csr,
                                              float* __restrict__ out, int N) {
    int tid = threadIdx.x, lane = tid & 63;
    int n = blockIdx.x * 4 + (tid >> 6);
    if (n >= N) return;
    int g = lane / 20, p = lane % 20;  // g==3 for lanes 60-63 (results unread)
    int c0 = 2 * p;
    const char* gbc = (const char*)gb;
    unsigned coff = (unsigned)(p << 2);
    int lm12 = lane % 12;
    int gi0 = (0 + g) < 12 ? (0 + g) : 11;   // clamp for g==3 lanes
    int gi1 = (3 + g) < 12 ? (3 + g) : 11;
    int gi2 = (6 + g) < 12 ? (6 + g) : 11;
    int gi3 = (9 + g) < 12 ? (9 + g) : 11;
    float add = ad2[n];
    float acc0 = 0.f, acc1 = 0.f, zl = 0.f;

    int j0 = rowptr[n], j1 = rowEnd[n];
    int d = j1 - j0;
    int dm1 = d > 0 ? d - 1 : 0;
    // ONE wave-wide csr load covers up to 64 edges
    int cv = (d > 0) ? csr[j0 + (lane < d ? lane : dm1)] : 0;

    {   // self loop (group 0 only)
        float e0 = as2[n] + add;
        float w = lrelu_exp(e0);
        if (g == 0) {
            unsigned int u = *(const unsigned int*)(gbc + ((unsigned)n * 80u + coff));
            acc0 = w * bf_lo(u); acc1 = w * bf_hi(u); zl = w;
        }
    }
    if (d > 0) {
        AGG2_C2(0);                    // edges 0..23 (covers ~98% of nodes)
        if (d > 24) {
            AGG2_C2(2);                // edges 24..47
            if (d > 48) {
                // edges 48.. : fallback loop with fresh csr loads (~never)
                for (int j = j0 + 48; j < j1; j += 12) {
                    int m = j1 - j;
                    int idx = lm12 < m ? lm12 : m - 1;
                    int cvt = csr[j + idx];
                    float av = as2[cvt];
                    float wall = (lm12 < m) ? lrelu_exp(av + add) : 0.f;
                    #pragma unroll
                    for (int i = 0; i < 4; i++) {
                        int e = 3 * i + g;
                        int gi = e < 12 ? e : 11;
                        int gim = gi < m ? gi : m - 1;
                        int s = __shfl(cvt, gim);
                        unsigned int u = *(const unsigned int*)(gbc + ((unsigned)s * 80u + coff));
                        float w = __shfl(wall, gi);  // 0 for e >= m
                        acc0 = fmaf(w, bf_lo(u), acc0);
                        acc1 = fmaf(w, bf_hi(u), acc1);
                        zl += w;
                    }
                }
            }
        }
    }
    // combine the 3 groups (valid at lanes 0..19)
    float A0 = acc0 + __shfl(acc0, (lane + 20) & 63) + __shfl(acc0, (lane + 40) & 63);
    float A1 = acc1 + __shfl(acc1, (lane + 20) & 63) + __shfl(acc1, (lane + 40) & 63);
    float Z  = zl + __shfl(zl, (lane + 20) & 63) + __shfl(zl, (lane + 40) & 63);
    float l0 = 0.f, l1 = 0.f;
    bool active = (lane < 20);
    if (active) {
        float inv = 1.f / (Z + 1e-16f);
        l0 = A0 * inv + b2[c0];
        l1 = A1 * inv + b2[c0 + 1];
    }
    // masked 32-lane butterfly for max and sum-exp over the 40 logits
    float mv = active ? fmaxf(l0, l1) : -INFINITY;
    #pragma unroll
    for (int ofs = 1; ofs < 32; ofs <<= 1) mv = fmaxf(mv, __shfl_xor(mv, ofs));
    float ev = active ? (__expf(l0 - mv) + __expf(l1 - mv)) : 0.f;
    #pragma unroll
    for (int ofs = 1; ofs < 32; ofs <<= 1) ev += __shfl_xor(ev, ofs);
    if (active) {
        float ls = mv + __logf(ev);
        *(float2*)&out[(size_t)n * 40 + c0] = make_float2(l0 - ls, l1 - ls);
    }
}

extern "C" void kernel_launch(void* const* d_in, const int* in_sizes, int n_in,
                              void* d_out, int out_size, void* d_ws, size_t ws_size,
                              hipStream_t stream) {
    const float* x    = (const float*)d_in[0];
    const float* topo = (const float*)d_in[1];
    const int*   ei   = (const int*)d_in[2];
    const float* W1   = (const float*)d_in[3];
    const float* a_s1 = (const float*)d_in[4];
    const float* a_d1 = (const float*)d_in[5];
    const float* b1   = (const float*)d_in[6];
    const float* W2   = (const float*)d_in[7];
    const float* a_s2 = (const float*)d_in[8];
    const float* a_d2 = (const float*)d_in[9];
    const float* b2   = (const float*)d_in[10];
    float* out = (float*)d_out;

    int N = in_sizes[0] / 128;
    int E = in_sizes[2] / 2;
    const int* esrc = ei;
    const int* edst = ei + E;
    int NBUK = (N + 255) / 256;
    size_t cap = (size_t)NBUK * BUK_CAP;

    char* ws = (char*)d_ws;
    size_t off = 0;
    auto alloc = [&](size_t bytes) -> void* {
        void* p = ws + off;
        off = (off + bytes + 255) & ~(size_t)255;
        return p;
    };
    ushort_t* h1b  = (ushort_t*)alloc((size_t)N * 64 * 2);
    float* as1     = (float*)alloc((size_t)N * 8 * 4);
    float* ad1     = (float*)alloc((size_t)N * 8 * 4);
    float* h2      = (float*)alloc((size_t)N * 64 * 4);
    ushort_t* gb   = (ushort_t*)alloc((size_t)N * 40 * 2);  // 80B rows
    float* as2     = (float*)alloc((size_t)N * 4);
    float* ad2     = (float*)alloc((size_t)N * 4);
    int*   rowptr  = (int*)alloc((size_t)N * 4);
    int*   rowEnd  = (int*)alloc((size_t)N * 4);
    int*   csr     = (int*)alloc(cap * 4);
    unsigned int* tmp = (unsigned int*)alloc(cap * 4);
    int* gCursor   = (int*)alloc((size_t)NBUK * 4);

    hipMemsetAsync(gCursor, 0, (size_t)NBUK * 4, stream);  // count-based cursors
    int nbin = (E + BIN_CHUNK - 1) / BIN_CHUNK;
    k_bin<<<nbin, 256, 0, stream>>>(esrc, edst, gCursor, tmp, E, NBUK);
    k_fill2<<<NBUK, 512, 0, stream>>>(tmp, gCursor, rowptr, rowEnd, csr, N);

    int nbg = (N + 63) / 64;  // 64-node GEMM tiles
    int nb8 = (N + 7) / 8;    // 2 nodes/wave x 4 waves/block (k_agg1)
    int nb4 = (N + 3) / 4;    // 1 node/wave x 4 waves/block (k_agg2)
    k_xform1<<<nbg, 256, 0, stream>>>(x, topo, W1, a_s1, a_d1, h1b, as1, ad1, N);
    k_agg1<<<nb8, 256, 0, stream>>>(h1b, as1, ad1, b1, rowptr, rowEnd, csr, h2, N);
    k_xform2<<<nbg, 256, 0, stream>>>(h2, W2, a_s2, a_d2, gb, as2, ad2, N);
    k_agg2<<<nb4, 256, 0, stream>>>(gb, as2, ad2, b2, rowptr, rowEnd, csr, out, N);
}

// Round 11
// 280.990 us; speedup vs baseline: 1.1261x; 1.0290x over previous
//
#include <hip/hip_runtime.h>
#include <math.h>

// ---------------------------------------------------------------------------
// TopoGAT: 2-layer GAT on MI355X.
// R10: fixed-capacity bucket CSR build; padded CSR with rowptr/rowEnd.
// R5:  gather tables h1/g in bf16.
// R7/R12: xform = LDS-tiled GEMM, node-minor staging (conflict-free).
// R14: CSR build — k_bin BIN_CHUNK=4096; k_fill2 512thr + uint4 count pass.
// R21/R22: agg kernels -> 1 wave-wide csr load + all gathers up-front.
// R23: per-edge FMA gating: +1us only => per-NODE fixed cost dominates.
// R24: k_agg1 -> 2 nodes/wave (halved fixed cost): 53.0 -> <52.5, total
//      291.6 -> 289.1. VERIFIED. k_agg2 now top (52.6us, VALUBusy 81%).
// R25: k_agg2 -> same 2-node structure + uint2 gathers. Per half: 3 edge
//      slots x 10 lanes x 8B (4 cols each) on 80B rows; weight-lane ==
//      compute-lane (as2[se] loaded per-group; zero weight shfls). Chunks
//      0..7 (24 edges) gathers up-front; compute gated on dmax; chunks 8/9
//      for dmax>24; direct-load fallback >=30. Reduce = 2 shfl (+10/+20,
//      original-value reads); epilogue butterfly = 4 xor levels in each
//      half's 16-lane group. ~210 -> ~130 wave-instrs/node.
// ---------------------------------------------------------------------------

#define NBUK_MAX 512
#define BIN_CHUNK 4096
#define BUK_CAP 4608

typedef unsigned short ushort_t;

__device__ inline unsigned int f2bf(float f) {  // RNE fp32->bf16
    unsigned int u = __float_as_uint(f);
    u += 0x7FFFu + ((u >> 16) & 1u);
    return u >> 16;
}
__device__ inline float bf_lo(unsigned int u) {
    return __uint_as_float(u << 16);
}
__device__ inline float bf_hi(unsigned int u) {
    return __uint_as_float(u & 0xFFFF0000u);
}
__device__ inline float lrelu_exp(float q) {
    return __expf(q >= 0.f ? q : 0.2f * q);
}

__device__ inline int wave_incl_scan(int v, int lane) {
    #pragma unroll
    for (int ofs = 1; ofs < 64; ofs <<= 1) {
        int t = __shfl_up(v, ofs);
        if (lane >= ofs) v += t;
    }
    return v;
}

// Bin edges into fixed-capacity bucket regions of tmp. One global atomic per
// (block,bucket); packed word = (src<<8) | (dst&255). 16 edges/thread via
// int4 loads; dst stashed in registers across the reservation barrier.
__global__ __launch_bounds__(256) void k_bin(const int* __restrict__ src,
                                             const int* __restrict__ dst,
                                             int* __restrict__ gCursor,
                                             unsigned int* __restrict__ tmp,
                                             int E, int NBUK) {
    __shared__ int lcnt[NBUK_MAX];
    __shared__ int lcur[NBUK_MAX];
    int tid = threadIdx.x;
    int base = blockIdx.x * BIN_CHUNK;
    for (int i = tid; i < NBUK; i += 256) lcnt[i] = 0;
    __syncthreads();
    int d[16];
    #pragma unroll
    for (int q = 0; q < 4; q++) {
        int e = base + q * 1024 + 4 * tid;
        if (e + 3 < E) {
            int4 v = *(const int4*)&dst[e];
            d[4 * q + 0] = v.x; d[4 * q + 1] = v.y;
            d[4 * q + 2] = v.z; d[4 * q + 3] = v.w;
        } else {
            #pragma unroll
            for (int k = 0; k < 4; k++)
                d[4 * q + k] = (e + k < E) ? dst[e + k] : -1;
        }
    }
    #pragma unroll
    for (int k = 0; k < 16; k++)
        if (d[k] >= 0) atomicAdd(&lcnt[d[k] >> 8], 1);
    __syncthreads();
    for (int b = tid; b < NBUK; b += 256) {
        int c = lcnt[b];
        lcur[b] = c ? b * BUK_CAP + atomicAdd(&gCursor[b], c) : 0;
    }
    __syncthreads();
    #pragma unroll
    for (int q = 0; q < 4; q++) {
        int e = base + q * 1024 + 4 * tid;
        int s[4];
        if (e + 3 < E) {
            int4 v = *(const int4*)&src[e];
            s[0] = v.x; s[1] = v.y; s[2] = v.z; s[3] = v.w;
        } else {
            #pragma unroll
            for (int k = 0; k < 4; k++)
                s[k] = (e + k < E) ? src[e + k] : 0;
        }
        #pragma unroll
        for (int k = 0; k < 4; k++) {
            int dd = d[4 * q + k];
            if (dd >= 0) {
                int p = atomicAdd(&lcur[dd >> 8], 1);
                tmp[p] = ((unsigned int)s[k] << 8) | (unsigned int)(dd & 255);
            }
        }
    }
}

// Exact CSR fill within a bucket (padded layout, base = b*BUK_CAP).
// 512 threads; count pass reads tmp as uint4.
__global__ __launch_bounds__(512) void k_fill2(const unsigned int* __restrict__ tmp,
                                               const int* __restrict__ gCursor,
                                               int* __restrict__ rowptr,
                                               int* __restrict__ rowEnd,
                                               int* __restrict__ csr, int N) {
    __shared__ int cnt[256];
    __shared__ int cur[256];
    __shared__ int wsum[4];
    int b = blockIdx.x, tid = threadIdx.x;
    int e0 = b * BUK_CAP;
    int cnt_e = gCursor[b];       // bucket edge count
    int e1 = e0 + cnt_e;
    if (tid < 256) cnt[tid] = 0;
    __syncthreads();
    {   // count pass: uint4 over the bulk (e0 is 16B-aligned: BUK_CAP*4 % 16 == 0)
        int nq = cnt_e >> 2;
        const uint4* t4 = (const uint4*)(tmp + e0);
        for (int q = tid; q < nq; q += 512) {
            uint4 v = t4[q];
            atomicAdd(&cnt[v.x & 255u], 1);
            atomicAdd(&cnt[v.y & 255u], 1);
            atomicAdd(&cnt[v.z & 255u], 1);
            atomicAdd(&cnt[v.w & 255u], 1);
        }
        for (int i = (nq << 2) + tid; i < cnt_e; i += 512)
            atomicAdd(&cnt[tmp[e0 + i] & 255u], 1);
    }
    __syncthreads();
    if (tid < 256) {
        int lane = tid & 63, wv = tid >> 6;
        int v = cnt[tid];
        int incl = wave_incl_scan(v, lane);
        if (lane == 63) wsum[wv] = incl;
        cnt[tid] = incl - v;  // stash exclusive-within-wave
    }
    __syncthreads();
    if (tid < 256) {
        int wv = tid >> 6;
        int woff = 0;
        for (int i = 0; i < wv; i++) woff += wsum[i];
        int excl = woff + cnt[tid];
        int node = b * 256 + tid;
        int start = e0 + excl;
        cur[tid] = start;
        if (node < N) {
            rowptr[node] = start;
        }
    }
    __syncthreads();
    // rowEnd[node] = next start (cur of tid+1) or e1 for the last
    if (tid < 256) {
        int node = b * 256 + tid;
        if (node < N) rowEnd[node] = (tid < 255) ? cur[tid + 1] : e1;
    }
    __syncthreads();
    for (int i = e0 + tid; i < e1; i += 512) {
        unsigned int t = tmp[i];
        int p = atomicAdd(&cur[t & 255u], 1);
        csr[p] = (int)(t >> 8);
    }
}

// h1b[n][64](bf16) = [x[n]|topo[n]] @ W1 ; as1/ad1 from fp32 accumulators.
// Block = 64 nodes x 64 cols GEMM tile, K=136. W1 + xT staged in LDS,
// node-minor (conflict-free transpose writes).
__global__ __launch_bounds__(256) void k_xform1(const float* __restrict__ x,
                                                const float* __restrict__ topo,
                                                const float* __restrict__ W1,
                                                const float* __restrict__ asrc,
                                                const float* __restrict__ adst,
                                                ushort_t* __restrict__ h1b,
                                                float* __restrict__ as1,
                                                float* __restrict__ ad1, int N) {
    __shared__ float XT[136 * 64];  // XT[k][node]
    __shared__ float WS[136 * 64];  // WS[k][col]
    int tid = threadIdx.x;
    int n0 = blockIdx.x * 64;
    {   // stage W1: 8704 floats = 2176 float4 (once per block)
        const float4* W4 = (const float4*)W1;
        float4* WS4 = (float4*)WS;
        for (int i = tid; i < 2176; i += 256) WS4[i] = W4[i];
    }
    {   // stage x transposed, node-minor: i = k4*64 + node
        const float4* x4 = (const float4*)x;
        for (int i = tid; i < 2048; i += 256) {
            int node = i & 63, k4 = i >> 6;
            int gn = n0 + node; if (gn > N - 1) gn = N - 1;
            float4 v = x4[(size_t)gn * 32 + k4];
            int k = k4 * 4;
            XT[(k + 0) * 64 + node] = v.x;
            XT[(k + 1) * 64 + node] = v.y;
            XT[(k + 2) * 64 + node] = v.z;
            XT[(k + 3) * 64 + node] = v.w;
        }
        // topo rows 128..135: i = j4*64 + node, j4 in {0,1}
        const float4* t4 = (const float4*)topo;
        if (tid < 128) {
            int node = tid & 63, j4 = tid >> 6;
            int gn = n0 + node; if (gn > N - 1) gn = N - 1;
            float4 v = t4[(size_t)gn * 2 + j4];
            int k = 128 + j4 * 4;
            XT[(k + 0) * 64 + node] = v.x;
            XT[(k + 1) * 64 + node] = v.y;
            XT[(k + 2) * 64 + node] = v.z;
            XT[(k + 3) * 64 + node] = v.w;
        }
    }
    __syncthreads();
    int ci = tid & 15, ni = tid >> 4;
    int nb = ni * 4, cb = ci * 4;
    float acc[16];
    #pragma unroll
    for (int i = 0; i < 16; i++) acc[i] = 0.f;
    #pragma unroll 4
    for (int k = 0; k < 136; k++) {
        float4 xv = *(const float4*)&XT[k * 64 + nb];
        float4 wv = *(const float4*)&WS[k * 64 + cb];
        acc[0]  = fmaf(xv.x, wv.x, acc[0]);  acc[1]  = fmaf(xv.x, wv.y, acc[1]);
        acc[2]  = fmaf(xv.x, wv.z, acc[2]);  acc[3]  = fmaf(xv.x, wv.w, acc[3]);
        acc[4]  = fmaf(xv.y, wv.x, acc[4]);  acc[5]  = fmaf(xv.y, wv.y, acc[5]);
        acc[6]  = fmaf(xv.y, wv.z, acc[6]);  acc[7]  = fmaf(xv.y, wv.w, acc[7]);
        acc[8]  = fmaf(xv.z, wv.x, acc[8]);  acc[9]  = fmaf(xv.z, wv.y, acc[9]);
        acc[10] = fmaf(xv.z, wv.z, acc[10]); acc[11] = fmaf(xv.z, wv.w, acc[11]);
        acc[12] = fmaf(xv.w, wv.x, acc[12]); acc[13] = fmaf(xv.w, wv.y, acc[13]);
        acc[14] = fmaf(xv.w, wv.z, acc[14]); acc[15] = fmaf(xv.w, wv.w, acc[15]);
    }
    int head = cb >> 3;  // cols cb..cb+3 lie in one head (cb multiple of 4)
    #pragma unroll
    for (int i = 0; i < 4; i++) {
        int n = n0 + nb + i;
        unsigned int p0 = f2bf(acc[i * 4 + 0]) | (f2bf(acc[i * 4 + 1]) << 16);
        unsigned int p1 = f2bf(acc[i * 4 + 2]) | (f2bf(acc[i * 4 + 3]) << 16);
        if (n < N) *(uint2*)&h1b[(size_t)n * 64 + cb] = make_uint2(p0, p1);
        float s = 0.f, d = 0.f;
        #pragma unroll
        for (int j = 0; j < 4; j++) {
            s = fmaf(acc[i * 4 + j], asrc[cb + j], s);
            d = fmaf(acc[i * 4 + j], adst[cb + j], d);
        }
        s += __shfl_xor(s, 1);  // combine the two half-head threads
        d += __shfl_xor(d, 1);
        if ((ci & 1) == 0 && n < N) {
            as1[n * 8 + head] = s;
            ad1[n * 8 + head] = d;
        }
    }
}

// NOTE: parameter names W_/U_ must not collide with vector members .x/.y/.z/.w
#define AGG_FMA(W_, U_)                                           \
    {                                                             \
        acc[0] = fmaf(W_, bf_lo(U_.x), acc[0]);                   \
        acc[1] = fmaf(W_, bf_hi(U_.x), acc[1]);                   \
        acc[2] = fmaf(W_, bf_lo(U_.y), acc[2]);                   \
        acc[3] = fmaf(W_, bf_hi(U_.y), acc[3]);                   \
        acc[4] = fmaf(W_, bf_lo(U_.z), acc[4]);                   \
        acc[5] = fmaf(W_, bf_hi(U_.z), acc[5]);                   \
        acc[6] = fmaf(W_, bf_lo(U_.w), acc[6]);                   \
        acc[7] = fmaf(W_, bf_hi(U_.w), acc[7]);                   \
        z += W_;                                                  \
    }

// 2-node gather: shfl within this half (nbase = nid*32); se masked to 0 when
// the half's row is empty (d==0) so no garbage-index OOB gather.
#define AGG1_GATHER(EIDX, SE_, AV_, UU_)                                     \
    int SE_ = __shfl(cv, nbase + ((EIDX) < d ? (EIDX) : dm1));               \
    SE_ = d > 0 ? SE_ : 0;                                                   \
    float AV_ = as1[SE_ * 8 + head];                                         \
    uint4 UU_ = *(const uint4*)(h1c + (((unsigned)SE_ << 7) + hoff));

#define AGG1_COMP(EIDX, AV_, UU_)                                            \
    {                                                                        \
        float w_ = (EIDX) < d ? lrelu_exp(AV_ + adv) : 0.f;                  \
        AGG_FMA(w_, UU_);                                                    \
    }

// Per-dst softmax-weighted aggregation, layer 1 (+ implicit self loop).
// R24: TWO nodes per wave. Lanes 0-31 = node A, 32-63 = node B; within a
// half: 4 edge slots x 8 heads on 128B rows. One wave-wide csr load covers
// 32 edges/node; gathers for chunks 0-5 (24 edges) issue up-front; compute
// chunks gated by wave-uniform dmax. Reduce = 2 shfl levels (xor 8/16).
__global__ __launch_bounds__(256) void k_agg1(const ushort_t* __restrict__ h1b,
                                              const float* __restrict__ as1,
                                              const float* __restrict__ ad1,
                                              const float* __restrict__ b1,
                                              const int* __restrict__ rowptr,
                                              const int* __restrict__ rowEnd,
                                              const int* __restrict__ csr,
                                              float* __restrict__ h2, int N) {
    int tid = threadIdx.x, lane = tid & 63;
    int nbase0 = blockIdx.x * 8 + ((tid >> 6) << 1);
    if (nbase0 >= N) return;              // wave-uniform
    int nid = lane >> 5;                  // node within wave (0/1)
    int nbase = nid << 5;                 // shfl base for this half
    int l32 = lane & 31;
    int g = (lane >> 3) & 3;              // edge slot 0..3
    int head = lane & 7;                  // head (cols 8h..8h+7)
    int n = nbase0 + nid;
    bool valid = n < N;
    int nc = valid ? n : N - 1;
    const char* h1c = (const char*)h1b;
    unsigned hoff = (unsigned)head << 4;  // 16B per head block
    float adv = ad1[nc * 8 + head];
    float acc[8];
    #pragma unroll
    for (int k = 0; k < 8; k++) acc[k] = 0.f;
    float z = 0.f;

    int j0 = rowptr[nc], j1 = rowEnd[nc];
    int d = valid ? (j1 - j0) : 0;
    int dm1 = d > 0 ? d - 1 : 0;
    int dx = __shfl_xor(d, 32);
    int dmax = d > dx ? d : dx;           // wave-uniform branch driver
    // ONE wave-wide csr load: 32 edges per node (value garbage if d==0;
    // address always in-bounds; masked at se stage)
    int cv = csr[j0 + (l32 < d ? l32 : dm1)];

    {   // self loop (g==0 lanes of each half: 16/64 active)
        float w = lrelu_exp(as1[nc * 8 + head] + adv);
        if (g == 0 && valid) {
            uint4 u = *(const uint4*)(h1c + (((unsigned)nc << 7) + hoff));
            acc[0] = w * bf_lo(u.x); acc[1] = w * bf_hi(u.x);
            acc[2] = w * bf_lo(u.y); acc[3] = w * bf_hi(u.y);
            acc[4] = w * bf_lo(u.z); acc[5] = w * bf_hi(u.z);
            acc[6] = w * bf_lo(u.w); acc[7] = w * bf_hi(u.w);
            z = w;
        }
    }
    if (dmax > 0) {
        // gathers for chunks 0..5 (edges 0..23 per node), 1 round trip
        int e0 = g, e1 = 4 + g, e2 = 8 + g, e3 = 12 + g, e4 = 16 + g, e5 = 20 + g;
        AGG1_GATHER(e0, s0, a0, u0)
        AGG1_GATHER(e1, s1, a1, u1)
        AGG1_GATHER(e2, s2, a2, u2)
        AGG1_GATHER(e3, s3, a3, u3)
        AGG1_GATHER(e4, s4, a4, u4)
        AGG1_GATHER(e5, s5, a5, u5)
        AGG1_COMP(e0, a0, u0)
        if (dmax > 4)  AGG1_COMP(e1, a1, u1)
        if (dmax > 8)  AGG1_COMP(e2, a2, u2)
        if (dmax > 12) AGG1_COMP(e3, a3, u3)
        if (dmax > 16) AGG1_COMP(e4, a4, u4)
        if (dmax > 20) AGG1_COMP(e5, a5, u5)
        if (dmax > 24) {                  // chunks 6/7 (edges 24..31)
            int e6 = 24 + g, e7 = 28 + g;
            AGG1_GATHER(e6, s6, a6, u6)
            AGG1_GATHER(e7, s7, a7, u7)
            AGG1_COMP(e6, a6, u6)
            if (dmax > 28) AGG1_COMP(e7, a7, u7)
            if (dmax > 32) {              // rare fallback: direct per-lane loads
                for (int eb = 32; eb < dmax; eb += 4) {
                    int e = eb + g;
                    int idx = e < d ? e : dm1;
                    int se = csr[j0 + idx];
                    se = d > 0 ? se : 0;
                    float av = as1[se * 8 + head];
                    uint4 u = *(const uint4*)(h1c + (((unsigned)se << 7) + hoff));
                    float w = e < d ? lrelu_exp(av + adv) : 0.f;
                    AGG_FMA(w, u);
                }
            }
        }
    }
    // reduce across the 4 edge-slot groups of each half (xor 8, 16 stay in-half)
    #pragma unroll
    for (int k = 0; k < 8; k++) {
        acc[k] += __shfl_xor(acc[k], 8);
        acc[k] += __shfl_xor(acc[k], 16);
    }
    z += __shfl_xor(z, 8); z += __shfl_xor(z, 16);
    if (g == 0 && valid) {
        float inv = 1.f / (z + 1e-16f);
        float o[8];
        #pragma unroll
        for (int k = 0; k < 8; k++) {
            float v = acc[k] * inv + b1[head * 8 + k];
            o[k] = v > 0.f ? v : (__expf(v) - 1.f);
        }
        float4* dp = (float4*)&h2[(size_t)n * 64 + head * 8];
        dp[0] = make_float4(o[0], o[1], o[2], o[3]);
        dp[1] = make_float4(o[4], o[5], o[6], o[7]);
    }
}

// gb[n][40](bf16) = h2[n] @ W2 ; as2/ad2 from fp32 accumulators.
// Block = 64 nodes x 40 cols GEMM tile, K=64. Node-minor staging.
__global__ __launch_bounds__(256) void k_xform2(const float* __restrict__ h2,
                                                const float* __restrict__ W2,
                                                const float* __restrict__ asrc2,
                                                const float* __restrict__ adst2,
                                                ushort_t* __restrict__ gb,
                                                float* __restrict__ as2,
                                                float* __restrict__ ad2, int N) {
    __shared__ float XT[64 * 64];  // h2T[k][node]
    __shared__ float WS[64 * 40];  // WS[k][col]
    int tid = threadIdx.x;
    int n0 = blockIdx.x * 64;
    {   // stage W2: 2560 floats = 640 float4
        const float4* W4 = (const float4*)W2;
        float4* WS4 = (float4*)WS;
        for (int i = tid; i < 640; i += 256) WS4[i] = W4[i];
    }
    {   // stage h2 transposed, node-minor: i = k4*64 + node
        const float4* h4 = (const float4*)h2;
        for (int i = tid; i < 1024; i += 256) {
            int node = i & 63, k4 = i >> 6;
            int gn = n0 + node; if (gn > N - 1) gn = N - 1;
            float4 v = h4[(size_t)gn * 16 + k4];
            int k = k4 * 4;
            XT[(k + 0) * 64 + node] = v.x;
            XT[(k + 1) * 64 + node] = v.y;
            XT[(k + 2) * 64 + node] = v.z;
            XT[(k + 3) * 64 + node] = v.w;
        }
    }
    __syncthreads();
    int ci = tid & 15, ni = tid >> 4;
    int nb = ni * 4, cb = ci * 4;
    float acc[16];
    #pragma unroll
    for (int i = 0; i < 16; i++) acc[i] = 0.f;
    if (ci < 10) {
        #pragma unroll 4
        for (int k = 0; k < 64; k++) {
            float4 xv = *(const float4*)&XT[k * 64 + nb];
            float4 wv = *(const float4*)&WS[k * 40 + cb];
            acc[0]  = fmaf(xv.x, wv.x, acc[0]);  acc[1]  = fmaf(xv.x, wv.y, acc[1]);
            acc[2]  = fmaf(xv.x, wv.z, acc[2]);  acc[3]  = fmaf(xv.x, wv.w, acc[3]);
            acc[4]  = fmaf(xv.y, wv.x, acc[4]);  acc[5]  = fmaf(xv.y, wv.y, acc[5]);
            acc[6]  = fmaf(xv.y, wv.z, acc[6]);  acc[7]  = fmaf(xv.y, wv.w, acc[7]);
            acc[8]  = fmaf(xv.z, wv.x, acc[8]);  acc[9]  = fmaf(xv.z, wv.y, acc[9]);
            acc[10] = fmaf(xv.z, wv.z, acc[10]); acc[11] = fmaf(xv.z, wv.w, acc[11]);
            acc[12] = fmaf(xv.w, wv.x, acc[12]); acc[13] = fmaf(xv.w, wv.y, acc[13]);
            acc[14] = fmaf(xv.w, wv.z, acc[14]); acc[15] = fmaf(xv.w, wv.w, acc[15]);
        }
    }
    #pragma unroll
    for (int i = 0; i < 4; i++) {
        int n = n0 + nb + i;
        if (ci < 10 && n < N) {
            unsigned int p0 = f2bf(acc[i * 4 + 0]) | (f2bf(acc[i * 4 + 1]) << 16);
            unsigned int p1 = f2bf(acc[i * 4 + 2]) | (f2bf(acc[i * 4 + 3]) << 16);
            *(uint2*)&gb[(size_t)n * 40 + cb] = make_uint2(p0, p1);  // 80B rows
        }
        float s = 0.f, d = 0.f;
        if (ci < 10) {
            #pragma unroll
            for (int j = 0; j < 4; j++) {
                s = fmaf(acc[i * 4 + j], asrc2[cb + j], s);
                d = fmaf(acc[i * 4 + j], adst2[cb + j], d);
            }
        }
        // reduce over the 16-lane ci group (ci>=10 contribute 0)
        s += __shfl_xor(s, 1); s += __shfl_xor(s, 2);
        s += __shfl_xor(s, 4); s += __shfl_xor(s, 8);
        d += __shfl_xor(d, 1); d += __shfl_xor(d, 2);
        d += __shfl_xor(d, 4); d += __shfl_xor(d, 8);
        if (ci == 0 && n < N) { as2[n] = s; ad2[n] = d; }
    }
}

// 2-node agg2 gather: uint2 (4 cols) of row se at this lane's col block.
// se masked to 0 when the half's row is empty (d==0).
#define AGG2_G(C_, SE_, AV_, UU_)                                            \
    int ee##C_ = 3 * (C_) + gg;                                              \
    int SE_ = __shfl(cv, nbase + (ee##C_ < d ? ee##C_ : dm1));               \
    SE_ = d > 0 ? SE_ : 0;                                                   \
    float AV_ = as2[SE_];                                                    \
    uint2 UU_ = *(const uint2*)(gbc + (unsigned)SE_ * 80u + poff);

#define AGG2_K(C_, AV_, UU_)                                                 \
    {                                                                        \
        float w_ = (ee##C_ < d) ? lrelu_exp(AV_ + add) : 0.f;                \
        acc[0] = fmaf(w_, bf_lo(UU_.x), acc[0]);                             \
        acc[1] = fmaf(w_, bf_hi(UU_.x), acc[1]);                             \
        acc[2] = fmaf(w_, bf_lo(UU_.y), acc[2]);                             \
        acc[3] = fmaf(w_, bf_hi(UU_.y), acc[3]);                             \
        z += w_;                                                             \
    }

// Layer-2 aggregation + bias + log_softmax.
// R25: TWO nodes per wave. Per half (32 lanes): 3 edge slots x 10 lanes,
// uint2 (8B = 4 cols) per lane on unpadded 80B rows; weight-lane ==
// compute-lane (each lane loads as2[se] of its own slot — no weight shfls).
// One wave-wide csr load covers 32 edges/node; gathers chunks 0..7
// (24 edges) up-front; compute gated on wave-uniform dmax; chunks 8/9 for
// dmax>24; direct-load fallback >=30. Reduce: +10/+20 shfls of ORIGINAL
// values (valid at lanes p<10 of each half). Epilogue: 4-level xor
// butterfly within each half's first 16 lanes.
__global__ __launch_bounds__(256) void k_agg2(const ushort_t* __restrict__ gb,
                                              const float* __restrict__ as2,
                                              const float* __restrict__ ad2,
                                              const float* __restrict__ b2,
                                              const int* __restrict__ rowptr,
                                              const int* __restrict__ rowEnd,
                                              const int* __restrict__ csr,
                                              float* __restrict__ out, int N) {
    int tid = threadIdx.x, lane = tid & 63;
    int nbase0 = blockIdx.x * 8 + ((tid >> 6) << 1);
    if (nbase0 >= N) return;              // wave-uniform
    int nid = lane >> 5;                  // node within wave (0/1)
    int nbase = nid << 5;                 // shfl base for this half
    int l32 = lane & 31;
    int gg = l32 / 10;                    // edge slot 0..2 (lanes 30/31 dup)
    int p = l32 - gg * 10;                // col block (4 cols each)
    if (gg > 2) { gg = 2; p = 9; }        // lanes 30,31: duplicate, unread
    int n = nbase0 + nid;
    bool valid = n < N;
    int nc = valid ? n : N - 1;
    const char* gbc = (const char*)gb;
    unsigned poff = (unsigned)p << 3;     // 8B per col block
    float add = ad2[nc];
    float acc[4] = {0.f, 0.f, 0.f, 0.f};
    float z = 0.f;

    int j0 = rowptr[nc], j1 = rowEnd[nc];
    int d = valid ? (j1 - j0) : 0;
    int dm1 = d > 0 ? d - 1 : 0;
    int dxx = __shfl_xor(d, 32);
    int dmax = d > dxx ? d : dxx;         // wave-uniform branch driver
    // ONE wave-wide csr load: 32 edges per node (masked at se stage)
    int cv = csr[j0 + (l32 < d ? l32 : dm1)];

    {   // self loop (gg==0 lanes of each half)
        float w = lrelu_exp(as2[nc] + add);
        if (gg == 0 && valid) {
            uint2 u = *(const uint2*)(gbc + (unsigned)nc * 80u + poff);
            acc[0] = w * bf_lo(u.x); acc[1] = w * bf_hi(u.x);
            acc[2] = w * bf_lo(u.y); acc[3] = w * bf_hi(u.y);
            z = w;
        }
    }
    if (dmax > 0) {
        // gathers for chunks 0..7 (edges 0..23 per node), 1 round trip
        AGG2_G(0, s0, a0, u0)
        AGG2_G(1, s1, a1, u1)
        AGG2_G(2, s2, a2, u2)
        AGG2_G(3, s3, a3, u3)
        AGG2_G(4, s4, a4, u4)
        AGG2_G(5, s5, a5, u5)
        AGG2_G(6, s6, a6, u6)
        AGG2_G(7, s7, a7, u7)
        AGG2_K(0, a0, u0)
        if (dmax > 3)  AGG2_K(1, a1, u1)
        if (dmax > 6)  AGG2_K(2, a2, u2)
        if (dmax > 9)  AGG2_K(3, a3, u3)
        if (dmax > 12) AGG2_K(4, a4, u4)
        if (dmax > 15) AGG2_K(5, a5, u5)
        if (dmax > 18) AGG2_K(6, a6, u6)
        if (dmax > 21) AGG2_K(7, a7, u7)
        if (dmax > 24) {                  // chunks 8/9 (edges 24..29)
            AGG2_G(8, s8, a8, u8)
            AGG2_G(9, s9, a9, u9)
            AGG2_K(8, a8, u8)
            if (dmax > 27) AGG2_K(9, a9, u9)
            if (dmax > 30) {              // rare fallback: direct per-lane loads
                for (int eb = 30; eb < dmax; eb += 3) {
                    int e = eb + gg;
                    int idx = e < d ? e : dm1;
                    int se = csr[j0 + idx];
                    se = d > 0 ? se : 0;
                    float av = as2[se];
                    uint2 u = *(const uint2*)(gbc + (unsigned)se * 80u + poff);
                    float w = (e < d) ? lrelu_exp(av + add) : 0.f;
                    acc[0] = fmaf(w, bf_lo(u.x), acc[0]);
                    acc[1] = fmaf(w, bf_hi(u.x), acc[1]);
                    acc[2] = fmaf(w, bf_lo(u.y), acc[2]);
                    acc[3] = fmaf(w, bf_hi(u.y), acc[3]);
                    z += w;
                }
            }
        }
    }
    // reduce across the 3 slot groups: A(p) = v(p) + v(p+10) + v(p+20).
    // Both shfls read the ORIGINAL value; result valid at lanes p<10 of
    // each half (reads stay within the half there).
    #pragma unroll
    for (int k = 0; k < 4; k++) {
        float t1 = __shfl(acc[k], lane + 10);
        float t2 = __shfl(acc[k], lane + 20);
        acc[k] += t1 + t2;
    }
    {
        float t1 = __shfl(z, lane + 10);
        float t2 = __shfl(z, lane + 20);
        z += t1 + t2;
    }
    // epilogue: lanes l32<10 hold 4 logits each (cols 4p..4p+3);
    // butterfly over each half's first 16 lanes (xor 1/2/4/8 stays inside)
    bool act = (l32 < 10) && valid;
    float l[4];
    float mv = -INFINITY;
    if (act) {
        float inv = 1.f / (z + 1e-16f);
        #pragma unroll
        for (int k = 0; k < 4; k++) {
            l[k] = acc[k] * inv + b2[p * 4 + k];
            mv = fmaxf(mv, l[k]);
        }
    }
    mv = fmaxf(mv, __shfl_xor(mv, 1));
    mv = fmaxf(mv, __shfl_xor(mv, 2));
    mv = fmaxf(mv, __shfl_xor(mv, 4));
    mv = fmaxf(mv, __shfl_xor(mv, 8));
    float ev = 0.f;
    if (act) {
        #pragma unroll
        for (int k = 0; k < 4; k++) ev += __expf(l[k] - mv);
    }
    ev += __shfl_xor(ev, 1);
    ev += __shfl_xor(ev, 2);
    ev += __shfl_xor(ev, 4);
    ev += __shfl_xor(ev, 8);
    if (act) {
        float ls = mv + __logf(ev);
        float4* dp = (float4*)&out[(size_t)n * 40 + p * 4];
        dp[0] = make_float4(l[0] - ls, l[1] - ls, l[2] - ls, l[3] - ls);
    }
}

extern "C" void kernel_launch(void* const* d_in, const int* in_sizes, int n_in,
                              void* d_out, int out_size, void* d_ws, size_t ws_size,
                              hipStream_t stream) {
    const float* x    = (const float*)d_in[0];
    const float* topo = (const float*)d_in[1];
    const int*   ei   = (const int*)d_in[2];
    const float* W1   = (const float*)d_in[3];
    const float* a_s1 = (const float*)d_in[4];
    const float* a_d1 = (const float*)d_in[5];
    const float* b1   = (const float*)d_in[6];
    const float* W2   = (const float*)d_in[7];
    const float* a_s2 = (const float*)d_in[8];
    const float* a_d2 = (const float*)d_in[9];
    const float* b2   = (const float*)d_in[10];
    float* out = (float*)d_out;

    int N = in_sizes[0] / 128;
    int E = in_sizes[2] / 2;
    const int* esrc = ei;
    const int* edst = ei + E;
    int NBUK = (N + 255) / 256;
    size_t cap = (size_t)NBUK * BUK_CAP;

    char* ws = (char*)d_ws;
    size_t off = 0;
    auto alloc = [&](size_t bytes) -> void* {
        void* p = ws + off;
        off = (off + bytes + 255) & ~(size_t)255;
        return p;
    };
    ushort_t* h1b  = (ushort_t*)alloc((size_t)N * 64 * 2);
    float* as1     = (float*)alloc((size_t)N * 8 * 4);
    float* ad1     = (float*)alloc((size_t)N * 8 * 4);
    float* h2      = (float*)alloc((size_t)N * 64 * 4);
    ushort_t* gb   = (ushort_t*)alloc((size_t)N * 40 * 2);  // 80B rows
    float* as2     = (float*)alloc((size_t)N * 4);
    float* ad2     = (float*)alloc((size_t)N * 4);
    int*   rowptr  = (int*)alloc((size_t)N * 4);
    int*   rowEnd  = (int*)alloc((size_t)N * 4);
    int*   csr     = (int*)alloc(cap * 4);
    unsigned int* tmp = (unsigned int*)alloc(cap * 4);
    int* gCursor   = (int*)alloc((size_t)NBUK * 4);

    hipMemsetAsync(gCursor, 0, (size_t)NBUK * 4, stream);  // count-based cursors
    int nbin = (E + BIN_CHUNK - 1) / BIN_CHUNK;
    k_bin<<<nbin, 256, 0, stream>>>(esrc, edst, gCursor, tmp, E, NBUK);
    k_fill2<<<NBUK, 512, 0, stream>>>(tmp, gCursor, rowptr, rowEnd, csr, N);

    int nbg = (N + 63) / 64;  // 64-node GEMM tiles
    int nb8 = (N + 7) / 8;    // 2 nodes/wave x 4 waves/block (agg kernels)
    k_xform1<<<nbg, 256, 0, stream>>>(x, topo, W1, a_s1, a_d1, h1b, as1, ad1, N);
    k_agg1<<<nb8, 256, 0, stream>>>(h1b, as1, ad1, b1, rowptr, rowEnd, csr, h2, N);
    k_xform2<<<nbg, 256, 0, stream>>>(h2, W2, a_s2, a_d2, gb, as2, ad2, N);
    k_agg2<<<nb8, 256, 0, stream>>>(gb, as2, ad2, b2, rowptr, rowEnd, csr, out, N);
}